// Round 1
// baseline (1837.952 us; speedup 1.0000x reference)
//
#include <hip/hip_runtime.h>
#include <math.h>

// MFFNet forward on MI355X. fp32 in/out; all GEMMs bf16-MFMA with fp32 acc.
// m97-structure GEMM core (global_load_lds width-16, BK=64, 2 barriers/k-step).
// This revision: FeatureAlignment fused to one K=4608 GEMM (wplus folded into
// input conversion, rowBias epilogue), 3 fastformer layers batched (z=3,
// duplicated-U trick), 128-tile GEMMs everywhere, fused ef+LN and LN3+sum+LN.
// 39 dispatches. Workspace ~240 MB.

typedef unsigned short u16;
typedef __attribute__((ext_vector_type(8))) short short8;     // 8 bf16
typedef __attribute__((ext_vector_type(8))) unsigned short us8;
typedef __attribute__((ext_vector_type(4))) float floatx4;
typedef unsigned __attribute__((address_space(1))) gu32;
typedef unsigned __attribute__((address_space(3))) lu32;

#define DD 768
#define TT 512
#define BB 8
#define MM 4096      // B*T rows
#define FFN 3072
#define MDL ((long)MM * DD)

__device__ __forceinline__ float b2f(u16 u) {
  union { unsigned u32; float f; } x; x.u32 = ((unsigned)u) << 16; return x.f;
}
__device__ __forceinline__ u16 f2b(float f) {   // round-to-nearest-even
  union { float f; unsigned u; } x; x.f = f;
  unsigned r = x.u + 0x7FFFu + ((x.u >> 16) & 1u);
  return (u16)(r >> 16);
}

// ---------------------------------------------------------------------------
// GEMM: C[M,N] = act(A[M,K] @ W[N,K]^T + bias + rowBias + resid)
// A, W bf16. 4 waves; BK=64; LDS stride 64. ntaps/pad = conv-over-T (zero page
// OOB). OP: 0=none 1=relu 2=gelu 3=sigmoid. ldc = C row pitch (also resid).
// ---------------------------------------------------------------------------
template<int BM, int BN, int OP>
__global__ __launch_bounds__(256)
void gemm_bt(const u16* __restrict__ A, const u16* __restrict__ W,
             const float* __restrict__ bias, const float* __restrict__ rowBias,
             const void* __restrict__ residv, void* __restrict__ Cv,
             int N, int K, int ldc, int rBf16, int outBf16,
             int ntaps, int pad, long wtapStride,
             long aBatch, long wBatch, long cBatch, long rBatch,
             const u16* __restrict__ zp)
{
  __shared__ __align__(16) u16 sA[BM * 64];
  __shared__ __align__(16) u16 sB[BN * 64];
  const int tid  = threadIdx.x;
  const int lane = tid & 63;
  const int wv   = tid >> 6;

  // XCD swizzle: contiguous tile range per XCD
  int gx = gridDim.x, gy = gridDim.y;
  int bn = blockIdx.y * gx + blockIdx.x;
  int Tt = gx * gy;
  if ((Tt & 7) == 0) bn = (bn & 7) * (Tt >> 3) + (bn >> 3);
  const int m0 = (bn / gx) * BM;
  const int n0 = (bn % gx) * BN;
  const u16* Ab  = A + (long)blockIdx.z * aBatch;
  const u16* Wb0 = W + (long)blockIdx.z * wBatch;

  constexpr int NI = (BM == 128 && BN == 128) ? 4 : (BM == 128 ? 2 : 1);
  constexpr int NJ = 4;
  int wr, wc;
  if constexpr (BM == 128 && BN == 128) { wr = (wv >> 1) * 64; wc = (wv & 1) * 64; }
  else if constexpr (BM == 128)          { wr = wv * 32;        wc = 0; }
  else                                    { wr = wv * 16;        wc = 0; }

  floatx4 acc[NI][NJ];
#pragma unroll
  for (int i = 0; i < NI; ++i)
#pragma unroll
    for (int j = 0; j < NJ; ++j) acc[i][j] = (floatx4){0.f, 0.f, 0.f, 0.f};

  const int mrow = lane & 15;
  const int ksub = (lane >> 4) * 8;

  for (int tap = 0; tap < ntaps; ++tap) {
    const int dt = tap - pad;
    const u16* Wt = Wb0 + (long)tap * wtapStride;
    for (int k0 = 0; k0 < K; k0 += 64) {
#pragma unroll
      for (int it = 0; it < BM / 32; ++it) {
        int slot = it * 256 + tid;
        int row = slot >> 3, col = (slot & 7) * 8;
        int gr = m0 + row;
        int t  = gr & (TT - 1);
        const u16* src = ((unsigned)(t + dt) < (unsigned)TT)
                       ? (Ab + (long)(gr + dt) * K + k0 + col) : zp;
        __builtin_amdgcn_global_load_lds((const gu32*)src,
                                         (lu32*)((char*)sA + slot * 16), 16, 0, 0);
      }
#pragma unroll
      for (int it = 0; it < BN / 32; ++it) {
        int slot = it * 256 + tid;
        int row = slot >> 3, col = (slot & 7) * 8;
        const u16* src = Wt + (long)(n0 + row) * K + k0 + col;
        __builtin_amdgcn_global_load_lds((const gu32*)src,
                                         (lu32*)((char*)sB + slot * 16), 16, 0, 0);
      }
      __syncthreads();     // drains vmcnt(0): DMA complete, LDS visible
#pragma unroll
      for (int kb = 0; kb < 64; kb += 32) {
        short8 af[NI], bfr[NJ];
#pragma unroll
        for (int i = 0; i < NI; ++i)
          af[i] = *(const short8*)(sA + (wr + i * 16 + mrow) * 64 + kb + ksub);
#pragma unroll
        for (int j = 0; j < NJ; ++j)
          bfr[j] = *(const short8*)(sB + (wc + j * 16 + mrow) * 64 + kb + ksub);
#pragma unroll
        for (int i = 0; i < NI; ++i)
#pragma unroll
          for (int j = 0; j < NJ; ++j)
            acc[i][j] = __builtin_amdgcn_mfma_f32_16x16x32_bf16(af[i], bfr[j], acc[i][j], 0, 0, 0);
      }
      __syncthreads();     // all reads done before next DMA overwrites
    }
  }

  // epilogue: C/D layout col=lane&15, row=(lane>>4)*4+reg (m89-verified)
  const int cn = lane & 15;
  const int rq = (lane >> 4) * 4;
  u16*   Ch = (u16*)Cv   + (long)blockIdx.z * cBatch;
  float* Cf = (float*)Cv + (long)blockIdx.z * cBatch;
  const long zr = (long)blockIdx.z * rBatch;
#pragma unroll
  for (int j = 0; j < NJ; ++j) {
    int gn = n0 + wc + j * 16 + cn;
    float bv = bias ? bias[gn] : 0.f;
#pragma unroll
    for (int i = 0; i < NI; ++i) {
#pragma unroll
      for (int r = 0; r < 4; ++r) {
        int gm = m0 + wr + i * 16 + rq + r;
        long idx = (long)gm * ldc + gn;
        float v = acc[i][j][r] + bv;
        if (rowBias) v += rowBias[(gm >> 9) * N + gn];
        if (residv)
          v += rBf16 ? b2f(((const u16*)residv)[idx + zr]) : ((const float*)residv)[idx + zr];
        if (OP == 1) v = fmaxf(v, 0.f);
        if (OP == 2) v = 0.5f * v * (1.f + erff(v * 0.70710678118654752440f));
        if (OP == 3) v = 1.f / (1.f + expf(-v));
        if (outBf16) Ch[idx] = f2b(v);
        else Cf[idx] = v;
      }
    }
  }
}

// ---------------------------------------------------------------------------
// bulk fp32 -> bf16 conversion with row remap (pitch) + per-b scale.
// 32 B read / 16 B write per thread. Used to build the wplus-scaled,
// K-concatenated align input A' and the K-concatenated align weight in-place.
// ---------------------------------------------------------------------------
#define NJOBS 27
struct ConvJobs {
  const float* src[NJOBS];
  u16* dst[NJOBS];
  int n2[NJOBS];         // pairs (8 floats) per job
  int rowLen2[NJOBS];    // pairs per source row
  int dstPitch2[NJOBS];  // dst row pitch in pairs
  const float* scl[NJOBS];  // per-(row>>9) scale or null
};
__global__ void convert_all(ConvJobs J, long total2)
{
  long g = (long)blockIdx.x * 256 + threadIdx.x;
  if (g >= total2) return;
  int j = 0; long off = g;
  while (off >= J.n2[j]) { off -= J.n2[j]; ++j; }
  long row = off / J.rowLen2[j];
  long c2  = off - row * J.rowLen2[j];
  const float4* s = (const float4*)J.src[j] + off * 2;
  float4 x = s[0], y = s[1];
  float sc = J.scl[j] ? J.scl[j][row >> 9] : 1.f;
  us8 h;
  h[0] = f2b(x.x * sc); h[1] = f2b(x.y * sc); h[2] = f2b(x.z * sc); h[3] = f2b(x.w * sc);
  h[4] = f2b(y.x * sc); h[5] = f2b(y.y * sc); h[6] = f2b(y.z * sc); h[7] = f2b(y.w * sc);
  *(us8*)(J.dst[j] + (row * (long)J.dstPitch2[j] + c2) * 8) = h;
}

__global__ void zero_kernel(u16* zp) { if (threadIdx.x < 128) zp[threadIdx.x] = 0; }

__global__ void copy16(const u16* __restrict__ s, u16* __restrict__ d)
{
  long g = (long)blockIdx.x * 256 + threadIdx.x;
  *(us8*)(d + g * 8) = *(const us8*)(s + g * 8);
}

// LayerNorm over D=768; input fp32 or bf16; out fp32 or bf16
__global__ void ln_kernel(const void* __restrict__ x, int xBf16,
                          const float* __restrict__ w, const float* __restrict__ b,
                          float* __restrict__ y32, u16* __restrict__ y16, int accum)
{
  const int row = blockIdx.x;
  const int tid = threadIdx.x;
  __shared__ float rs[256], rq[256];
  float v[3];
  long base = (long)row * DD;
  float s = 0.f, q = 0.f;
#pragma unroll
  for (int i = 0; i < 3; ++i) {
    int c = tid + i * 256;
    float t = xBf16 ? b2f(((const u16*)x)[base + c]) : ((const float*)x)[base + c];
    v[i] = t; s += t; q += t * t;
  }
  rs[tid] = s; rq[tid] = q; __syncthreads();
  for (int st = 128; st > 0; st >>= 1) {
    if (tid < st) { rs[tid] += rs[tid + st]; rq[tid] += rq[tid + st]; }
    __syncthreads();
  }
  float mean = rs[0] * (1.f / DD);
  float var  = fmaxf(rq[0] * (1.f / DD) - mean * mean, 0.f);
  float rstd = rsqrtf(var + 1e-12f);
#pragma unroll
  for (int i = 0; i < 3; ++i) {
    int c = tid + i * 256;
    float o = ((v[i] - mean) * rstd) * w[c] + b[c];
    if (y32) { if (accum) y32[base + c] += o; else y32[base + c] = o; }
    if (y16) {
      if (accum && !y32) y16[base + c] = f2b(b2f(y16[base + c]) + o);
      else y16[base + c] = f2b(o);
    }
  }
}

// Ef = g*Ea + (1-g)*Et, then LN(Ef) -> bf16. Et read from cc left half (pitch 1536).
__global__ void ef_ln_kernel(const u16* __restrict__ g, const float* __restrict__ Ea,
                             const u16* __restrict__ EtC,
                             const float* __restrict__ w, const float* __restrict__ b,
                             u16* __restrict__ xo)
{
  const int row = blockIdx.x;
  const int tid = threadIdx.x;
  __shared__ float rs[256], rq[256];
  float v[3];
  float s = 0.f, q = 0.f;
#pragma unroll
  for (int i = 0; i < 3; ++i) {
    int c = tid + i * 256;
    float gv = b2f(g[(long)row * DD + c]);
    float et = b2f(EtC[(long)row * 1536 + c]);
    float e  = gv * Ea[(long)row * DD + c] + (1.f - gv) * et;
    v[i] = e; s += e; q += e * e;
  }
  rs[tid] = s; rq[tid] = q; __syncthreads();
  for (int st = 128; st > 0; st >>= 1) {
    if (tid < st) { rs[tid] += rs[tid + st]; rq[tid] += rq[tid + st]; }
    __syncthreads();
  }
  float mean = rs[0] * (1.f / DD);
  float var  = fmaxf(rq[0] * (1.f / DD) - mean * mean, 0.f);
  float rstd = rsqrtf(var + 1e-12f);
#pragma unroll
  for (int i = 0; i < 3; ++i) {
    int c = tid + i * 256;
    xo[(long)row * DD + c] = f2b(((v[i] - mean) * rstd) * w[c] + b[c]);
  }
}

// Pn = LN( sum_z LN(outp[z], fln) , ln ). Sum in f32 (was bf16 accumulate).
__global__ void ln3sum_kernel(const u16* __restrict__ o,
                              const float* __restrict__ fw, const float* __restrict__ fb,
                              const float* __restrict__ lw, const float* __restrict__ lb,
                              u16* __restrict__ Pn)
{
  const int row = blockIdx.x;
  const int tid = threadIdx.x;
  __shared__ float rs[256], rq[256];
  float v[3][3], mz[3], rz[3];
  for (int z = 0; z < 3; ++z) {
    long base = (long)z * MDL + (long)row * DD;
    float s = 0.f, q = 0.f;
#pragma unroll
    for (int i = 0; i < 3; ++i) {
      int c = tid + i * 256;
      float t = b2f(o[base + c]);
      v[z][i] = t; s += t; q += t * t;
    }
    rs[tid] = s; rq[tid] = q; __syncthreads();
    for (int st = 128; st > 0; st >>= 1) {
      if (tid < st) { rs[tid] += rs[tid + st]; rq[tid] += rq[tid + st]; }
      __syncthreads();
    }
    float mean = rs[0] * (1.f / DD);
    float var  = fmaxf(rq[0] * (1.f / DD) - mean * mean, 0.f);
    mz[z] = mean; rz[z] = rsqrtf(var + 1e-12f);
    __syncthreads();   // protect rs/rq reuse next z
  }
  float p[3];
  float s = 0.f, q = 0.f;
#pragma unroll
  for (int i = 0; i < 3; ++i) {
    int c = tid + i * 256;
    float pv = 0.f;
#pragma unroll
    for (int z = 0; z < 3; ++z) pv += (v[z][i] - mz[z]) * rz[z];
    pv = pv * fw[c] + 3.f * fb[c];
    p[i] = pv; s += pv; q += pv * pv;
  }
  rs[tid] = s; rq[tid] = q; __syncthreads();
  for (int st = 128; st > 0; st >>= 1) {
    if (tid < st) { rs[tid] += rs[tid + st]; rq[tid] += rq[tid + st]; }
    __syncthreads();
  }
  float mean = rs[0] * (1.f / DD);
  float var  = fmaxf(rq[0] * (1.f / DD) - mean * mean, 0.f);
  float rstd = rsqrtf(var + 1e-12f);
#pragma unroll
  for (int i = 0; i < 3; ++i) {
    int c = tid + i * 256;
    Pn[(long)row * DD + c] = f2b(((p[i] - mean) * rstd) * lw[c] + lb[c]);
  }
}

// all 6 streams' rowmeans in one launch (was 6x 24-block launches)
__global__ void rowmean_all(const float* f0, const float* f1, const float* f2,
                            const float* f3, const float* f4, const float* f5,
                            float* __restrict__ rm)
{
  const float* fs[6] = {f0, f1, f2, f3, f4, f5};
  int n = blockIdx.y;
  int b = blockIdx.x / 3, chunk = blockIdx.x % 3;
  int d = chunk * 256 + threadIdx.x;
  const float* base = fs[n] + (long)b * TT * DD + d;
  float s = 0.f;
  for (int t = 0; t < TT; ++t) s += base[(long)t * DD];
  rm[((long)n * BB + b) * DD + d] = s * (1.f / TT);
}

__global__ void colsum_kernel(const float* __restrict__ w, float* __restrict__ cs)
{
  int n = blockIdx.x / 3, chunk = blockIdx.x % 3;
  int e = chunk * 256 + threadIdx.x;
  const float* base = w + (long)n * DD * DD + e;
  float s = 0.f;
  for (int d = 0; d < DD; ++d) s += base[(long)d * DD];
  cs[n * DD + e] = s;
}

__global__ void fusion_weights(const float* __restrict__ rm, const float* __restrict__ cs,
                               const float* __restrict__ align_b,
                               const float* __restrict__ aw, const float* __restrict__ ab,
                               float* __restrict__ wpT)
{
  __shared__ float msh[48];
  int tid = threadIdx.x;
  if (tid < 48) {
    int b = tid / 6, n = tid % 6;
    const float* r = rm + ((long)n * BB + b) * DD;
    const float* c = cs + n * DD;
    float dot = 0.f, bs = 0.f;
    for (int e = 0; e < DD; ++e) dot += r[e] * c[e];
    for (int d = 0; d < DD; ++d) bs += align_b[n * DD + d];
    msh[b * 6 + n] = (dot + bs) * (1.f / DD);
  }
  __syncthreads();
  if (tid < BB) {
    int b = tid;
    float z[6];
#pragma unroll
    for (int n = 0; n < 6; ++n) {
      float s = ab[n];
#pragma unroll
      for (int j = 0; j < 6; ++j)
        s += (aw[n * 12 + j] + aw[n * 12 + 6 + j]) * msh[b * 6 + j];
      z[n] = fmaxf(s, 0.f);
    }
    float mx = z[0];
#pragma unroll
    for (int n = 1; n < 6; ++n) mx = fmaxf(mx, z[n]);
    float se = 0.f, e[6];
#pragma unroll
    for (int n = 0; n < 6; ++n) { e[n] = expf(z[n] - mx); se += e[n]; }
#pragma unroll
    for (int n = 0; n < 6; ++n) wpT[n * 8 + b] = e[n] / se + (1.f / 6.f);
  }
}

// rb[b,d] = sum_n wplus[b,n] * align_b[n,d]
__global__ void rowbias_kernel(const float* __restrict__ wpT, const float* __restrict__ ab,
                               float* __restrict__ rb)
{
  int b = blockIdx.x / 3;
  int d = (blockIdx.x % 3) * 256 + threadIdx.x;
  float s = 0.f;
#pragma unroll
  for (int n = 0; n < 6; ++n) s += wpT[n * 8 + b] * ab[n * DD + d];
  rb[b * DD + d] = s;
}

// conv weight [O,I,KT] fp32 -> [KT][O][I] bf16
__global__ void repack_conv(const float* __restrict__ src, u16* __restrict__ dst, int KT)
{
  long e = (long)blockIdx.x * 256 + threadIdx.x;
  if (e >= (long)KT * DD * DD) return;
  int k = (int)(e / (DD * DD));
  int rem = (int)(e - (long)k * DD * DD);
  int o = rem / DD, i = rem % DD;
  dst[e] = f2b(src[((long)o * DD + i) * KT + k]);
}

// out[row,h] = (X[row,:] . Wt[h,:] + bias[h]) * scale ; H=12, X bf16
__global__ void lin_small(const u16* __restrict__ X, const float* __restrict__ Wt,
                          const float* __restrict__ bias, float scale,
                          float* __restrict__ out)
{
  int row = blockIdx.x * 4 + (threadIdx.x >> 6);
  int lane = threadIdx.x & 63;
  float acc[12];
#pragma unroll
  for (int h = 0; h < 12; ++h) acc[h] = 0.f;
  for (int k = lane; k < DD; k += 64) {
    float xv = b2f(X[(long)row * DD + k]);
#pragma unroll
    for (int h = 0; h < 12; ++h) acc[h] += xv * Wt[h * DD + k];
  }
#pragma unroll
  for (int h = 0; h < 12; ++h)
    for (int off = 32; off > 0; off >>= 1) acc[h] += __shfl_down(acc[h], off);
  if (lane == 0) {
#pragma unroll
    for (int h = 0; h < 12; ++h)
      out[(long)row * 12 + h] = (acc[h] + bias[h]) * scale;
  }
}

__global__ void scores_softmax(const float* __restrict__ qs, const float* __restrict__ ks,
                               u16* __restrict__ aw)
{
  int bs = blockIdx.x;            // global (z*8+b)*512+s
  int b = bs >> 9;
  int tid = threadIdx.x;
  __shared__ float qsh[12];
  __shared__ float red[256];
  if (tid < 12) qsh[tid] = qs[(long)bs * 12 + tid];
  __syncthreads();
  float sc[2];
#pragma unroll
  for (int p = 0; p < 2; ++p) {
    int c = tid + p * 256;
    const float* kr = ks + (long)(b * 512 + c) * 12;
    float v = 0.f;
#pragma unroll
    for (int h = 0; h < 12; ++h) v += qsh[h] * kr[h];
    sc[p] = v;
  }
  red[tid] = fmaxf(sc[0], sc[1]); __syncthreads();
  for (int st = 128; st > 0; st >>= 1) {
    if (tid < st) red[tid] = fmaxf(red[tid], red[tid + st]);
    __syncthreads();
  }
  float mx = red[0]; __syncthreads();
  float e0 = expf(sc[0] - mx), e1 = expf(sc[1] - mx);
  red[tid] = e0 + e1; __syncthreads();
  for (int st = 128; st > 0; st >>= 1) {
    if (tid < st) red[tid] += red[tid + st];
    __syncthreads();
  }
  float inv = 1.f / red[0];
  aw[(long)bs * 512 + tid]       = f2b(e0 * inv);
  aw[(long)bs * 512 + tid + 256] = f2b(e1 * inv);
}

__global__ void transpose_kernel(const u16* __restrict__ in, u16* __restrict__ out)
{
  int b = blockIdx.z;
  const u16* ib = in + (long)b * TT * DD;
  u16* ob = out + (long)b * TT * DD;
  __shared__ u16 tile[32][33];
  int c0 = blockIdx.x * 32;   // d
  int r0 = blockIdx.y * 32;   // t
  int tx = threadIdx.x, ty = threadIdx.y;
#pragma unroll
  for (int i = 0; i < 4; ++i)
    tile[ty + 8 * i][tx] = ib[(long)(r0 + ty + 8 * i) * DD + c0 + tx];
  __syncthreads();
#pragma unroll
  for (int i = 0; i < 4; ++i)
    ob[(long)(c0 + ty + 8 * i) * TT + r0 + tx] = tile[tx][ty + 8 * i];
}

// ---------------------------------------------------------------------------
extern "C" void kernel_launch(void* const* d_in, const int* in_sizes, int n_in,
                              void* d_out, int out_size, void* d_ws, size_t ws_size,
                              hipStream_t stream)
{
  (void)in_sizes; (void)n_in; (void)out_size; (void)ws_size;
  const float* fin[6];
  for (int i = 0; i < 6; ++i) fin[i] = (const float*)d_in[i];
  const float* Ea      = (const float*)d_in[6];
  const float* align_w = (const float*)d_in[7];
  const float* align_b = (const float*)d_in[8];
  const float* att_w   = (const float*)d_in[9];
  const float* att_b   = (const float*)d_in[10];
  const float* g1_w = (const float*)d_in[11]; const float* g1_b = (const float*)d_in[12];
  const float* g2_w = (const float*)d_in[13]; const float* g2_b = (const float*)d_in[14];
  const float* g3_w = (const float*)d_in[15]; const float* g3_b = (const float*)d_in[16];
  const float* g4_w = (const float*)d_in[17]; const float* g4_b = (const float*)d_in[18];
  const float* ln_w = (const float*)d_in[19]; const float* ln_b = (const float*)d_in[20];
  const float* c1_w = (const float*)d_in[21]; const float* c1_b = (const float*)d_in[22];
  const float* c3_w = (const float*)d_in[23]; const float* c3_b = (const float*)d_in[24];
  const float* c5_w = (const float*)d_in[25]; const float* c5_b = (const float*)d_in[26];
  const float* q_w  = (const float*)d_in[27]; const float* q_b  = (const float*)d_in[28];
  const float* qa_w = (const float*)d_in[29]; const float* qa_b = (const float*)d_in[30];
  const float* k_w  = (const float*)d_in[31]; const float* k_b  = (const float*)d_in[32];
  const float* ka_w = (const float*)d_in[33]; const float* ka_b = (const float*)d_in[34];
  const float* tr_w = (const float*)d_in[35]; const float* tr_b = (const float*)d_in[36];
  const float* ao_w = (const float*)d_in[37]; const float* ao_b = (const float*)d_in[38];
  const float* fln_w = (const float*)d_in[39]; const float* fln_b = (const float*)d_in[40];
  const float* fi_w = (const float*)d_in[41]; const float* fi_b = (const float*)d_in[42];
  const float* fo_w = (const float*)d_in[43]; const float* fo_b = (const float*)d_in[44];
  const float* m1_w = (const float*)d_in[45]; const float* m1_b = (const float*)d_in[46];
  const float* m2_w = (const float*)d_in[47]; const float* m2_b = (const float*)d_in[48];
  const float* out_w = (const float*)d_in[49]; const float* out_b = (const float*)d_in[50];

  char* ws = (char*)d_ws;
  size_t off = 0;
  auto alloc = [&](size_t bytes) -> char* {
    char* p = ws + off;
    off += bytes;
    off = (off + 255) & ~(size_t)255;
    return p;
  };

  // small scratch
  u16*   zp    = (u16*)alloc(256);
  float* rmb   = (float*)alloc(6L * BB * DD * 4);
  float* csb   = (float*)alloc(6L * DD * 4);
  float* wpT   = (float*)alloc(48 * 4);
  float* rbias = (float*)alloc((long)BB * DD * 4);
  float* qsf   = (float*)alloc(3L * MM * 12 * 4);
  float* ksf   = (float*)alloc(3L * MM * 12 * 4);

  // bf16 weight cache (27,721,728 els = 55.4 MB); cW_al is the K-concatenated
  // align weight [768][4608] (same element count as the 6 separate matrices)
  u16* Wc = (u16*)alloc(27721728L * 2);
  u16* cW_g1   = Wc;
  u16* cW_g2   = Wc + 2359296L;
  u16* cW_fi   = Wc + 4718592L;
  u16* cW_fo   = Wc + 7077888L;
  u16* cW_m1   = Wc + 9437184L;
  u16* cW_m2   = Wc + 11796480L;
  u16* cW_g3   = Wc + 14155776L;
  u16* cW_al   = Wc + 15335424L;
  u16* cW_g4   = Wc + 18874368L;
  u16* cW_c1   = Wc + 19464192L;
  u16* cW_q    = Wc + 20054016L;
  u16* cW_k    = Wc + 20643840L;
  u16* cW_tr   = Wc + 21233664L;
  u16* cW_ao   = Wc + 21823488L;
  u16* cW_out  = Wc + 22413312L;
  u16* w3r     = Wc + 23003136L;
  u16* w5r     = Wc + 24772608L;

  // big aliased regions (~184 MB):
  char* R1 = alloc((long)MM * 4608 * 2);  // A'(37.7) -> qbuf(3MD b16) -> Jb(f32)
  char* R3 = alloc(MDL * 8);              // cc+o1 -> ctxkk -> Pn+Jn
  char* R4 = alloc(MDL * 8);              // o2+o3+gb -> kkTsf
  char* R5 = alloc(MDL * 2);              // xb16 (persistent)
  char* R6 = alloc(MDL * 8);              // U = [U5,U3,U1,U5dup]
  char* R8 = alloc(MDL * 6);              // attp -> outp (3 layers)
  char* R9 = alloc(MDL * 6);              // attb (3 layers)
  char* R10 = alloc((long)MM * FFN * 2);  // awb (12.6) -> interb (25.2)

  u16*   Ap    = (u16*)R1;
  u16*   qbuf  = (u16*)R1;
  float* Jb    = (float*)R1;
  u16*   cc    = (u16*)R3;                 // [MM][1536]: left=Et(bf16), right=Ea(bf16)
  u16*   o1    = (u16*)R3 + 2 * MDL;
  u16*   ctxkk = (u16*)R3;
  u16*   PnB   = (u16*)R3;
  u16*   Jn    = (u16*)R3 + MDL;
  u16*   o2    = (u16*)R4;
  u16*   o3    = (u16*)R4 + 2 * MDL;
  u16*   gbuf  = (u16*)R4 + 3 * MDL;
  u16*   kkTsf = (u16*)R4;
  u16*   xb16  = (u16*)R5;
  u16*   U     = (u16*)R6;
  u16*   attp  = (u16*)R8;
  u16*   outp  = (u16*)R8;
  u16*   attb  = (u16*)R9;
  u16*   awb   = (u16*)R10;
  u16*   interb = (u16*)R10;

  auto gemm = [&](int tile, int op, const u16* A, const u16* W,
                  const float* bias, const float* rowBias,
                  const void* resid, int rB, void* Cc, int oB,
                  int Mi, int Ni, int Ki, int ldc,
                  int ntaps, int pad, long wtap,
                  int batch, long ab, long wb, long cb, long rbch) {
#define GL(BM, BN, OPV) gemm_bt<BM, BN, OPV><<<dim3(Ni / BN, Mi / BM, batch), 256, 0, stream>>>( \
      A, W, bias, rowBias, resid, Cc, Ni, Ki, ldc, rB, oB, ntaps, pad, wtap, ab, wb, cb, rbch, zp)
    if (tile == 1) {
      if (op == 0) GL(128, 64, 0); else if (op == 1) GL(128, 64, 1);
      else if (op == 2) GL(128, 64, 2); else GL(128, 64, 3);
    } else {
      if (op == 0) GL(128, 128, 0); else if (op == 1) GL(128, 128, 1);
      else if (op == 2) GL(128, 128, 2); else GL(128, 128, 3);
    }
#undef GL
  };

  zero_kernel<<<1, 128, 0, stream>>>(zp);

  // --- fusion weights first (analytic means over fp32 inputs) ---
  rowmean_all<<<dim3(24, 6), 256, 0, stream>>>(fin[0], fin[1], fin[2], fin[3], fin[4], fin[5], rmb);
  colsum_kernel<<<18, 256, 0, stream>>>(align_w, csb);
  fusion_weights<<<1, 64, 0, stream>>>(rmb, csb, align_b, att_w, att_b, wpT);
  rowbias_kernel<<<24, 256, 0, stream>>>(wpT, align_b, rbias);

  // --- bulk conversion: weights + wplus-scaled interleaved A' + Ea->cc right half ---
  {
    ConvJobs J;
    int idx = 0;
    long total2 = 0;
    auto add = [&](const float* s, u16* d, int n2v, int rl2, int dp2, const float* sc) {
      J.src[idx] = s; J.dst[idx] = d; J.n2[idx] = n2v;
      J.rowLen2[idx] = rl2; J.dstPitch2[idx] = dp2; J.scl[idx] = sc;
      total2 += n2v; ++idx;
    };
    for (int n = 0; n < 6; ++n)                       // A'[row][n*768+k] = wplus*f_n
      add(fin[n], Ap + n * DD, 393216, 96, 576, wpT + n * 8);
    add(Ea, cc + DD, 393216, 96, 192, nullptr);       // cc right half
    add(g1_w, cW_g1, 294912, 294912, 294912, nullptr);
    add(g2_w, cW_g2, 294912, 294912, 294912, nullptr);
    add(fi_w, cW_fi, 294912, 294912, 294912, nullptr);
    add(fo_w, cW_fo, 294912, 294912, 294912, nullptr);
    add(m1_w, cW_m1, 294912, 294912, 294912, nullptr);
    add(m2_w, cW_m2, 294912, 294912, 294912, nullptr);
    add(g3_w, cW_g3, 147456, 147456, 147456, nullptr);
    for (int n = 0; n < 6; ++n)                       // W'[o][n*768+k] = align_w[n][o][k]
      add(align_w + (long)n * 589824, cW_al + n * DD, 73728, 96, 576, nullptr);
    add(g4_w, cW_g4, 73728, 73728, 73728, nullptr);
    add(c1_w, cW_c1, 73728, 73728, 73728, nullptr);
    add(q_w,  cW_q,  73728, 73728, 73728, nullptr);
    add(k_w,  cW_k,  73728, 73728, 73728, nullptr);
    add(tr_w, cW_tr, 73728, 73728, 73728, nullptr);
    add(ao_w, cW_ao, 73728, 73728, 73728, nullptr);
    add(out_w, cW_out, 73728, 73728, 73728, nullptr);
    convert_all<<<(int)((total2 + 255) / 256), 256, 0, stream>>>(J, total2);
  }
  repack_conv<<<(3 * 589824 + 255) / 256, 256, 0, stream>>>(c3_w, w3r, 3);
  repack_conv<<<(5 * 589824 + 255) / 256, 256, 0, stream>>>(c5_w, w5r, 5);

  // --- FeatureAlignment: ONE GEMM, K=4608, writes Et(bf16) into cc left half ---
  gemm(1, 0, Ap, cW_al, nullptr, rbias, nullptr, 0, cc, 1,
       MM, DD, 4608, 1536, 1, 0, 0, 1, 0, 0, 0, 0);

  // --- GatedFusion ---
  gemm(2, 1, cc, cW_g1, g1_b, nullptr, nullptr, 0, o1, 1, MM, 1536, 1536, 1536, 1, 0, 0, 1, 0, 0, 0, 0);
  gemm(2, 1, o1, cW_g2, g2_b, nullptr, nullptr, 0, o2, 1, MM, 1536, 1536, 1536, 1, 0, 0, 1, 0, 0, 0, 0);
  gemm(1, 1, o2, cW_g3, g3_b, nullptr, nullptr, 0, o3, 1, MM, DD, 1536, DD, 1, 0, 0, 1, 0, 0, 0, 0);
  gemm(1, 3, o3, cW_g4, g4_b, nullptr, nullptr, 0, gbuf, 1, MM, DD, DD, DD, 1, 0, 0, 1, 0, 0, 0, 0);
  ef_ln_kernel<<<MM, 256, 0, stream>>>(gbuf, Ea, cc, ln_w, ln_b, xb16);   // x = LN(Ef)

  // --- multi-scale convs; U layout [U5,U3,U1,U5dup] for affine batched hid/ctx ---
  gemm(1, 0, xb16, w5r, c5_b, nullptr, nullptr, 0, U, 1, MM, DD, DD, DD, 5, 2, 589824, 1, 0, 0, 0, 0);
  gemm(1, 0, xb16, w3r, c3_b, nullptr, nullptr, 0, U + MDL, 1, MM, DD, DD, DD, 3, 1, 589824, 1, 0, 0, 0, 0);
  gemm(1, 0, xb16, cW_c1, c1_b, nullptr, nullptr, 0, U + 2 * MDL, 1, MM, DD, DD, DD, 1, 0, 0, 1, 0, 0, 0, 0);
  copy16<<<1536, 256, 0, stream>>>(U, U + 3 * MDL);   // U5dup

  // --- 3 fastformer layers, batched z=3: hid=U+z*MDL, ctx=U+(z+1)*MDL ---
  gemm(2, 0, U,       cW_q, q_b, nullptr, nullptr, 0, qbuf,  1, MM, DD, DD, DD, 1, 0, 0, 3, MDL, 0, MDL, 0);
  gemm(2, 0, U + MDL, cW_k, k_b, nullptr, nullptr, 0, ctxkk, 1, MM, DD, DD, DD, 1, 0, 0, 3, MDL, 0, MDL, 0);
  lin_small<<<3 * MM / 4, 256, 0, stream>>>(qbuf,  qa_w, qa_b, 0.125f, qsf);
  lin_small<<<3 * MM / 4, 256, 0, stream>>>(ctxkk, ka_w, ka_b, 0.125f, ksf);
  scores_softmax<<<3 * MM, 256, 0, stream>>>(qsf, ksf, awb);
  transpose_kernel<<<dim3(24, 16, 24), dim3(32, 8), 0, stream>>>(ctxkk, kkTsf);
  gemm(2, 0, awb, kkTsf, nullptr, nullptr, nullptr, 0, ctxkk, 1, TT, DD, TT, DD,
       1, 0, 0, 24, (long)TT * TT, (long)DD * TT, (long)TT * DD, 0);
  gemm(2, 0, ctxkk, cW_tr, tr_b, nullptr, qbuf, 1, kkTsf, 1, MM, DD, DD, DD, 1, 0, 0, 3, MDL, 0, MDL, MDL);
  gemm(2, 0, kkTsf, cW_ao, ao_b, nullptr, U,    1, attp,  1, MM, DD, DD, DD, 1, 0, 0, 3, MDL, 0, MDL, MDL);
  ln_kernel<<<3 * MM, 256, 0, stream>>>(attp, 1, fln_w, fln_b, nullptr, attb, 0);
  for (int z = 0; z < 3; ++z) {
    gemm(2, 2, attb + (long)z * MDL, cW_fi, fi_b, nullptr, nullptr, 0, interb, 1,
         MM, FFN, DD, FFN, 1, 0, 0, 1, 0, 0, 0, 0);
    gemm(1, 0, interb, cW_fo, fo_b, nullptr, attb + (long)z * MDL, 1, outp + (long)z * MDL, 1,
         MM, DD, FFN, DD, 1, 0, 0, 1, 0, 0, 0, 0);
  }
  ln3sum_kernel<<<MM, 256, 0, stream>>>(outp, fln_w, fln_b, ln_w, ln_b, PnB);

  // --- tail ---
  gemm(2, 2, PnB, cW_m1, m1_b, nullptr, nullptr, 0, interb, 1, MM, FFN, DD, FFN, 1, 0, 0, 1, 0, 0, 0, 0);
  gemm(1, 0, interb, cW_m2, m2_b, nullptr, xb16, 1, Jb, 0, MM, DD, FFN, DD, 1, 0, 0, 1, 0, 0, 0, 0);
  ln_kernel<<<MM, 256, 0, stream>>>(Jb, 0, ln_w, ln_b, nullptr, Jn, 0);
  gemm(1, 0, Jn, cW_out, out_b, nullptr, nullptr, 0, d_out, 0, MM, DD, DD, DD, 1, 0, 0, 1, 0, 0, 0, 0);
}

// Round 2
// 1682.981 us; speedup vs baseline: 1.0921x; 1.0921x over previous
//
#include <hip/hip_runtime.h>
#include <math.h>

// MFFNet forward on MI355X. fp32 in/out; all GEMMs bf16-MFMA with fp32 acc.
// GEMM core now T3 "minimum 2-phase": double-buffered LDS, global_load_lds
// prefetch of tile t+1 issued BEFORE compute of tile t, ONE vmcnt(0)+s_barrier
// per k-step (was 2x __syncthreads with full drain before compute).
// fi/fo FFN GEMMs batched z=3 (interb3 aliases dead R1+R3+R4). ~35 dispatches.

typedef unsigned short u16;
typedef __attribute__((ext_vector_type(8))) short short8;     // 8 bf16
typedef __attribute__((ext_vector_type(8))) unsigned short us8;
typedef __attribute__((ext_vector_type(4))) float floatx4;
typedef unsigned __attribute__((address_space(1))) gu32;
typedef unsigned __attribute__((address_space(3))) lu32;

#define DD 768
#define TT 512
#define BB 8
#define MM 4096      // B*T rows
#define FFN 3072
#define MDL ((long)MM * DD)

__device__ __forceinline__ float b2f(u16 u) {
  union { unsigned u32; float f; } x; x.u32 = ((unsigned)u) << 16; return x.f;
}
__device__ __forceinline__ u16 f2b(float f) {   // round-to-nearest-even
  union { float f; unsigned u; } x; x.f = f;
  unsigned r = x.u + 0x7FFFu + ((x.u >> 16) & 1u);
  return (u16)(r >> 16);
}

// ---------------------------------------------------------------------------
// GEMM: C[M,N] = act(A[M,K] @ W[N,K]^T + bias + rowBias + resid)
// A, W bf16. 4 waves; BK=64; LDS stride 64; DOUBLE-BUFFERED with prefetch.
// ntaps/pad = conv-over-T (zero page OOB). OP: 0=none 1=relu 2=gelu 3=sigmoid.
// ---------------------------------------------------------------------------
template<int BM, int BN, int OP>
__global__ __launch_bounds__(256)
void gemm_bt(const u16* __restrict__ A, const u16* __restrict__ W,
             const float* __restrict__ bias, const float* __restrict__ rowBias,
             const void* __restrict__ residv, void* __restrict__ Cv,
             int N, int K, int ldc, int rBf16, int outBf16,
             int ntaps, int pad, long wtapStride,
             long aBatch, long wBatch, long cBatch, long rBatch,
             const u16* __restrict__ zp)
{
  __shared__ __align__(16) u16 sA[2][BM * 64];
  __shared__ __align__(16) u16 sB[2][BN * 64];
  const int tid  = threadIdx.x;
  const int lane = tid & 63;
  const int wv   = tid >> 6;

  // XCD swizzle: contiguous tile range per XCD
  int gx = gridDim.x, gy = gridDim.y;
  int bn = blockIdx.y * gx + blockIdx.x;
  int Tt = gx * gy;
  if ((Tt & 7) == 0) bn = (bn & 7) * (Tt >> 3) + (bn >> 3);
  const int m0 = (bn / gx) * BM;
  const int n0 = (bn % gx) * BN;
  const u16* Ab  = A + (long)blockIdx.z * aBatch;
  const u16* Wb0 = W + (long)blockIdx.z * wBatch;

  constexpr int NI = (BM == 128 && BN == 128) ? 4 : (BM == 128 ? 2 : 1);
  constexpr int NJ = 4;
  int wr, wc;
  if constexpr (BM == 128 && BN == 128) { wr = (wv >> 1) * 64; wc = (wv & 1) * 64; }
  else if constexpr (BM == 128)          { wr = wv * 32;        wc = 0; }
  else                                    { wr = wv * 16;        wc = 0; }

  floatx4 acc[NI][NJ];
#pragma unroll
  for (int i = 0; i < NI; ++i)
#pragma unroll
    for (int j = 0; j < NJ; ++j) acc[i][j] = (floatx4){0.f, 0.f, 0.f, 0.f};

  const int mrow = lane & 15;
  const int ksub = (lane >> 4) * 8;

  auto STAGE = [&](int tap_, int k0_, int bsel) {
    const int dt = tap_ - pad;
    const u16* Wt = Wb0 + (long)tap_ * wtapStride;
    u16* sAb = &sA[bsel][0];
    u16* sBb = &sB[bsel][0];
#pragma unroll
    for (int it = 0; it < BM / 32; ++it) {
      int slot = it * 256 + tid;
      int row = slot >> 3, col = (slot & 7) * 8;
      int gr = m0 + row;
      int t  = gr & (TT - 1);
      const u16* src = ((unsigned)(t + dt) < (unsigned)TT)
                     ? (Ab + (long)(gr + dt) * K + k0_ + col) : zp;
      __builtin_amdgcn_global_load_lds((const gu32*)src,
                                       (lu32*)((char*)sAb + slot * 16), 16, 0, 0);
    }
#pragma unroll
    for (int it = 0; it < BN / 32; ++it) {
      int slot = it * 256 + tid;
      int row = slot >> 3, col = (slot & 7) * 8;
      const u16* src = Wt + (long)(n0 + row) * K + k0_ + col;
      __builtin_amdgcn_global_load_lds((const gu32*)src,
                                       (lu32*)((char*)sBb + slot * 16), 16, 0, 0);
    }
  };

  const int nk = K >> 6;
  const int nsteps = ntaps * nk;

  // prologue: stage step 0 into buf 0
  STAGE(0, 0, 0);
  asm volatile("s_waitcnt vmcnt(0)" ::: "memory");
  __builtin_amdgcn_s_barrier();

  int tap = 0, k0 = 0, cur = 0;
  for (int s = 0; s < nsteps; ++s) {
    int ntap = tap, nk0 = k0 + 64;
    if (nk0 >= K) { nk0 = 0; ntap = tap + 1; }
    if (s + 1 < nsteps) STAGE(ntap, nk0, cur ^ 1);   // prefetch BEFORE compute
    {
      const u16* sAb = &sA[cur][0];
      const u16* sBb = &sB[cur][0];
#pragma unroll
      for (int kb = 0; kb < 64; kb += 32) {
        short8 af[NI], bfr[NJ];
#pragma unroll
        for (int i = 0; i < NI; ++i)
          af[i] = *(const short8*)(sAb + (wr + i * 16 + mrow) * 64 + kb + ksub);
#pragma unroll
        for (int j = 0; j < NJ; ++j)
          bfr[j] = *(const short8*)(sBb + (wc + j * 16 + mrow) * 64 + kb + ksub);
#pragma unroll
        for (int i = 0; i < NI; ++i)
#pragma unroll
          for (int j = 0; j < NJ; ++j)
            acc[i][j] = __builtin_amdgcn_mfma_f32_16x16x32_bf16(af[i], bfr[j], acc[i][j], 0, 0, 0);
      }
    }
    asm volatile("s_waitcnt vmcnt(0)" ::: "memory");  // next tile landed
    __builtin_amdgcn_s_barrier();                     // all waves: reads done + stage visible
    cur ^= 1; tap = ntap; k0 = nk0;
  }

  // epilogue: C/D layout col=lane&15, row=(lane>>4)*4+reg (m89-verified)
  const int cn = lane & 15;
  const int rq = (lane >> 4) * 4;
  u16*   Ch = (u16*)Cv   + (long)blockIdx.z * cBatch;
  float* Cf = (float*)Cv + (long)blockIdx.z * cBatch;
  const long zr = (long)blockIdx.z * rBatch;
#pragma unroll
  for (int j = 0; j < NJ; ++j) {
    int gn = n0 + wc + j * 16 + cn;
    float bv = bias ? bias[gn] : 0.f;
#pragma unroll
    for (int i = 0; i < NI; ++i) {
#pragma unroll
      for (int r = 0; r < 4; ++r) {
        int gm = m0 + wr + i * 16 + rq + r;
        long idx = (long)gm * ldc + gn;
        float v = acc[i][j][r] + bv;
        if (rowBias) v += rowBias[(gm >> 9) * N + gn];
        if (residv)
          v += rBf16 ? b2f(((const u16*)residv)[idx + zr]) : ((const float*)residv)[idx + zr];
        if (OP == 1) v = fmaxf(v, 0.f);
        if (OP == 2) v = 0.5f * v * (1.f + erff(v * 0.70710678118654752440f));
        if (OP == 3) v = 1.f / (1.f + expf(-v));
        if (outBf16) Ch[idx] = f2b(v);
        else Cf[idx] = v;
      }
    }
  }
}

// ---------------------------------------------------------------------------
// bulk fp32 -> bf16 conversion with row remap (pitch) + per-b scale.
// ---------------------------------------------------------------------------
#define NJOBS 27
struct ConvJobs {
  const float* src[NJOBS];
  u16* dst[NJOBS];
  int n2[NJOBS];         // pairs (8 floats) per job
  int rowLen2[NJOBS];    // pairs per source row
  int dstPitch2[NJOBS];  // dst row pitch in pairs
  const float* scl[NJOBS];  // per-(row>>9) scale or null
};
__global__ void convert_all(ConvJobs J, long total2)
{
  long g = (long)blockIdx.x * 256 + threadIdx.x;
  if (g >= total2) return;
  int j = 0; long off = g;
  while (off >= J.n2[j]) { off -= J.n2[j]; ++j; }
  long row = off / J.rowLen2[j];
  long c2  = off - row * J.rowLen2[j];
  const float4* s = (const float4*)J.src[j] + off * 2;
  float4 x = s[0], y = s[1];
  float sc = J.scl[j] ? J.scl[j][row >> 9] : 1.f;
  us8 h;
  h[0] = f2b(x.x * sc); h[1] = f2b(x.y * sc); h[2] = f2b(x.z * sc); h[3] = f2b(x.w * sc);
  h[4] = f2b(y.x * sc); h[5] = f2b(y.y * sc); h[6] = f2b(y.z * sc); h[7] = f2b(y.w * sc);
  *(us8*)(J.dst[j] + (row * (long)J.dstPitch2[j] + c2) * 8) = h;
}

__global__ void zero_kernel(u16* zp) { if (threadIdx.x < 128) zp[threadIdx.x] = 0; }

__global__ void copy16(const u16* __restrict__ s, u16* __restrict__ d)
{
  long g = (long)blockIdx.x * 256 + threadIdx.x;
  *(us8*)(d + g * 8) = *(const us8*)(s + g * 8);
}

// LayerNorm over D=768; input fp32 or bf16; out fp32 or bf16
__global__ void ln_kernel(const void* __restrict__ x, int xBf16,
                          const float* __restrict__ w, const float* __restrict__ b,
                          float* __restrict__ y32, u16* __restrict__ y16, int accum)
{
  const int row = blockIdx.x;
  const int tid = threadIdx.x;
  __shared__ float rs[256], rq[256];
  float v[3];
  long base = (long)row * DD;
  float s = 0.f, q = 0.f;
#pragma unroll
  for (int i = 0; i < 3; ++i) {
    int c = tid + i * 256;
    float t = xBf16 ? b2f(((const u16*)x)[base + c]) : ((const float*)x)[base + c];
    v[i] = t; s += t; q += t * t;
  }
  rs[tid] = s; rq[tid] = q; __syncthreads();
  for (int st = 128; st > 0; st >>= 1) {
    if (tid < st) { rs[tid] += rs[tid + st]; rq[tid] += rq[tid + st]; }
    __syncthreads();
  }
  float mean = rs[0] * (1.f / DD);
  float var  = fmaxf(rq[0] * (1.f / DD) - mean * mean, 0.f);
  float rstd = rsqrtf(var + 1e-12f);
#pragma unroll
  for (int i = 0; i < 3; ++i) {
    int c = tid + i * 256;
    float o = ((v[i] - mean) * rstd) * w[c] + b[c];
    if (y32) { if (accum) y32[base + c] += o; else y32[base + c] = o; }
    if (y16) {
      if (accum && !y32) y16[base + c] = f2b(b2f(y16[base + c]) + o);
      else y16[base + c] = f2b(o);
    }
  }
}

// Ef = g*Ea + (1-g)*Et, then LN(Ef) -> bf16. Et read from cc left half (pitch 1536).
__global__ void ef_ln_kernel(const u16* __restrict__ g, const float* __restrict__ Ea,
                             const u16* __restrict__ EtC,
                             const float* __restrict__ w, const float* __restrict__ b,
                             u16* __restrict__ xo)
{
  const int row = blockIdx.x;
  const int tid = threadIdx.x;
  __shared__ float rs[256], rq[256];
  float v[3];
  float s = 0.f, q = 0.f;
#pragma unroll
  for (int i = 0; i < 3; ++i) {
    int c = tid + i * 256;
    float gv = b2f(g[(long)row * DD + c]);
    float et = b2f(EtC[(long)row * 1536 + c]);
    float e  = gv * Ea[(long)row * DD + c] + (1.f - gv) * et;
    v[i] = e; s += e; q += e * e;
  }
  rs[tid] = s; rq[tid] = q; __syncthreads();
  for (int st = 128; st > 0; st >>= 1) {
    if (tid < st) { rs[tid] += rs[tid + st]; rq[tid] += rq[tid + st]; }
    __syncthreads();
  }
  float mean = rs[0] * (1.f / DD);
  float var  = fmaxf(rq[0] * (1.f / DD) - mean * mean, 0.f);
  float rstd = rsqrtf(var + 1e-12f);
#pragma unroll
  for (int i = 0; i < 3; ++i) {
    int c = tid + i * 256;
    xo[(long)row * DD + c] = f2b(((v[i] - mean) * rstd) * w[c] + b[c]);
  }
}

// Pn = LN( sum_z LN(outp[z], fln) , ln ). Sum in f32.
__global__ void ln3sum_kernel(const u16* __restrict__ o,
                              const float* __restrict__ fw, const float* __restrict__ fb,
                              const float* __restrict__ lw, const float* __restrict__ lb,
                              u16* __restrict__ Pn)
{
  const int row = blockIdx.x;
  const int tid = threadIdx.x;
  __shared__ float rs[256], rq[256];
  float v[3][3], mz[3], rz[3];
  for (int z = 0; z < 3; ++z) {
    long base = (long)z * MDL + (long)row * DD;
    float s = 0.f, q = 0.f;
#pragma unroll
    for (int i = 0; i < 3; ++i) {
      int c = tid + i * 256;
      float t = b2f(o[base + c]);
      v[z][i] = t; s += t; q += t * t;
    }
    rs[tid] = s; rq[tid] = q; __syncthreads();
    for (int st = 128; st > 0; st >>= 1) {
      if (tid < st) { rs[tid] += rs[tid + st]; rq[tid] += rq[tid + st]; }
      __syncthreads();
    }
    float mean = rs[0] * (1.f / DD);
    float var  = fmaxf(rq[0] * (1.f / DD) - mean * mean, 0.f);
    mz[z] = mean; rz[z] = rsqrtf(var + 1e-12f);
    __syncthreads();
  }
  float p[3];
  float s = 0.f, q = 0.f;
#pragma unroll
  for (int i = 0; i < 3; ++i) {
    int c = tid + i * 256;
    float pv = 0.f;
#pragma unroll
    for (int z = 0; z < 3; ++z) pv += (v[z][i] - mz[z]) * rz[z];
    pv = pv * fw[c] + 3.f * fb[c];
    p[i] = pv; s += pv; q += pv * pv;
  }
  rs[tid] = s; rq[tid] = q; __syncthreads();
  for (int st = 128; st > 0; st >>= 1) {
    if (tid < st) { rs[tid] += rs[tid + st]; rq[tid] += rq[tid + st]; }
    __syncthreads();
  }
  float mean = rs[0] * (1.f / DD);
  float var  = fmaxf(rq[0] * (1.f / DD) - mean * mean, 0.f);
  float rstd = rsqrtf(var + 1e-12f);
#pragma unroll
  for (int i = 0; i < 3; ++i) {
    int c = tid + i * 256;
    Pn[(long)row * DD + c] = f2b(((p[i] - mean) * rstd) * lw[c] + lb[c]);
  }
}

// all 6 streams' rowmeans in one launch
__global__ void rowmean_all(const float* f0, const float* f1, const float* f2,
                            const float* f3, const float* f4, const float* f5,
                            float* __restrict__ rm)
{
  const float* fs[6] = {f0, f1, f2, f3, f4, f5};
  int n = blockIdx.y;
  int b = blockIdx.x / 3, chunk = blockIdx.x % 3;
  int d = chunk * 256 + threadIdx.x;
  const float* base = fs[n] + (long)b * TT * DD + d;
  float s = 0.f;
  for (int t = 0; t < TT; ++t) s += base[(long)t * DD];
  rm[((long)n * BB + b) * DD + d] = s * (1.f / TT);
}

__global__ void colsum_kernel(const float* __restrict__ w, float* __restrict__ cs)
{
  int n = blockIdx.x / 3, chunk = blockIdx.x % 3;
  int e = chunk * 256 + threadIdx.x;
  const float* base = w + (long)n * DD * DD + e;
  float s = 0.f;
  for (int d = 0; d < DD; ++d) s += base[(long)d * DD];
  cs[n * DD + e] = s;
}

__global__ void fusion_weights(const float* __restrict__ rm, const float* __restrict__ cs,
                               const float* __restrict__ align_b,
                               const float* __restrict__ aw, const float* __restrict__ ab,
                               float* __restrict__ wpT)
{
  __shared__ float msh[48];
  int tid = threadIdx.x;
  if (tid < 48) {
    int b = tid / 6, n = tid % 6;
    const float* r = rm + ((long)n * BB + b) * DD;
    const float* c = cs + n * DD;
    float dot = 0.f, bs = 0.f;
    for (int e = 0; e < DD; ++e) dot += r[e] * c[e];
    for (int d = 0; d < DD; ++d) bs += align_b[n * DD + d];
    msh[b * 6 + n] = (dot + bs) * (1.f / DD);
  }
  __syncthreads();
  if (tid < BB) {
    int b = tid;
    float z[6];
#pragma unroll
    for (int n = 0; n < 6; ++n) {
      float s = ab[n];
#pragma unroll
      for (int j = 0; j < 6; ++j)
        s += (aw[n * 12 + j] + aw[n * 12 + 6 + j]) * msh[b * 6 + j];
      z[n] = fmaxf(s, 0.f);
    }
    float mx = z[0];
#pragma unroll
    for (int n = 1; n < 6; ++n) mx = fmaxf(mx, z[n]);
    float se = 0.f, e[6];
#pragma unroll
    for (int n = 0; n < 6; ++n) { e[n] = expf(z[n] - mx); se += e[n]; }
#pragma unroll
    for (int n = 0; n < 6; ++n) wpT[n * 8 + b] = e[n] / se + (1.f / 6.f);
  }
}

// rb[b,d] = sum_n wplus[b,n] * align_b[n,d]
__global__ void rowbias_kernel(const float* __restrict__ wpT, const float* __restrict__ ab,
                               float* __restrict__ rb)
{
  int b = blockIdx.x / 3;
  int d = (blockIdx.x % 3) * 256 + threadIdx.x;
  float s = 0.f;
#pragma unroll
  for (int n = 0; n < 6; ++n) s += wpT[n * 8 + b] * ab[n * DD + d];
  rb[b * DD + d] = s;
}

// conv weight [O,I,KT] fp32 -> [KT][O][I] bf16
__global__ void repack_conv(const float* __restrict__ src, u16* __restrict__ dst, int KT)
{
  long e = (long)blockIdx.x * 256 + threadIdx.x;
  if (e >= (long)KT * DD * DD) return;
  int k = (int)(e / (DD * DD));
  int rem = (int)(e - (long)k * DD * DD);
  int o = rem / DD, i = rem % DD;
  dst[e] = f2b(src[((long)o * DD + i) * KT + k]);
}

// out[row,h] = (X[row,:] . Wt[h,:] + bias[h]) * scale ; H=12, X bf16
__global__ void lin_small(const u16* __restrict__ X, const float* __restrict__ Wt,
                          const float* __restrict__ bias, float scale,
                          float* __restrict__ out)
{
  int row = blockIdx.x * 4 + (threadIdx.x >> 6);
  int lane = threadIdx.x & 63;
  float acc[12];
#pragma unroll
  for (int h = 0; h < 12; ++h) acc[h] = 0.f;
  for (int k = lane; k < DD; k += 64) {
    float xv = b2f(X[(long)row * DD + k]);
#pragma unroll
    for (int h = 0; h < 12; ++h) acc[h] += xv * Wt[h * DD + k];
  }
#pragma unroll
  for (int h = 0; h < 12; ++h)
    for (int off = 32; off > 0; off >>= 1) acc[h] += __shfl_down(acc[h], off);
  if (lane == 0) {
#pragma unroll
    for (int h = 0; h < 12; ++h)
      out[(long)row * 12 + h] = (acc[h] + bias[h]) * scale;
  }
}

__global__ void scores_softmax(const float* __restrict__ qs, const float* __restrict__ ks,
                               u16* __restrict__ aw)
{
  int bs = blockIdx.x;            // global (z*8+b)*512+s
  int b = bs >> 9;
  int tid = threadIdx.x;
  __shared__ float qsh[12];
  __shared__ float red[256];
  if (tid < 12) qsh[tid] = qs[(long)bs * 12 + tid];
  __syncthreads();
  float sc[2];
#pragma unroll
  for (int p = 0; p < 2; ++p) {
    int c = tid + p * 256;
    const float* kr = ks + (long)(b * 512 + c) * 12;
    float v = 0.f;
#pragma unroll
    for (int h = 0; h < 12; ++h) v += qsh[h] * kr[h];
    sc[p] = v;
  }
  red[tid] = fmaxf(sc[0], sc[1]); __syncthreads();
  for (int st = 128; st > 0; st >>= 1) {
    if (tid < st) red[tid] = fmaxf(red[tid], red[tid + st]);
    __syncthreads();
  }
  float mx = red[0]; __syncthreads();
  float e0 = expf(sc[0] - mx), e1 = expf(sc[1] - mx);
  red[tid] = e0 + e1; __syncthreads();
  for (int st = 128; st > 0; st >>= 1) {
    if (tid < st) red[tid] += red[tid + st];
    __syncthreads();
  }
  float inv = 1.f / red[0];
  aw[(long)bs * 512 + tid]       = f2b(e0 * inv);
  aw[(long)bs * 512 + tid + 256] = f2b(e1 * inv);
}

__global__ void transpose_kernel(const u16* __restrict__ in, u16* __restrict__ out)
{
  int b = blockIdx.z;
  const u16* ib = in + (long)b * TT * DD;
  u16* ob = out + (long)b * TT * DD;
  __shared__ u16 tile[32][33];
  int c0 = blockIdx.x * 32;   // d
  int r0 = blockIdx.y * 32;   // t
  int tx = threadIdx.x, ty = threadIdx.y;
#pragma unroll
  for (int i = 0; i < 4; ++i)
    tile[ty + 8 * i][tx] = ib[(long)(r0 + ty + 8 * i) * DD + c0 + tx];
  __syncthreads();
#pragma unroll
  for (int i = 0; i < 4; ++i)
    ob[(long)(c0 + ty + 8 * i) * TT + r0 + tx] = tile[tx][ty + 8 * i];
}

// ---------------------------------------------------------------------------
extern "C" void kernel_launch(void* const* d_in, const int* in_sizes, int n_in,
                              void* d_out, int out_size, void* d_ws, size_t ws_size,
                              hipStream_t stream)
{
  (void)in_sizes; (void)n_in; (void)out_size; (void)ws_size;
  const float* fin[6];
  for (int i = 0; i < 6; ++i) fin[i] = (const float*)d_in[i];
  const float* Ea      = (const float*)d_in[6];
  const float* align_w = (const float*)d_in[7];
  const float* align_b = (const float*)d_in[8];
  const float* att_w   = (const float*)d_in[9];
  const float* att_b   = (const float*)d_in[10];
  const float* g1_w = (const float*)d_in[11]; const float* g1_b = (const float*)d_in[12];
  const float* g2_w = (const float*)d_in[13]; const float* g2_b = (const float*)d_in[14];
  const float* g3_w = (const float*)d_in[15]; const float* g3_b = (const float*)d_in[16];
  const float* g4_w = (const float*)d_in[17]; const float* g4_b = (const float*)d_in[18];
  const float* ln_w = (const float*)d_in[19]; const float* ln_b = (const float*)d_in[20];
  const float* c1_w = (const float*)d_in[21]; const float* c1_b = (const float*)d_in[22];
  const float* c3_w = (const float*)d_in[23]; const float* c3_b = (const float*)d_in[24];
  const float* c5_w = (const float*)d_in[25]; const float* c5_b = (const float*)d_in[26];
  const float* q_w  = (const float*)d_in[27]; const float* q_b  = (const float*)d_in[28];
  const float* qa_w = (const float*)d_in[29]; const float* qa_b = (const float*)d_in[30];
  const float* k_w  = (const float*)d_in[31]; const float* k_b  = (const float*)d_in[32];
  const float* ka_w = (const float*)d_in[33]; const float* ka_b = (const float*)d_in[34];
  const float* tr_w = (const float*)d_in[35]; const float* tr_b = (const float*)d_in[36];
  const float* ao_w = (const float*)d_in[37]; const float* ao_b = (const float*)d_in[38];
  const float* fln_w = (const float*)d_in[39]; const float* fln_b = (const float*)d_in[40];
  const float* fi_w = (const float*)d_in[41]; const float* fi_b = (const float*)d_in[42];
  const float* fo_w = (const float*)d_in[43]; const float* fo_b = (const float*)d_in[44];
  const float* m1_w = (const float*)d_in[45]; const float* m1_b = (const float*)d_in[46];
  const float* m2_w = (const float*)d_in[47]; const float* m2_b = (const float*)d_in[48];
  const float* out_w = (const float*)d_in[49]; const float* out_b = (const float*)d_in[50];

  char* ws = (char*)d_ws;
  size_t off = 0;
  auto alloc = [&](size_t bytes) -> char* {
    char* p = ws + off;
    off += bytes;
    off = (off + 255) & ~(size_t)255;
    return p;
  };

  // small scratch
  u16*   zp    = (u16*)alloc(256);
  float* rmb   = (float*)alloc(6L * BB * DD * 4);
  float* csb   = (float*)alloc(6L * DD * 4);
  float* wpT   = (float*)alloc(48 * 4);
  float* rbias = (float*)alloc((long)BB * DD * 4);
  float* qsf   = (float*)alloc(3L * MM * 12 * 4);
  float* ksf   = (float*)alloc(3L * MM * 12 * 4);

  // bf16 weight cache (55.4 MB); cW_al is the K-concatenated align weight
  u16* Wc = (u16*)alloc(27721728L * 2);
  u16* cW_g1   = Wc;
  u16* cW_g2   = Wc + 2359296L;
  u16* cW_fi   = Wc + 4718592L;
  u16* cW_fo   = Wc + 7077888L;
  u16* cW_m1   = Wc + 9437184L;
  u16* cW_m2   = Wc + 11796480L;
  u16* cW_g3   = Wc + 14155776L;
  u16* cW_al   = Wc + 15335424L;
  u16* cW_g4   = Wc + 18874368L;
  u16* cW_c1   = Wc + 19464192L;
  u16* cW_q    = Wc + 20054016L;
  u16* cW_k    = Wc + 20643840L;
  u16* cW_tr   = Wc + 21233664L;
  u16* cW_ao   = Wc + 21823488L;
  u16* cW_out  = Wc + 22413312L;
  u16* w3r     = Wc + 23003136L;
  u16* w5r     = Wc + 24772608L;

  // big aliased regions (~184 MB); R1,R3,R4 are CONTIGUOUS (sizes 256-aligned)
  char* R1 = alloc((long)MM * 4608 * 2);  // A' -> qbuf -> [interb3 head] -> Jb
  char* R3 = alloc(MDL * 8);              // cc+o1 -> ctxkk -> [interb3] -> Pn+Jn
  char* R4 = alloc(MDL * 8);              // o2+o3+gb -> kkTsf -> [interb3 tail]
  char* R5 = alloc(MDL * 2);              // xb16 (persistent)
  char* R6 = alloc(MDL * 8);              // U = [U5,U3,U1,U5dup]
  char* R8 = alloc(MDL * 6);              // attp -> outp (3 layers)
  char* R9 = alloc(MDL * 6);              // attb (3 layers)
  char* R10 = alloc((long)MM * FFN * 2);  // awb -> interb (m1/m2)

  u16*   Ap    = (u16*)R1;
  u16*   qbuf  = (u16*)R1;
  float* Jb    = (float*)R1;
  u16*   interb3 = (u16*)R1;               // 75.5 MB spans R1+R3+R4 (fi->fo only)
  u16*   cc    = (u16*)R3;                 // [MM][1536]: left=Et(b16), right=Ea(b16)
  u16*   o1    = (u16*)R3 + 2 * MDL;
  u16*   ctxkk = (u16*)R3;
  u16*   PnB   = (u16*)R3;
  u16*   Jn    = (u16*)R3 + MDL;
  u16*   o2    = (u16*)R4;
  u16*   o3    = (u16*)R4 + 2 * MDL;
  u16*   gbuf  = (u16*)R4 + 3 * MDL;
  u16*   kkTsf = (u16*)R4;
  u16*   xb16  = (u16*)R5;
  u16*   U     = (u16*)R6;
  u16*   attp  = (u16*)R8;
  u16*   outp  = (u16*)R8;
  u16*   attb  = (u16*)R9;
  u16*   awb   = (u16*)R10;
  u16*   interb = (u16*)R10;

  auto gemm = [&](int tile, int op, const u16* A, const u16* W,
                  const float* bias, const float* rowBias,
                  const void* resid, int rB, void* Cc, int oB,
                  int Mi, int Ni, int Ki, int ldc,
                  int ntaps, int pad, long wtap,
                  int batch, long ab, long wb, long cb, long rbch) {
#define GL(BM, BN, OPV) gemm_bt<BM, BN, OPV><<<dim3(Ni / BN, Mi / BM, batch), 256, 0, stream>>>( \
      A, W, bias, rowBias, resid, Cc, Ni, Ki, ldc, rB, oB, ntaps, pad, wtap, ab, wb, cb, rbch, zp)
    if (tile == 1) {
      if (op == 0) GL(128, 64, 0); else if (op == 1) GL(128, 64, 1);
      else if (op == 2) GL(128, 64, 2); else GL(128, 64, 3);
    } else {
      if (op == 0) GL(128, 128, 0); else if (op == 1) GL(128, 128, 1);
      else if (op == 2) GL(128, 128, 2); else GL(128, 128, 3);
    }
#undef GL
  };

  zero_kernel<<<1, 128, 0, stream>>>(zp);

  // --- fusion weights first (analytic means over fp32 inputs) ---
  rowmean_all<<<dim3(24, 6), 256, 0, stream>>>(fin[0], fin[1], fin[2], fin[3], fin[4], fin[5], rmb);
  colsum_kernel<<<18, 256, 0, stream>>>(align_w, csb);
  fusion_weights<<<1, 64, 0, stream>>>(rmb, csb, align_b, att_w, att_b, wpT);
  rowbias_kernel<<<24, 256, 0, stream>>>(wpT, align_b, rbias);

  // --- bulk conversion: weights + wplus-scaled interleaved A' + Ea->cc right half ---
  {
    ConvJobs J;
    int idx = 0;
    long total2 = 0;
    auto add = [&](const float* s, u16* d, int n2v, int rl2, int dp2, const float* sc) {
      J.src[idx] = s; J.dst[idx] = d; J.n2[idx] = n2v;
      J.rowLen2[idx] = rl2; J.dstPitch2[idx] = dp2; J.scl[idx] = sc;
      total2 += n2v; ++idx;
    };
    for (int n = 0; n < 6; ++n)                       // A'[row][n*768+k] = wplus*f_n
      add(fin[n], Ap + n * DD, 393216, 96, 576, wpT + n * 8);
    add(Ea, cc + DD, 393216, 96, 192, nullptr);       // cc right half
    add(g1_w, cW_g1, 294912, 294912, 294912, nullptr);
    add(g2_w, cW_g2, 294912, 294912, 294912, nullptr);
    add(fi_w, cW_fi, 294912, 294912, 294912, nullptr);
    add(fo_w, cW_fo, 294912, 294912, 294912, nullptr);
    add(m1_w, cW_m1, 294912, 294912, 294912, nullptr);
    add(m2_w, cW_m2, 294912, 294912, 294912, nullptr);
    add(g3_w, cW_g3, 147456, 147456, 147456, nullptr);
    for (int n = 0; n < 6; ++n)                       // W'[o][n*768+k] = align_w[n][o][k]
      add(align_w + (long)n * 589824, cW_al + n * DD, 73728, 96, 576, nullptr);
    add(g4_w, cW_g4, 73728, 73728, 73728, nullptr);
    add(c1_w, cW_c1, 73728, 73728, 73728, nullptr);
    add(q_w,  cW_q,  73728, 73728, 73728, nullptr);
    add(k_w,  cW_k,  73728, 73728, 73728, nullptr);
    add(tr_w, cW_tr, 73728, 73728, 73728, nullptr);
    add(ao_w, cW_ao, 73728, 73728, 73728, nullptr);
    add(out_w, cW_out, 73728, 73728, 73728, nullptr);
    convert_all<<<(int)((total2 + 255) / 256), 256, 0, stream>>>(J, total2);
  }
  repack_conv<<<(3 * 589824 + 255) / 256, 256, 0, stream>>>(c3_w, w3r, 3);
  repack_conv<<<(5 * 589824 + 255) / 256, 256, 0, stream>>>(c5_w, w5r, 5);

  // --- FeatureAlignment: ONE GEMM, K=4608, writes Et(bf16) into cc left half ---
  gemm(1, 0, Ap, cW_al, nullptr, rbias, nullptr, 0, cc, 1,
       MM, DD, 4608, 1536, 1, 0, 0, 1, 0, 0, 0, 0);

  // --- GatedFusion ---
  gemm(1, 1, cc, cW_g1, g1_b, nullptr, nullptr, 0, o1, 1, MM, 1536, 1536, 1536, 1, 0, 0, 1, 0, 0, 0, 0);
  gemm(1, 1, o1, cW_g2, g2_b, nullptr, nullptr, 0, o2, 1, MM, 1536, 1536, 1536, 1, 0, 0, 1, 0, 0, 0, 0);
  gemm(1, 1, o2, cW_g3, g3_b, nullptr, nullptr, 0, o3, 1, MM, DD, 1536, DD, 1, 0, 0, 1, 0, 0, 0, 0);
  gemm(1, 3, o3, cW_g4, g4_b, nullptr, nullptr, 0, gbuf, 1, MM, DD, DD, DD, 1, 0, 0, 1, 0, 0, 0, 0);
  ef_ln_kernel<<<MM, 256, 0, stream>>>(gbuf, Ea, cc, ln_w, ln_b, xb16);   // x = LN(Ef)

  // --- multi-scale convs; U layout [U5,U3,U1,U5dup] ---
  gemm(1, 0, xb16, w5r, c5_b, nullptr, nullptr, 0, U, 1, MM, DD, DD, DD, 5, 2, 589824, 1, 0, 0, 0, 0);
  gemm(1, 0, xb16, w3r, c3_b, nullptr, nullptr, 0, U + MDL, 1, MM, DD, DD, DD, 3, 1, 589824, 1, 0, 0, 0, 0);
  gemm(1, 0, xb16, cW_c1, c1_b, nullptr, nullptr, 0, U + 2 * MDL, 1, MM, DD, DD, DD, 1, 0, 0, 1, 0, 0, 0, 0);
  copy16<<<1536, 256, 0, stream>>>(U, U + 3 * MDL);   // U5dup

  // --- 3 fastformer layers, batched z=3: hid=U+z*MDL, ctx=U+(z+1)*MDL ---
  gemm(1, 0, U,       cW_q, q_b, nullptr, nullptr, 0, qbuf,  1, MM, DD, DD, DD, 1, 0, 0, 3, MDL, 0, MDL, 0);
  gemm(1, 0, U + MDL, cW_k, k_b, nullptr, nullptr, 0, ctxkk, 1, MM, DD, DD, DD, 1, 0, 0, 3, MDL, 0, MDL, 0);
  lin_small<<<3 * MM / 4, 256, 0, stream>>>(qbuf,  qa_w, qa_b, 0.125f, qsf);
  lin_small<<<3 * MM / 4, 256, 0, stream>>>(ctxkk, ka_w, ka_b, 0.125f, ksf);
  scores_softmax<<<3 * MM, 256, 0, stream>>>(qsf, ksf, awb);
  transpose_kernel<<<dim3(24, 16, 24), dim3(32, 8), 0, stream>>>(ctxkk, kkTsf);
  gemm(1, 0, awb, kkTsf, nullptr, nullptr, nullptr, 0, ctxkk, 1, TT, DD, TT, DD,
       1, 0, 0, 24, (long)TT * TT, (long)DD * TT, (long)TT * DD, 0);
  gemm(1, 0, ctxkk, cW_tr, tr_b, nullptr, qbuf, 1, kkTsf, 1, MM, DD, DD, DD, 1, 0, 0, 3, MDL, 0, MDL, MDL);
  gemm(1, 0, kkTsf, cW_ao, ao_b, nullptr, U,    1, attp,  1, MM, DD, DD, DD, 1, 0, 0, 3, MDL, 0, MDL, MDL);
  ln_kernel<<<3 * MM, 256, 0, stream>>>(attp, 1, fln_w, fln_b, nullptr, attb, 0);
  // FFN: batched z=3 (interb3 spans dead R1+R3+R4; qbuf/ctxkk/kkTsf all consumed)
  gemm(2, 2, attb, cW_fi, fi_b, nullptr, nullptr, 0, interb3, 1,
       MM, FFN, DD, FFN, 1, 0, 0, 3, MDL, 0, (long)MM * FFN, 0);
  gemm(2, 0, interb3, cW_fo, fo_b, nullptr, attb, 1, outp, 1,
       MM, DD, FFN, DD, 1, 0, 0, 3, (long)MM * FFN, 0, MDL, MDL);
  ln3sum_kernel<<<MM, 256, 0, stream>>>(outp, fln_w, fln_b, ln_w, ln_b, PnB);

  // --- tail ---
  gemm(2, 2, PnB, cW_m1, m1_b, nullptr, nullptr, 0, interb, 1, MM, FFN, DD, FFN, 1, 0, 0, 1, 0, 0, 0, 0);
  gemm(1, 0, interb, cW_m2, m2_b, nullptr, xb16, 1, Jb, 0, MM, DD, FFN, DD, 1, 0, 0, 1, 0, 0, 0, 0);
  ln_kernel<<<MM, 256, 0, stream>>>(Jb, 0, ln_w, ln_b, nullptr, Jn, 0);
  gemm(1, 0, Jn, cW_out, out_b, nullptr, nullptr, 0, d_out, 0, MM, DD, DD, DD, 1, 0, 0, 1, 0, 0, 0, 0);
}

// Round 3
// 1482.740 us; speedup vs baseline: 1.2396x; 1.1350x over previous
//
#include <hip/hip_runtime.h>
#include <math.h>

// MFFNet forward on MI355X. fp32 in/out; all GEMMs bf16-MFMA with fp32 acc.
// GEMM core: T3 2-phase double-buffered LDS with prefetch-before-compute,
// ONE vmcnt(0)+s_barrier per k-step, and T2 XOR chunk-swizzle applied
// both-sides (pre-swizzled global_load_lds SOURCE + swizzled ds_read) to kill
// the 16-way LDS bank conflict of the 128B-stride row-major tile.
// fi/fo FFN GEMMs batched z=3. ~35 dispatches.

typedef unsigned short u16;
typedef __attribute__((ext_vector_type(8))) short short8;     // 8 bf16
typedef __attribute__((ext_vector_type(8))) unsigned short us8;
typedef __attribute__((ext_vector_type(4))) float floatx4;
typedef unsigned __attribute__((address_space(1))) gu32;
typedef unsigned __attribute__((address_space(3))) lu32;

#define DD 768
#define TT 512
#define BB 8
#define MM 4096      // B*T rows
#define FFN 3072
#define MDL ((long)MM * DD)

__device__ __forceinline__ float b2f(u16 u) {
  union { unsigned u32; float f; } x; x.u32 = ((unsigned)u) << 16; return x.f;
}
__device__ __forceinline__ u16 f2b(float f) {   // round-to-nearest-even
  union { float f; unsigned u; } x; x.f = f;
  unsigned r = x.u + 0x7FFFu + ((x.u >> 16) & 1u);
  return (u16)(r >> 16);
}

// ---------------------------------------------------------------------------
// GEMM: C[M,N] = act(A[M,K] @ W[N,K]^T + bias + rowBias + resid)
// A, W bf16. 4 waves; BK=64; LDS stride 64 els (128 B); double-buffered.
// T2 swizzle: LDS row's 8x16B chunks permuted by chunk^=(row&7), applied on
// the global source during staging and on the ds_read address (rule #21:
// both-sides same involution; LDS dest of global_load_lds stays linear).
// ntaps/pad = conv-over-T (zero page OOB). OP: 0=none 1=relu 2=gelu 3=sigmoid.
// ---------------------------------------------------------------------------
template<int BM, int BN, int OP>
__global__ __launch_bounds__(256)
void gemm_bt(const u16* __restrict__ A, const u16* __restrict__ W,
             const float* __restrict__ bias, const float* __restrict__ rowBias,
             const void* __restrict__ residv, void* __restrict__ Cv,
             int N, int K, int ldc, int rBf16, int outBf16,
             int ntaps, int pad, long wtapStride,
             long aBatch, long wBatch, long cBatch, long rBatch,
             const u16* __restrict__ zp)
{
  __shared__ __align__(16) u16 sA[2][BM * 64];
  __shared__ __align__(16) u16 sB[2][BN * 64];
  const int tid  = threadIdx.x;
  const int lane = tid & 63;
  const int wv   = tid >> 6;

  // XCD swizzle: contiguous tile range per XCD
  int gx = gridDim.x, gy = gridDim.y;
  int bn = blockIdx.y * gx + blockIdx.x;
  int Tt = gx * gy;
  if ((Tt & 7) == 0) bn = (bn & 7) * (Tt >> 3) + (bn >> 3);
  const int m0 = (bn / gx) * BM;
  const int n0 = (bn % gx) * BN;
  const u16* Ab  = A + (long)blockIdx.z * aBatch;
  const u16* Wb0 = W + (long)blockIdx.z * wBatch;

  constexpr int NI = (BM == 128 && BN == 128) ? 4 : (BM == 128 ? 2 : 1);
  constexpr int NJ = 4;
  int wr, wc;
  if constexpr (BM == 128 && BN == 128) { wr = (wv >> 1) * 64; wc = (wv & 1) * 64; }
  else if constexpr (BM == 128)          { wr = wv * 32;        wc = 0; }
  else                                    { wr = wv * 16;        wc = 0; }

  floatx4 acc[NI][NJ];
#pragma unroll
  for (int i = 0; i < NI; ++i)
#pragma unroll
    for (int j = 0; j < NJ; ++j) acc[i][j] = (floatx4){0.f, 0.f, 0.f, 0.f};

  const int mrow = lane & 15;
  const int ksub = (lane >> 4) * 8;

  auto STAGE = [&](int tap_, int k0_, int bsel) {
    const int dt = tap_ - pad;
    const u16* Wt = Wb0 + (long)tap_ * wtapStride;
    u16* sAb = &sA[bsel][0];
    u16* sBb = &sB[bsel][0];
#pragma unroll
    for (int it = 0; it < BM / 32; ++it) {
      int slot = it * 256 + tid;
      int row = slot >> 3;
      int col = ((slot ^ row) & 7) * 8;        // T2: source chunk ^= row&7
      int gr = m0 + row;
      int t  = gr & (TT - 1);
      const u16* src = ((unsigned)(t + dt) < (unsigned)TT)
                     ? (Ab + (long)(gr + dt) * K + k0_ + col) : zp;
      __builtin_amdgcn_global_load_lds((const gu32*)src,
                                       (lu32*)((char*)sAb + slot * 16), 16, 0, 0);
    }
#pragma unroll
    for (int it = 0; it < BN / 32; ++it) {
      int slot = it * 256 + tid;
      int row = slot >> 3;
      int col = ((slot ^ row) & 7) * 8;        // T2: source chunk ^= row&7
      const u16* src = Wt + (long)(n0 + row) * K + k0_ + col;
      __builtin_amdgcn_global_load_lds((const gu32*)src,
                                       (lu32*)((char*)sBb + slot * 16), 16, 0, 0);
    }
  };

  const int nk = K >> 6;
  const int nsteps = ntaps * nk;

  // prologue: stage step 0 into buf 0
  STAGE(0, 0, 0);
  asm volatile("s_waitcnt vmcnt(0)" ::: "memory");
  __builtin_amdgcn_s_barrier();

  int tap = 0, k0 = 0, cur = 0;
  for (int s = 0; s < nsteps; ++s) {
    int ntap = tap, nk0 = k0 + 64;
    if (nk0 >= K) { nk0 = 0; ntap = tap + 1; }
    if (s + 1 < nsteps) STAGE(ntap, nk0, cur ^ 1);   // prefetch BEFORE compute
    {
      const u16* sAb = &sA[cur][0];
      const u16* sBb = &sB[cur][0];
#pragma unroll
      for (int kb = 0; kb < 64; kb += 32) {
        const int ch0 = (kb + ksub) >> 3;            // logical chunk 0..7
        short8 af[NI], bfr[NJ];
#pragma unroll
        for (int i = 0; i < NI; ++i) {
          int ra = wr + i * 16 + mrow;
          af[i] = *(const short8*)(sAb + ra * 64 + ((ch0 ^ (ra & 7)) << 3));
        }
#pragma unroll
        for (int j = 0; j < NJ; ++j) {
          int rb = wc + j * 16 + mrow;
          bfr[j] = *(const short8*)(sBb + rb * 64 + ((ch0 ^ (rb & 7)) << 3));
        }
#pragma unroll
        for (int i = 0; i < NI; ++i)
#pragma unroll
          for (int j = 0; j < NJ; ++j)
            acc[i][j] = __builtin_amdgcn_mfma_f32_16x16x32_bf16(af[i], bfr[j], acc[i][j], 0, 0, 0);
      }
    }
    asm volatile("s_waitcnt vmcnt(0)" ::: "memory");  // next tile landed
    __builtin_amdgcn_s_barrier();                     // all waves: reads done + stage visible
    cur ^= 1; tap = ntap; k0 = nk0;
  }

  // epilogue: C/D layout col=lane&15, row=(lane>>4)*4+reg (m89-verified)
  const int cn = lane & 15;
  const int rq = (lane >> 4) * 4;
  u16*   Ch = (u16*)Cv   + (long)blockIdx.z * cBatch;
  float* Cf = (float*)Cv + (long)blockIdx.z * cBatch;
  const long zr = (long)blockIdx.z * rBatch;
#pragma unroll
  for (int j = 0; j < NJ; ++j) {
    int gn = n0 + wc + j * 16 + cn;
    float bv = bias ? bias[gn] : 0.f;
#pragma unroll
    for (int i = 0; i < NI; ++i) {
#pragma unroll
      for (int r = 0; r < 4; ++r) {
        int gm = m0 + wr + i * 16 + rq + r;
        long idx = (long)gm * ldc + gn;
        float v = acc[i][j][r] + bv;
        if (rowBias) v += rowBias[(gm >> 9) * N + gn];
        if (residv)
          v += rBf16 ? b2f(((const u16*)residv)[idx + zr]) : ((const float*)residv)[idx + zr];
        if (OP == 1) v = fmaxf(v, 0.f);
        if (OP == 2) v = 0.5f * v * (1.f + erff(v * 0.70710678118654752440f));
        if (OP == 3) v = 1.f / (1.f + expf(-v));
        if (outBf16) Ch[idx] = f2b(v);
        else Cf[idx] = v;
      }
    }
  }
}

// ---------------------------------------------------------------------------
// bulk fp32 -> bf16 conversion with row remap (pitch) + per-b scale.
// ---------------------------------------------------------------------------
#define NJOBS 27
struct ConvJobs {
  const float* src[NJOBS];
  u16* dst[NJOBS];
  int n2[NJOBS];         // pairs (8 floats) per job
  int rowLen2[NJOBS];    // pairs per source row
  int dstPitch2[NJOBS];  // dst row pitch in pairs
  const float* scl[NJOBS];  // per-(row>>9) scale or null
};
__global__ void convert_all(ConvJobs J, long total2)
{
  long g = (long)blockIdx.x * 256 + threadIdx.x;
  if (g >= total2) return;
  int j = 0; long off = g;
  while (off >= J.n2[j]) { off -= J.n2[j]; ++j; }
  long row = off / J.rowLen2[j];
  long c2  = off - row * J.rowLen2[j];
  const float4* s = (const float4*)J.src[j] + off * 2;
  float4 x = s[0], y = s[1];
  float sc = J.scl[j] ? J.scl[j][row >> 9] : 1.f;
  us8 h;
  h[0] = f2b(x.x * sc); h[1] = f2b(x.y * sc); h[2] = f2b(x.z * sc); h[3] = f2b(x.w * sc);
  h[4] = f2b(y.x * sc); h[5] = f2b(y.y * sc); h[6] = f2b(y.z * sc); h[7] = f2b(y.w * sc);
  *(us8*)(J.dst[j] + (row * (long)J.dstPitch2[j] + c2) * 8) = h;
}

__global__ void zero_kernel(u16* zp) { if (threadIdx.x < 128) zp[threadIdx.x] = 0; }

__global__ void copy16(const u16* __restrict__ s, u16* __restrict__ d)
{
  long g = (long)blockIdx.x * 256 + threadIdx.x;
  *(us8*)(d + g * 8) = *(const us8*)(s + g * 8);
}

// LayerNorm over D=768; input fp32 or bf16; out fp32 or bf16
__global__ void ln_kernel(const void* __restrict__ x, int xBf16,
                          const float* __restrict__ w, const float* __restrict__ b,
                          float* __restrict__ y32, u16* __restrict__ y16, int accum)
{
  const int row = blockIdx.x;
  const int tid = threadIdx.x;
  __shared__ float rs[256], rq[256];
  float v[3];
  long base = (long)row * DD;
  float s = 0.f, q = 0.f;
#pragma unroll
  for (int i = 0; i < 3; ++i) {
    int c = tid + i * 256;
    float t = xBf16 ? b2f(((const u16*)x)[base + c]) : ((const float*)x)[base + c];
    v[i] = t; s += t; q += t * t;
  }
  rs[tid] = s; rq[tid] = q; __syncthreads();
  for (int st = 128; st > 0; st >>= 1) {
    if (tid < st) { rs[tid] += rs[tid + st]; rq[tid] += rq[tid + st]; }
    __syncthreads();
  }
  float mean = rs[0] * (1.f / DD);
  float var  = fmaxf(rq[0] * (1.f / DD) - mean * mean, 0.f);
  float rstd = rsqrtf(var + 1e-12f);
#pragma unroll
  for (int i = 0; i < 3; ++i) {
    int c = tid + i * 256;
    float o = ((v[i] - mean) * rstd) * w[c] + b[c];
    if (y32) { if (accum) y32[base + c] += o; else y32[base + c] = o; }
    if (y16) {
      if (accum && !y32) y16[base + c] = f2b(b2f(y16[base + c]) + o);
      else y16[base + c] = f2b(o);
    }
  }
}

// Ef = g*Ea + (1-g)*Et, then LN(Ef) -> bf16. Et read from cc left half (pitch 1536).
__global__ void ef_ln_kernel(const u16* __restrict__ g, const float* __restrict__ Ea,
                             const u16* __restrict__ EtC,
                             const float* __restrict__ w, const float* __restrict__ b,
                             u16* __restrict__ xo)
{
  const int row = blockIdx.x;
  const int tid = threadIdx.x;
  __shared__ float rs[256], rq[256];
  float v[3];
  float s = 0.f, q = 0.f;
#pragma unroll
  for (int i = 0; i < 3; ++i) {
    int c = tid + i * 256;
    float gv = b2f(g[(long)row * DD + c]);
    float et = b2f(EtC[(long)row * 1536 + c]);
    float e  = gv * Ea[(long)row * DD + c] + (1.f - gv) * et;
    v[i] = e; s += e; q += e * e;
  }
  rs[tid] = s; rq[tid] = q; __syncthreads();
  for (int st = 128; st > 0; st >>= 1) {
    if (tid < st) { rs[tid] += rs[tid + st]; rq[tid] += rq[tid + st]; }
    __syncthreads();
  }
  float mean = rs[0] * (1.f / DD);
  float var  = fmaxf(rq[0] * (1.f / DD) - mean * mean, 0.f);
  float rstd = rsqrtf(var + 1e-12f);
#pragma unroll
  for (int i = 0; i < 3; ++i) {
    int c = tid + i * 256;
    xo[(long)row * DD + c] = f2b(((v[i] - mean) * rstd) * w[c] + b[c]);
  }
}

// Pn = LN( sum_z LN(outp[z], fln) , ln ). Sum in f32.
__global__ void ln3sum_kernel(const u16* __restrict__ o,
                              const float* __restrict__ fw, const float* __restrict__ fb,
                              const float* __restrict__ lw, const float* __restrict__ lb,
                              u16* __restrict__ Pn)
{
  const int row = blockIdx.x;
  const int tid = threadIdx.x;
  __shared__ float rs[256], rq[256];
  float v[3][3], mz[3], rz[3];
  for (int z = 0; z < 3; ++z) {
    long base = (long)z * MDL + (long)row * DD;
    float s = 0.f, q = 0.f;
#pragma unroll
    for (int i = 0; i < 3; ++i) {
      int c = tid + i * 256;
      float t = b2f(o[base + c]);
      v[z][i] = t; s += t; q += t * t;
    }
    rs[tid] = s; rq[tid] = q; __syncthreads();
    for (int st = 128; st > 0; st >>= 1) {
      if (tid < st) { rs[tid] += rs[tid + st]; rq[tid] += rq[tid + st]; }
      __syncthreads();
    }
    float mean = rs[0] * (1.f / DD);
    float var  = fmaxf(rq[0] * (1.f / DD) - mean * mean, 0.f);
    mz[z] = mean; rz[z] = rsqrtf(var + 1e-12f);
    __syncthreads();
  }
  float p[3];
  float s = 0.f, q = 0.f;
#pragma unroll
  for (int i = 0; i < 3; ++i) {
    int c = tid + i * 256;
    float pv = 0.f;
#pragma unroll
    for (int z = 0; z < 3; ++z) pv += (v[z][i] - mz[z]) * rz[z];
    pv = pv * fw[c] + 3.f * fb[c];
    p[i] = pv; s += pv; q += pv * pv;
  }
  rs[tid] = s; rq[tid] = q; __syncthreads();
  for (int st = 128; st > 0; st >>= 1) {
    if (tid < st) { rs[tid] += rs[tid + st]; rq[tid] += rq[tid + st]; }
    __syncthreads();
  }
  float mean = rs[0] * (1.f / DD);
  float var  = fmaxf(rq[0] * (1.f / DD) - mean * mean, 0.f);
  float rstd = rsqrtf(var + 1e-12f);
#pragma unroll
  for (int i = 0; i < 3; ++i) {
    int c = tid + i * 256;
    Pn[(long)row * DD + c] = f2b(((p[i] - mean) * rstd) * lw[c] + lb[c]);
  }
}

// all 6 streams' rowmeans in one launch
__global__ void rowmean_all(const float* f0, const float* f1, const float* f2,
                            const float* f3, const float* f4, const float* f5,
                            float* __restrict__ rm)
{
  const float* fs[6] = {f0, f1, f2, f3, f4, f5};
  int n = blockIdx.y;
  int b = blockIdx.x / 3, chunk = blockIdx.x % 3;
  int d = chunk * 256 + threadIdx.x;
  const float* base = fs[n] + (long)b * TT * DD + d;
  float s = 0.f;
  for (int t = 0; t < TT; ++t) s += base[(long)t * DD];
  rm[((long)n * BB + b) * DD + d] = s * (1.f / TT);
}

__global__ void colsum_kernel(const float* __restrict__ w, float* __restrict__ cs)
{
  int n = blockIdx.x / 3, chunk = blockIdx.x % 3;
  int e = chunk * 256 + threadIdx.x;
  const float* base = w + (long)n * DD * DD + e;
  float s = 0.f;
  for (int d = 0; d < DD; ++d) s += base[(long)d * DD];
  cs[n * DD + e] = s;
}

__global__ void fusion_weights(const float* __restrict__ rm, const float* __restrict__ cs,
                               const float* __restrict__ align_b,
                               const float* __restrict__ aw, const float* __restrict__ ab,
                               float* __restrict__ wpT)
{
  __shared__ float msh[48];
  int tid = threadIdx.x;
  if (tid < 48) {
    int b = tid / 6, n = tid % 6;
    const float* r = rm + ((long)n * BB + b) * DD;
    const float* c = cs + n * DD;
    float dot = 0.f, bs = 0.f;
    for (int e = 0; e < DD; ++e) dot += r[e] * c[e];
    for (int d = 0; d < DD; ++d) bs += align_b[n * DD + d];
    msh[b * 6 + n] = (dot + bs) * (1.f / DD);
  }
  __syncthreads();
  if (tid < BB) {
    int b = tid;
    float z[6];
#pragma unroll
    for (int n = 0; n < 6; ++n) {
      float s = ab[n];
#pragma unroll
      for (int j = 0; j < 6; ++j)
        s += (aw[n * 12 + j] + aw[n * 12 + 6 + j]) * msh[b * 6 + j];
      z[n] = fmaxf(s, 0.f);
    }
    float mx = z[0];
#pragma unroll
    for (int n = 1; n < 6; ++n) mx = fmaxf(mx, z[n]);
    float se = 0.f, e[6];
#pragma unroll
    for (int n = 0; n < 6; ++n) { e[n] = expf(z[n] - mx); se += e[n]; }
#pragma unroll
    for (int n = 0; n < 6; ++n) wpT[n * 8 + b] = e[n] / se + (1.f / 6.f);
  }
}

// rb[b,d] = sum_n wplus[b,n] * align_b[n,d]
__global__ void rowbias_kernel(const float* __restrict__ wpT, const float* __restrict__ ab,
                               float* __restrict__ rb)
{
  int b = blockIdx.x / 3;
  int d = (blockIdx.x % 3) * 256 + threadIdx.x;
  float s = 0.f;
#pragma unroll
  for (int n = 0; n < 6; ++n) s += wpT[n * 8 + b] * ab[n * DD + d];
  rb[b * DD + d] = s;
}

// conv weight [O,I,KT] fp32 -> [KT][O][I] bf16
__global__ void repack_conv(const float* __restrict__ src, u16* __restrict__ dst, int KT)
{
  long e = (long)blockIdx.x * 256 + threadIdx.x;
  if (e >= (long)KT * DD * DD) return;
  int k = (int)(e / (DD * DD));
  int rem = (int)(e - (long)k * DD * DD);
  int o = rem / DD, i = rem % DD;
  dst[e] = f2b(src[((long)o * DD + i) * KT + k]);
}

// out[row,h] = (X[row,:] . Wt[h,:] + bias[h]) * scale ; H=12, X bf16
__global__ void lin_small(const u16* __restrict__ X, const float* __restrict__ Wt,
                          const float* __restrict__ bias, float scale,
                          float* __restrict__ out)
{
  int row = blockIdx.x * 4 + (threadIdx.x >> 6);
  int lane = threadIdx.x & 63;
  float acc[12];
#pragma unroll
  for (int h = 0; h < 12; ++h) acc[h] = 0.f;
  for (int k = lane; k < DD; k += 64) {
    float xv = b2f(X[(long)row * DD + k]);
#pragma unroll
    for (int h = 0; h < 12; ++h) acc[h] += xv * Wt[h * DD + k];
  }
#pragma unroll
  for (int h = 0; h < 12; ++h)
    for (int off = 32; off > 0; off >>= 1) acc[h] += __shfl_down(acc[h], off);
  if (lane == 0) {
#pragma unroll
    for (int h = 0; h < 12; ++h)
      out[(long)row * 12 + h] = (acc[h] + bias[h]) * scale;
  }
}

__global__ void scores_softmax(const float* __restrict__ qs, const float* __restrict__ ks,
                               u16* __restrict__ aw)
{
  int bs = blockIdx.x;            // global (z*8+b)*512+s
  int b = bs >> 9;
  int tid = threadIdx.x;
  __shared__ float qsh[12];
  __shared__ float red[256];
  if (tid < 12) qsh[tid] = qs[(long)bs * 12 + tid];
  __syncthreads();
  float sc[2];
#pragma unroll
  for (int p = 0; p < 2; ++p) {
    int c = tid + p * 256;
    const float* kr = ks + (long)(b * 512 + c) * 12;
    float v = 0.f;
#pragma unroll
    for (int h = 0; h < 12; ++h) v += qsh[h] * kr[h];
    sc[p] = v;
  }
  red[tid] = fmaxf(sc[0], sc[1]); __syncthreads();
  for (int st = 128; st > 0; st >>= 1) {
    if (tid < st) red[tid] = fmaxf(red[tid], red[tid + st]);
    __syncthreads();
  }
  float mx = red[0]; __syncthreads();
  float e0 = expf(sc[0] - mx), e1 = expf(sc[1] - mx);
  red[tid] = e0 + e1; __syncthreads();
  for (int st = 128; st > 0; st >>= 1) {
    if (tid < st) red[tid] += red[tid + st];
    __syncthreads();
  }
  float inv = 1.f / red[0];
  aw[(long)bs * 512 + tid]       = f2b(e0 * inv);
  aw[(long)bs * 512 + tid + 256] = f2b(e1 * inv);
}

__global__ void transpose_kernel(const u16* __restrict__ in, u16* __restrict__ out)
{
  int b = blockIdx.z;
  const u16* ib = in + (long)b * TT * DD;
  u16* ob = out + (long)b * TT * DD;
  __shared__ u16 tile[32][33];
  int c0 = blockIdx.x * 32;   // d
  int r0 = blockIdx.y * 32;   // t
  int tx = threadIdx.x, ty = threadIdx.y;
#pragma unroll
  for (int i = 0; i < 4; ++i)
    tile[ty + 8 * i][tx] = ib[(long)(r0 + ty + 8 * i) * DD + c0 + tx];
  __syncthreads();
#pragma unroll
  for (int i = 0; i < 4; ++i)
    ob[(long)(c0 + ty + 8 * i) * TT + r0 + tx] = tile[tx][ty + 8 * i];
}

// ---------------------------------------------------------------------------
extern "C" void kernel_launch(void* const* d_in, const int* in_sizes, int n_in,
                              void* d_out, int out_size, void* d_ws, size_t ws_size,
                              hipStream_t stream)
{
  (void)in_sizes; (void)n_in; (void)out_size; (void)ws_size;
  const float* fin[6];
  for (int i = 0; i < 6; ++i) fin[i] = (const float*)d_in[i];
  const float* Ea      = (const float*)d_in[6];
  const float* align_w = (const float*)d_in[7];
  const float* align_b = (const float*)d_in[8];
  const float* att_w   = (const float*)d_in[9];
  const float* att_b   = (const float*)d_in[10];
  const float* g1_w = (const float*)d_in[11]; const float* g1_b = (const float*)d_in[12];
  const float* g2_w = (const float*)d_in[13]; const float* g2_b = (const float*)d_in[14];
  const float* g3_w = (const float*)d_in[15]; const float* g3_b = (const float*)d_in[16];
  const float* g4_w = (const float*)d_in[17]; const float* g4_b = (const float*)d_in[18];
  const float* ln_w = (const float*)d_in[19]; const float* ln_b = (const float*)d_in[20];
  const float* c1_w = (const float*)d_in[21]; const float* c1_b = (const float*)d_in[22];
  const float* c3_w = (const float*)d_in[23]; const float* c3_b = (const float*)d_in[24];
  const float* c5_w = (const float*)d_in[25]; const float* c5_b = (const float*)d_in[26];
  const float* q_w  = (const float*)d_in[27]; const float* q_b  = (const float*)d_in[28];
  const float* qa_w = (const float*)d_in[29]; const float* qa_b = (const float*)d_in[30];
  const float* k_w  = (const float*)d_in[31]; const float* k_b  = (const float*)d_in[32];
  const float* ka_w = (const float*)d_in[33]; const float* ka_b = (const float*)d_in[34];
  const float* tr_w = (const float*)d_in[35]; const float* tr_b = (const float*)d_in[36];
  const float* ao_w = (const float*)d_in[37]; const float* ao_b = (const float*)d_in[38];
  const float* fln_w = (const float*)d_in[39]; const float* fln_b = (const float*)d_in[40];
  const float* fi_w = (const float*)d_in[41]; const float* fi_b = (const float*)d_in[42];
  const float* fo_w = (const float*)d_in[43]; const float* fo_b = (const float*)d_in[44];
  const float* m1_w = (const float*)d_in[45]; const float* m1_b = (const float*)d_in[46];
  const float* m2_w = (const float*)d_in[47]; const float* m2_b = (const float*)d_in[48];
  const float* out_w = (const float*)d_in[49]; const float* out_b = (const float*)d_in[50];

  char* ws = (char*)d_ws;
  size_t off = 0;
  auto alloc = [&](size_t bytes) -> char* {
    char* p = ws + off;
    off += bytes;
    off = (off + 255) & ~(size_t)255;
    return p;
  };

  // small scratch
  u16*   zp    = (u16*)alloc(256);
  float* rmb   = (float*)alloc(6L * BB * DD * 4);
  float* csb   = (float*)alloc(6L * DD * 4);
  float* wpT   = (float*)alloc(48 * 4);
  float* rbias = (float*)alloc((long)BB * DD * 4);
  float* qsf   = (float*)alloc(3L * MM * 12 * 4);
  float* ksf   = (float*)alloc(3L * MM * 12 * 4);

  // bf16 weight cache (55.4 MB); cW_al is the K-concatenated align weight
  u16* Wc = (u16*)alloc(27721728L * 2);
  u16* cW_g1   = Wc;
  u16* cW_g2   = Wc + 2359296L;
  u16* cW_fi   = Wc + 4718592L;
  u16* cW_fo   = Wc + 7077888L;
  u16* cW_m1   = Wc + 9437184L;
  u16* cW_m2   = Wc + 11796480L;
  u16* cW_g3   = Wc + 14155776L;
  u16* cW_al   = Wc + 15335424L;
  u16* cW_g4   = Wc + 18874368L;
  u16* cW_c1   = Wc + 19464192L;
  u16* cW_q    = Wc + 20054016L;
  u16* cW_k    = Wc + 20643840L;
  u16* cW_tr   = Wc + 21233664L;
  u16* cW_ao   = Wc + 21823488L;
  u16* cW_out  = Wc + 22413312L;
  u16* w3r     = Wc + 23003136L;
  u16* w5r     = Wc + 24772608L;

  // big aliased regions (~184 MB); R1,R3,R4 are CONTIGUOUS (sizes 256-aligned)
  char* R1 = alloc((long)MM * 4608 * 2);  // A' -> qbuf -> [interb3 head] -> Jb
  char* R3 = alloc(MDL * 8);              // cc+o1 -> ctxkk -> [interb3] -> Pn+Jn
  char* R4 = alloc(MDL * 8);              // o2+o3+gb -> kkTsf -> [interb3 tail]
  char* R5 = alloc(MDL * 2);              // xb16 (persistent)
  char* R6 = alloc(MDL * 8);              // U = [U5,U3,U1,U5dup]
  char* R8 = alloc(MDL * 6);              // attp -> outp (3 layers)
  char* R9 = alloc(MDL * 6);              // attb (3 layers)
  char* R10 = alloc((long)MM * FFN * 2);  // awb -> interb (m1/m2)

  u16*   Ap    = (u16*)R1;
  u16*   qbuf  = (u16*)R1;
  float* Jb    = (float*)R1;
  u16*   interb3 = (u16*)R1;               // 75.5 MB spans R1+R3+R4 (fi->fo only)
  u16*   cc    = (u16*)R3;                 // [MM][1536]: left=Et(b16), right=Ea(b16)
  u16*   o1    = (u16*)R3 + 2 * MDL;
  u16*   ctxkk = (u16*)R3;
  u16*   PnB   = (u16*)R3;
  u16*   Jn    = (u16*)R3 + MDL;
  u16*   o2    = (u16*)R4;
  u16*   o3    = (u16*)R4 + 2 * MDL;
  u16*   gbuf  = (u16*)R4 + 3 * MDL;
  u16*   kkTsf = (u16*)R4;
  u16*   xb16  = (u16*)R5;
  u16*   U     = (u16*)R6;
  u16*   attp  = (u16*)R8;
  u16*   outp  = (u16*)R8;
  u16*   attb  = (u16*)R9;
  u16*   awb   = (u16*)R10;
  u16*   interb = (u16*)R10;

  auto gemm = [&](int tile, int op, const u16* A, const u16* W,
                  const float* bias, const float* rowBias,
                  const void* resid, int rB, void* Cc, int oB,
                  int Mi, int Ni, int Ki, int ldc,
                  int ntaps, int pad, long wtap,
                  int batch, long ab, long wb, long cb, long rbch) {
#define GL(BM, BN, OPV) gemm_bt<BM, BN, OPV><<<dim3(Ni / BN, Mi / BM, batch), 256, 0, stream>>>( \
      A, W, bias, rowBias, resid, Cc, Ni, Ki, ldc, rB, oB, ntaps, pad, wtap, ab, wb, cb, rbch, zp)
    if (tile == 1) {
      if (op == 0) GL(128, 64, 0); else if (op == 1) GL(128, 64, 1);
      else if (op == 2) GL(128, 64, 2); else GL(128, 64, 3);
    } else {
      if (op == 0) GL(128, 128, 0); else if (op == 1) GL(128, 128, 1);
      else if (op == 2) GL(128, 128, 2); else GL(128, 128, 3);
    }
#undef GL
  };

  zero_kernel<<<1, 128, 0, stream>>>(zp);

  // --- fusion weights first (analytic means over fp32 inputs) ---
  rowmean_all<<<dim3(24, 6), 256, 0, stream>>>(fin[0], fin[1], fin[2], fin[3], fin[4], fin[5], rmb);
  colsum_kernel<<<18, 256, 0, stream>>>(align_w, csb);
  fusion_weights<<<1, 64, 0, stream>>>(rmb, csb, align_b, att_w, att_b, wpT);
  rowbias_kernel<<<24, 256, 0, stream>>>(wpT, align_b, rbias);

  // --- bulk conversion: weights + wplus-scaled interleaved A' + Ea->cc right half ---
  {
    ConvJobs J;
    int idx = 0;
    long total2 = 0;
    auto add = [&](const float* s, u16* d, int n2v, int rl2, int dp2, const float* sc) {
      J.src[idx] = s; J.dst[idx] = d; J.n2[idx] = n2v;
      J.rowLen2[idx] = rl2; J.dstPitch2[idx] = dp2; J.scl[idx] = sc;
      total2 += n2v; ++idx;
    };
    for (int n = 0; n < 6; ++n)                       // A'[row][n*768+k] = wplus*f_n
      add(fin[n], Ap + n * DD, 393216, 96, 576, wpT + n * 8);
    add(Ea, cc + DD, 393216, 96, 192, nullptr);       // cc right half
    add(g1_w, cW_g1, 294912, 294912, 294912, nullptr);
    add(g2_w, cW_g2, 294912, 294912, 294912, nullptr);
    add(fi_w, cW_fi, 294912, 294912, 294912, nullptr);
    add(fo_w, cW_fo, 294912, 294912, 294912, nullptr);
    add(m1_w, cW_m1, 294912, 294912, 294912, nullptr);
    add(m2_w, cW_m2, 294912, 294912, 294912, nullptr);
    add(g3_w, cW_g3, 147456, 147456, 147456, nullptr);
    for (int n = 0; n < 6; ++n)                       // W'[o][n*768+k] = align_w[n][o][k]
      add(align_w + (long)n * 589824, cW_al + n * DD, 73728, 96, 576, nullptr);
    add(g4_w, cW_g4, 73728, 73728, 73728, nullptr);
    add(c1_w, cW_c1, 73728, 73728, 73728, nullptr);
    add(q_w,  cW_q,  73728, 73728, 73728, nullptr);
    add(k_w,  cW_k,  73728, 73728, 73728, nullptr);
    add(tr_w, cW_tr, 73728, 73728, 73728, nullptr);
    add(ao_w, cW_ao, 73728, 73728, 73728, nullptr);
    add(out_w, cW_out, 73728, 73728, 73728, nullptr);
    convert_all<<<(int)((total2 + 255) / 256), 256, 0, stream>>>(J, total2);
  }
  repack_conv<<<(3 * 589824 + 255) / 256, 256, 0, stream>>>(c3_w, w3r, 3);
  repack_conv<<<(5 * 589824 + 255) / 256, 256, 0, stream>>>(c5_w, w5r, 5);

  // --- FeatureAlignment: ONE GEMM, K=4608, writes Et(bf16) into cc left half ---
  gemm(1, 0, Ap, cW_al, nullptr, rbias, nullptr, 0, cc, 1,
       MM, DD, 4608, 1536, 1, 0, 0, 1, 0, 0, 0, 0);

  // --- GatedFusion ---
  gemm(1, 1, cc, cW_g1, g1_b, nullptr, nullptr, 0, o1, 1, MM, 1536, 1536, 1536, 1, 0, 0, 1, 0, 0, 0, 0);
  gemm(1, 1, o1, cW_g2, g2_b, nullptr, nullptr, 0, o2, 1, MM, 1536, 1536, 1536, 1, 0, 0, 1, 0, 0, 0, 0);
  gemm(1, 1, o2, cW_g3, g3_b, nullptr, nullptr, 0, o3, 1, MM, DD, 1536, DD, 1, 0, 0, 1, 0, 0, 0, 0);
  gemm(1, 3, o3, cW_g4, g4_b, nullptr, nullptr, 0, gbuf, 1, MM, DD, DD, DD, 1, 0, 0, 1, 0, 0, 0, 0);
  ef_ln_kernel<<<MM, 256, 0, stream>>>(gbuf, Ea, cc, ln_w, ln_b, xb16);   // x = LN(Ef)

  // --- multi-scale convs; U layout [U5,U3,U1,U5dup] ---
  gemm(1, 0, xb16, w5r, c5_b, nullptr, nullptr, 0, U, 1, MM, DD, DD, DD, 5, 2, 589824, 1, 0, 0, 0, 0);
  gemm(1, 0, xb16, w3r, c3_b, nullptr, nullptr, 0, U + MDL, 1, MM, DD, DD, DD, 3, 1, 589824, 1, 0, 0, 0, 0);
  gemm(1, 0, xb16, cW_c1, c1_b, nullptr, nullptr, 0, U + 2 * MDL, 1, MM, DD, DD, DD, 1, 0, 0, 1, 0, 0, 0, 0);
  copy16<<<1536, 256, 0, stream>>>(U, U + 3 * MDL);   // U5dup

  // --- 3 fastformer layers, batched z=3: hid=U+z*MDL, ctx=U+(z+1)*MDL ---
  gemm(1, 0, U,       cW_q, q_b, nullptr, nullptr, 0, qbuf,  1, MM, DD, DD, DD, 1, 0, 0, 3, MDL, 0, MDL, 0);
  gemm(1, 0, U + MDL, cW_k, k_b, nullptr, nullptr, 0, ctxkk, 1, MM, DD, DD, DD, 1, 0, 0, 3, MDL, 0, MDL, 0);
  lin_small<<<3 * MM / 4, 256, 0, stream>>>(qbuf,  qa_w, qa_b, 0.125f, qsf);
  lin_small<<<3 * MM / 4, 256, 0, stream>>>(ctxkk, ka_w, ka_b, 0.125f, ksf);
  scores_softmax<<<3 * MM, 256, 0, stream>>>(qsf, ksf, awb);
  transpose_kernel<<<dim3(24, 16, 24), dim3(32, 8), 0, stream>>>(ctxkk, kkTsf);
  gemm(1, 0, awb, kkTsf, nullptr, nullptr, nullptr, 0, ctxkk, 1, TT, DD, TT, DD,
       1, 0, 0, 24, (long)TT * TT, (long)DD * TT, (long)TT * DD, 0);
  gemm(1, 0, ctxkk, cW_tr, tr_b, nullptr, qbuf, 1, kkTsf, 1, MM, DD, DD, DD, 1, 0, 0, 3, MDL, 0, MDL, MDL);
  gemm(1, 0, kkTsf, cW_ao, ao_b, nullptr, U,    1, attp,  1, MM, DD, DD, DD, 1, 0, 0, 3, MDL, 0, MDL, MDL);
  ln_kernel<<<3 * MM, 256, 0, stream>>>(attp, 1, fln_w, fln_b, nullptr, attb, 0);
  // FFN: batched z=3 (interb3 spans dead R1+R3+R4; qbuf/ctxkk/kkTsf all consumed)
  gemm(2, 2, attb, cW_fi, fi_b, nullptr, nullptr, 0, interb3, 1,
       MM, FFN, DD, FFN, 1, 0, 0, 3, MDL, 0, (long)MM * FFN, 0);
  gemm(2, 0, interb3, cW_fo, fo_b, nullptr, attb, 1, outp, 1,
       MM, DD, FFN, DD, 1, 0, 0, 3, (long)MM * FFN, 0, MDL, MDL);
  ln3sum_kernel<<<MM, 256, 0, stream>>>(outp, fln_w, fln_b, ln_w, ln_b, PnB);

  // --- tail ---
  gemm(2, 2, PnB, cW_m1, m1_b, nullptr, nullptr, 0, interb, 1, MM, FFN, DD, FFN, 1, 0, 0, 1, 0, 0, 0, 0);
  gemm(1, 0, interb, cW_m2, m2_b, nullptr, xb16, 1, Jb, 0, MM, DD, FFN, DD, 1, 0, 0, 1, 0, 0, 0, 0);
  ln_kernel<<<MM, 256, 0, stream>>>(Jb, 0, ln_w, ln_b, nullptr, Jn, 0);
  gemm(1, 0, Jn, cW_out, out_b, nullptr, nullptr, 0, d_out, 0, MM, DD, DD, DD, 1, 0, 0, 1, 0, 0, 0, 0);
}

// Round 4
// 1399.869 us; speedup vs baseline: 1.3129x; 1.0592x over previous
//
#include <hip/hip_runtime.h>
#include <math.h>

// MFFNet forward on MI355X. fp32 in/out; all GEMMs bf16-MFMA with fp32 acc.
// GEMM core: double-buffered LDS, T2 XOR chunk-swizzle (both-sides),
// T4 counted vmcnt: STAGE(s+1) -> vmcnt(L) -> barrier -> compute -> barrier,
// newest stage's loads stay in flight across the compute. T5 setprio around
// MFMA. All big GEMMs on 128x64 tile (48KB LDS -> 3 blocks/CU, 12 waves).

typedef unsigned short u16;
typedef __attribute__((ext_vector_type(8))) short short8;     // 8 bf16
typedef __attribute__((ext_vector_type(8))) unsigned short us8;
typedef __attribute__((ext_vector_type(4))) float floatx4;
typedef unsigned __attribute__((address_space(1))) gu32;
typedef unsigned __attribute__((address_space(3))) lu32;

#define DD 768
#define TT 512
#define BB 8
#define MM 4096      // B*T rows
#define FFN 3072
#define MDL ((long)MM * DD)

__device__ __forceinline__ float b2f(u16 u) {
  union { unsigned u32; float f; } x; x.u32 = ((unsigned)u) << 16; return x.f;
}
__device__ __forceinline__ u16 f2b(float f) {   // round-to-nearest-even
  union { float f; unsigned u; } x; x.f = f;
  unsigned r = x.u + 0x7FFFu + ((x.u >> 16) & 1u);
  return (u16)(r >> 16);
}

// ---------------------------------------------------------------------------
// GEMM: C[M,N] = act(A[M,K] @ W[N,K]^T + bias + rowBias + resid)
// A, W bf16. 4 waves; BK=64; LDS stride 64 els (128 B); double-buffered.
// T2 swizzle: row's 8x16B chunks permuted chunk^=(row&7) on global source
// (global_load_lds dest linear) and on ds_read address (rule #21).
// Loop: STAGE(s+1); vmcnt(L=loads just issued -> waits slice s only);
// barrier; ds_read+MFMA; barrier. 2 barriers/iter, counted vmcnt (T4).
// ntaps/pad = conv-over-T (zero page OOB). OP: 0=none 1=relu 2=gelu 3=sigmoid.
// ---------------------------------------------------------------------------
template<int BM, int BN, int OP>
__global__ __launch_bounds__(256)
void gemm_bt(const u16* __restrict__ A, const u16* __restrict__ W,
             const float* __restrict__ bias, const float* __restrict__ rowBias,
             const void* __restrict__ residv, void* __restrict__ Cv,
             int N, int K, int ldc, int rBf16, int outBf16,
             int ntaps, int pad, long wtapStride,
             long aBatch, long wBatch, long cBatch, long rBatch,
             const u16* __restrict__ zp)
{
  __shared__ __align__(16) u16 sA[2][BM * 64];
  __shared__ __align__(16) u16 sB[2][BN * 64];
  const int tid  = threadIdx.x;
  const int lane = tid & 63;
  const int wv   = tid >> 6;

  // XCD swizzle: contiguous tile range per XCD
  int gx = gridDim.x, gy = gridDim.y;
  int bn = blockIdx.y * gx + blockIdx.x;
  int Tt = gx * gy;
  if ((Tt & 7) == 0) bn = (bn & 7) * (Tt >> 3) + (bn >> 3);
  const int m0 = (bn / gx) * BM;
  const int n0 = (bn % gx) * BN;
  const u16* Ab  = A + (long)blockIdx.z * aBatch;
  const u16* Wb0 = W + (long)blockIdx.z * wBatch;

  constexpr int NI = (BM == 128 && BN == 128) ? 4 : (BM == 128 ? 2 : 1);
  constexpr int NJ = 4;
  int wr, wc;
  if constexpr (BM == 128 && BN == 128) { wr = (wv >> 1) * 64; wc = (wv & 1) * 64; }
  else if constexpr (BM == 128)          { wr = wv * 32;        wc = 0; }
  else                                    { wr = wv * 16;        wc = 0; }

  floatx4 acc[NI][NJ];
#pragma unroll
  for (int i = 0; i < NI; ++i)
#pragma unroll
    for (int j = 0; j < NJ; ++j) acc[i][j] = (floatx4){0.f, 0.f, 0.f, 0.f};

  const int mrow = lane & 15;
  const int ksub = (lane >> 4) * 8;

  auto STAGE = [&](int tap_, int k0_, int bsel) {
    const int dt = tap_ - pad;
    const u16* Wt = Wb0 + (long)tap_ * wtapStride;
    u16* sAb = &sA[bsel][0];
    u16* sBb = &sB[bsel][0];
#pragma unroll
    for (int it = 0; it < BM / 32; ++it) {
      int slot = it * 256 + tid;
      int row = slot >> 3;
      int col = ((slot ^ row) & 7) * 8;        // T2: source chunk ^= row&7
      int gr = m0 + row;
      int t  = gr & (TT - 1);
      const u16* src = ((unsigned)(t + dt) < (unsigned)TT)
                     ? (Ab + (long)(gr + dt) * K + k0_ + col) : zp;
      __builtin_amdgcn_global_load_lds((const gu32*)src,
                                       (lu32*)((char*)sAb + slot * 16), 16, 0, 0);
    }
#pragma unroll
    for (int it = 0; it < BN / 32; ++it) {
      int slot = it * 256 + tid;
      int row = slot >> 3;
      int col = ((slot ^ row) & 7) * 8;        // T2: source chunk ^= row&7
      const u16* src = Wt + (long)(n0 + row) * K + k0_ + col;
      __builtin_amdgcn_global_load_lds((const gu32*)src,
                                       (lu32*)((char*)sBb + slot * 16), 16, 0, 0);
    }
  };

  const int nk = K >> 6;
  const int nsteps = ntaps * nk;

  // prologue: stage step 0 into buf 0 (wait folded into first loop iter)
  STAGE(0, 0, 0);

  int tap = 0, k0 = 0, cur = 0;
  for (int s = 0; s < nsteps; ++s) {
    int ntap = tap, nk0 = k0 + 64;
    if (nk0 >= K) { nk0 = 0; ntap = tap + 1; }
    if (s + 1 < nsteps) {
      STAGE(ntap, nk0, cur ^ 1);               // issue next-tile loads first
      // wait for slice s only; slice s+1's loads stay in flight (T4)
      if constexpr (BM / 32 + BN / 32 == 6)
        asm volatile("s_waitcnt vmcnt(6)" ::: "memory");
      else
        asm volatile("s_waitcnt vmcnt(8)" ::: "memory");
    } else {
      asm volatile("s_waitcnt vmcnt(0)" ::: "memory");
    }
    __builtin_amdgcn_s_barrier();              // slice s visible to all waves
    {
      const u16* sAb = &sA[cur][0];
      const u16* sBb = &sB[cur][0];
      __builtin_amdgcn_s_setprio(1);
#pragma unroll
      for (int kb = 0; kb < 64; kb += 32) {
        const int ch0 = (kb + ksub) >> 3;            // logical chunk 0..7
        short8 af[NI], bfr[NJ];
#pragma unroll
        for (int i = 0; i < NI; ++i) {
          int ra = wr + i * 16 + mrow;
          af[i] = *(const short8*)(sAb + ra * 64 + ((ch0 ^ (ra & 7)) << 3));
        }
#pragma unroll
        for (int j = 0; j < NJ; ++j) {
          int rb = wc + j * 16 + mrow;
          bfr[j] = *(const short8*)(sBb + rb * 64 + ((ch0 ^ (rb & 7)) << 3));
        }
#pragma unroll
        for (int i = 0; i < NI; ++i)
#pragma unroll
          for (int j = 0; j < NJ; ++j)
            acc[i][j] = __builtin_amdgcn_mfma_f32_16x16x32_bf16(af[i], bfr[j], acc[i][j], 0, 0, 0);
      }
      __builtin_amdgcn_s_setprio(0);
    }
    __builtin_amdgcn_s_barrier();              // all reads done before overwrite
    cur ^= 1; tap = ntap; k0 = nk0;
  }

  // epilogue: C/D layout col=lane&15, row=(lane>>4)*4+reg (m89-verified)
  const int cn = lane & 15;
  const int rq = (lane >> 4) * 4;
  u16*   Ch = (u16*)Cv   + (long)blockIdx.z * cBatch;
  float* Cf = (float*)Cv + (long)blockIdx.z * cBatch;
  const long zr = (long)blockIdx.z * rBatch;
#pragma unroll
  for (int j = 0; j < NJ; ++j) {
    int gn = n0 + wc + j * 16 + cn;
    float bv = bias ? bias[gn] : 0.f;
#pragma unroll
    for (int i = 0; i < NI; ++i) {
#pragma unroll
      for (int r = 0; r < 4; ++r) {
        int gm = m0 + wr + i * 16 + rq + r;
        long idx = (long)gm * ldc + gn;
        float v = acc[i][j][r] + bv;
        if (rowBias) v += rowBias[(gm >> 9) * N + gn];
        if (residv)
          v += rBf16 ? b2f(((const u16*)residv)[idx + zr]) : ((const float*)residv)[idx + zr];
        if (OP == 1) v = fmaxf(v, 0.f);
        if (OP == 2) v = 0.5f * v * (1.f + erff(v * 0.70710678118654752440f));
        if (OP == 3) v = 1.f / (1.f + expf(-v));
        if (outBf16) Ch[idx] = f2b(v);
        else Cf[idx] = v;
      }
    }
  }
}

// ---------------------------------------------------------------------------
// bulk fp32 -> bf16 conversion with row remap (pitch) + per-b scale.
// ---------------------------------------------------------------------------
#define NJOBS 27
struct ConvJobs {
  const float* src[NJOBS];
  u16* dst[NJOBS];
  int n2[NJOBS];         // pairs (8 floats) per job
  int rowLen2[NJOBS];    // pairs per source row
  int dstPitch2[NJOBS];  // dst row pitch in pairs
  const float* scl[NJOBS];  // per-(row>>9) scale or null
};
__global__ void convert_all(ConvJobs J, long total2)
{
  long g = (long)blockIdx.x * 256 + threadIdx.x;
  if (g >= total2) return;
  int j = 0; long off = g;
  while (off >= J.n2[j]) { off -= J.n2[j]; ++j; }
  long row = off / J.rowLen2[j];
  long c2  = off - row * J.rowLen2[j];
  const float4* s = (const float4*)J.src[j] + off * 2;
  float4 x = s[0], y = s[1];
  float sc = J.scl[j] ? J.scl[j][row >> 9] : 1.f;
  us8 h;
  h[0] = f2b(x.x * sc); h[1] = f2b(x.y * sc); h[2] = f2b(x.z * sc); h[3] = f2b(x.w * sc);
  h[4] = f2b(y.x * sc); h[5] = f2b(y.y * sc); h[6] = f2b(y.z * sc); h[7] = f2b(y.w * sc);
  *(us8*)(J.dst[j] + (row * (long)J.dstPitch2[j] + c2) * 8) = h;
}

__global__ void zero_kernel(u16* zp) { if (threadIdx.x < 128) zp[threadIdx.x] = 0; }

__global__ void copy16(const u16* __restrict__ s, u16* __restrict__ d)
{
  long g = (long)blockIdx.x * 256 + threadIdx.x;
  *(us8*)(d + g * 8) = *(const us8*)(s + g * 8);
}

// LayerNorm over D=768; input fp32 or bf16; out fp32 or bf16
__global__ void ln_kernel(const void* __restrict__ x, int xBf16,
                          const float* __restrict__ w, const float* __restrict__ b,
                          float* __restrict__ y32, u16* __restrict__ y16, int accum)
{
  const int row = blockIdx.x;
  const int tid = threadIdx.x;
  __shared__ float rs[256], rq[256];
  float v[3];
  long base = (long)row * DD;
  float s = 0.f, q = 0.f;
#pragma unroll
  for (int i = 0; i < 3; ++i) {
    int c = tid + i * 256;
    float t = xBf16 ? b2f(((const u16*)x)[base + c]) : ((const float*)x)[base + c];
    v[i] = t; s += t; q += t * t;
  }
  rs[tid] = s; rq[tid] = q; __syncthreads();
  for (int st = 128; st > 0; st >>= 1) {
    if (tid < st) { rs[tid] += rs[tid + st]; rq[tid] += rq[tid + st]; }
    __syncthreads();
  }
  float mean = rs[0] * (1.f / DD);
  float var  = fmaxf(rq[0] * (1.f / DD) - mean * mean, 0.f);
  float rstd = rsqrtf(var + 1e-12f);
#pragma unroll
  for (int i = 0; i < 3; ++i) {
    int c = tid + i * 256;
    float o = ((v[i] - mean) * rstd) * w[c] + b[c];
    if (y32) { if (accum) y32[base + c] += o; else y32[base + c] = o; }
    if (y16) {
      if (accum && !y32) y16[base + c] = f2b(b2f(y16[base + c]) + o);
      else y16[base + c] = f2b(o);
    }
  }
}

// Ef = g*Ea + (1-g)*Et, then LN(Ef) -> bf16. Et read from cc left half (pitch 1536).
__global__ void ef_ln_kernel(const u16* __restrict__ g, const float* __restrict__ Ea,
                             const u16* __restrict__ EtC,
                             const float* __restrict__ w, const float* __restrict__ b,
                             u16* __restrict__ xo)
{
  const int row = blockIdx.x;
  const int tid = threadIdx.x;
  __shared__ float rs[256], rq[256];
  float v[3];
  float s = 0.f, q = 0.f;
#pragma unroll
  for (int i = 0; i < 3; ++i) {
    int c = tid + i * 256;
    float gv = b2f(g[(long)row * DD + c]);
    float et = b2f(EtC[(long)row * 1536 + c]);
    float e  = gv * Ea[(long)row * DD + c] + (1.f - gv) * et;
    v[i] = e; s += e; q += e * e;
  }
  rs[tid] = s; rq[tid] = q; __syncthreads();
  for (int st = 128; st > 0; st >>= 1) {
    if (tid < st) { rs[tid] += rs[tid + st]; rq[tid] += rq[tid + st]; }
    __syncthreads();
  }
  float mean = rs[0] * (1.f / DD);
  float var  = fmaxf(rq[0] * (1.f / DD) - mean * mean, 0.f);
  float rstd = rsqrtf(var + 1e-12f);
#pragma unroll
  for (int i = 0; i < 3; ++i) {
    int c = tid + i * 256;
    xo[(long)row * DD + c] = f2b(((v[i] - mean) * rstd) * w[c] + b[c]);
  }
}

// Pn = LN( sum_z LN(outp[z], fln) , ln ). Sum in f32.
__global__ void ln3sum_kernel(const u16* __restrict__ o,
                              const float* __restrict__ fw, const float* __restrict__ fb,
                              const float* __restrict__ lw, const float* __restrict__ lb,
                              u16* __restrict__ Pn)
{
  const int row = blockIdx.x;
  const int tid = threadIdx.x;
  __shared__ float rs[256], rq[256];
  float v[3][3], mz[3], rz[3];
  for (int z = 0; z < 3; ++z) {
    long base = (long)z * MDL + (long)row * DD;
    float s = 0.f, q = 0.f;
#pragma unroll
    for (int i = 0; i < 3; ++i) {
      int c = tid + i * 256;
      float t = b2f(o[base + c]);
      v[z][i] = t; s += t; q += t * t;
    }
    rs[tid] = s; rq[tid] = q; __syncthreads();
    for (int st = 128; st > 0; st >>= 1) {
      if (tid < st) { rs[tid] += rs[tid + st]; rq[tid] += rq[tid + st]; }
      __syncthreads();
    }
    float mean = rs[0] * (1.f / DD);
    float var  = fmaxf(rq[0] * (1.f / DD) - mean * mean, 0.f);
    mz[z] = mean; rz[z] = rsqrtf(var + 1e-12f);
    __syncthreads();
  }
  float p[3];
  float s = 0.f, q = 0.f;
#pragma unroll
  for (int i = 0; i < 3; ++i) {
    int c = tid + i * 256;
    float pv = 0.f;
#pragma unroll
    for (int z = 0; z < 3; ++z) pv += (v[z][i] - mz[z]) * rz[z];
    pv = pv * fw[c] + 3.f * fb[c];
    p[i] = pv; s += pv; q += pv * pv;
  }
  rs[tid] = s; rq[tid] = q; __syncthreads();
  for (int st = 128; st > 0; st >>= 1) {
    if (tid < st) { rs[tid] += rs[tid + st]; rq[tid] += rq[tid + st]; }
    __syncthreads();
  }
  float mean = rs[0] * (1.f / DD);
  float var  = fmaxf(rq[0] * (1.f / DD) - mean * mean, 0.f);
  float rstd = rsqrtf(var + 1e-12f);
#pragma unroll
  for (int i = 0; i < 3; ++i) {
    int c = tid + i * 256;
    Pn[(long)row * DD + c] = f2b(((p[i] - mean) * rstd) * lw[c] + lb[c]);
  }
}

// all 6 streams' rowmeans in one launch
__global__ void rowmean_all(const float* f0, const float* f1, const float* f2,
                            const float* f3, const float* f4, const float* f5,
                            float* __restrict__ rm)
{
  const float* fs[6] = {f0, f1, f2, f3, f4, f5};
  int n = blockIdx.y;
  int b = blockIdx.x / 3, chunk = blockIdx.x % 3;
  int d = chunk * 256 + threadIdx.x;
  const float* base = fs[n] + (long)b * TT * DD + d;
  float s = 0.f;
  for (int t = 0; t < TT; ++t) s += base[(long)t * DD];
  rm[((long)n * BB + b) * DD + d] = s * (1.f / TT);
}

__global__ void colsum_kernel(const float* __restrict__ w, float* __restrict__ cs)
{
  int n = blockIdx.x / 3, chunk = blockIdx.x % 3;
  int e = chunk * 256 + threadIdx.x;
  const float* base = w + (long)n * DD * DD + e;
  float s = 0.f;
  for (int d = 0; d < DD; ++d) s += base[(long)d * DD];
  cs[n * DD + e] = s;
}

__global__ void fusion_weights(const float* __restrict__ rm, const float* __restrict__ cs,
                               const float* __restrict__ align_b,
                               const float* __restrict__ aw, const float* __restrict__ ab,
                               float* __restrict__ wpT)
{
  __shared__ float msh[48];
  int tid = threadIdx.x;
  if (tid < 48) {
    int b = tid / 6, n = tid % 6;
    const float* r = rm + ((long)n * BB + b) * DD;
    const float* c = cs + n * DD;
    float dot = 0.f, bs = 0.f;
    for (int e = 0; e < DD; ++e) dot += r[e] * c[e];
    for (int d = 0; d < DD; ++d) bs += align_b[n * DD + d];
    msh[b * 6 + n] = (dot + bs) * (1.f / DD);
  }
  __syncthreads();
  if (tid < BB) {
    int b = tid;
    float z[6];
#pragma unroll
    for (int n = 0; n < 6; ++n) {
      float s = ab[n];
#pragma unroll
      for (int j = 0; j < 6; ++j)
        s += (aw[n * 12 + j] + aw[n * 12 + 6 + j]) * msh[b * 6 + j];
      z[n] = fmaxf(s, 0.f);
    }
    float mx = z[0];
#pragma unroll
    for (int n = 1; n < 6; ++n) mx = fmaxf(mx, z[n]);
    float se = 0.f, e[6];
#pragma unroll
    for (int n = 0; n < 6; ++n) { e[n] = expf(z[n] - mx); se += e[n]; }
#pragma unroll
    for (int n = 0; n < 6; ++n) wpT[n * 8 + b] = e[n] / se + (1.f / 6.f);
  }
}

// rb[b,d] = sum_n wplus[b,n] * align_b[n,d]
__global__ void rowbias_kernel(const float* __restrict__ wpT, const float* __restrict__ ab,
                               float* __restrict__ rb)
{
  int b = blockIdx.x / 3;
  int d = (blockIdx.x % 3) * 256 + threadIdx.x;
  float s = 0.f;
#pragma unroll
  for (int n = 0; n < 6; ++n) s += wpT[n * 8 + b] * ab[n * DD + d];
  rb[b * DD + d] = s;
}

// conv weight [O,I,KT] fp32 -> [KT][O][I] bf16
__global__ void repack_conv(const float* __restrict__ src, u16* __restrict__ dst, int KT)
{
  long e = (long)blockIdx.x * 256 + threadIdx.x;
  if (e >= (long)KT * DD * DD) return;
  int k = (int)(e / (DD * DD));
  int rem = (int)(e - (long)k * DD * DD);
  int o = rem / DD, i = rem % DD;
  dst[e] = f2b(src[((long)o * DD + i) * KT + k]);
}

// out[row,h] = (X[row,:] . Wt[h,:] + bias[h]) * scale ; H=12, X bf16
__global__ void lin_small(const u16* __restrict__ X, const float* __restrict__ Wt,
                          const float* __restrict__ bias, float scale,
                          float* __restrict__ out)
{
  int row = blockIdx.x * 4 + (threadIdx.x >> 6);
  int lane = threadIdx.x & 63;
  float acc[12];
#pragma unroll
  for (int h = 0; h < 12; ++h) acc[h] = 0.f;
  for (int k = lane; k < DD; k += 64) {
    float xv = b2f(X[(long)row * DD + k]);
#pragma unroll
    for (int h = 0; h < 12; ++h) acc[h] += xv * Wt[h * DD + k];
  }
#pragma unroll
  for (int h = 0; h < 12; ++h)
    for (int off = 32; off > 0; off >>= 1) acc[h] += __shfl_down(acc[h], off);
  if (lane == 0) {
#pragma unroll
    for (int h = 0; h < 12; ++h)
      out[(long)row * 12 + h] = (acc[h] + bias[h]) * scale;
  }
}

__global__ void scores_softmax(const float* __restrict__ qs, const float* __restrict__ ks,
                               u16* __restrict__ aw)
{
  int bs = blockIdx.x;            // global (z*8+b)*512+s
  int b = bs >> 9;
  int tid = threadIdx.x;
  __shared__ float qsh[12];
  __shared__ float red[256];
  if (tid < 12) qsh[tid] = qs[(long)bs * 12 + tid];
  __syncthreads();
  float sc[2];
#pragma unroll
  for (int p = 0; p < 2; ++p) {
    int c = tid + p * 256;
    const float* kr = ks + (long)(b * 512 + c) * 12;
    float v = 0.f;
#pragma unroll
    for (int h = 0; h < 12; ++h) v += qsh[h] * kr[h];
    sc[p] = v;
  }
  red[tid] = fmaxf(sc[0], sc[1]); __syncthreads();
  for (int st = 128; st > 0; st >>= 1) {
    if (tid < st) red[tid] = fmaxf(red[tid], red[tid + st]);
    __syncthreads();
  }
  float mx = red[0]; __syncthreads();
  float e0 = expf(sc[0] - mx), e1 = expf(sc[1] - mx);
  red[tid] = e0 + e1; __syncthreads();
  for (int st = 128; st > 0; st >>= 1) {
    if (tid < st) red[tid] += red[tid + st];
    __syncthreads();
  }
  float inv = 1.f / red[0];
  aw[(long)bs * 512 + tid]       = f2b(e0 * inv);
  aw[(long)bs * 512 + tid + 256] = f2b(e1 * inv);
}

__global__ void transpose_kernel(const u16* __restrict__ in, u16* __restrict__ out)
{
  int b = blockIdx.z;
  const u16* ib = in + (long)b * TT * DD;
  u16* ob = out + (long)b * TT * DD;
  __shared__ u16 tile[32][33];
  int c0 = blockIdx.x * 32;   // d
  int r0 = blockIdx.y * 32;   // t
  int tx = threadIdx.x, ty = threadIdx.y;
#pragma unroll
  for (int i = 0; i < 4; ++i)
    tile[ty + 8 * i][tx] = ib[(long)(r0 + ty + 8 * i) * DD + c0 + tx];
  __syncthreads();
#pragma unroll
  for (int i = 0; i < 4; ++i)
    ob[(long)(c0 + ty + 8 * i) * TT + r0 + tx] = tile[tx][ty + 8 * i];
}

// ---------------------------------------------------------------------------
extern "C" void kernel_launch(void* const* d_in, const int* in_sizes, int n_in,
                              void* d_out, int out_size, void* d_ws, size_t ws_size,
                              hipStream_t stream)
{
  (void)in_sizes; (void)n_in; (void)out_size; (void)ws_size;
  const float* fin[6];
  for (int i = 0; i < 6; ++i) fin[i] = (const float*)d_in[i];
  const float* Ea      = (const float*)d_in[6];
  const float* align_w = (const float*)d_in[7];
  const float* align_b = (const float*)d_in[8];
  const float* att_w   = (const float*)d_in[9];
  const float* att_b   = (const float*)d_in[10];
  const float* g1_w = (const float*)d_in[11]; const float* g1_b = (const float*)d_in[12];
  const float* g2_w = (const float*)d_in[13]; const float* g2_b = (const float*)d_in[14];
  const float* g3_w = (const float*)d_in[15]; const float* g3_b = (const float*)d_in[16];
  const float* g4_w = (const float*)d_in[17]; const float* g4_b = (const float*)d_in[18];
  const float* ln_w = (const float*)d_in[19]; const float* ln_b = (const float*)d_in[20];
  const float* c1_w = (const float*)d_in[21]; const float* c1_b = (const float*)d_in[22];
  const float* c3_w = (const float*)d_in[23]; const float* c3_b = (const float*)d_in[24];
  const float* c5_w = (const float*)d_in[25]; const float* c5_b = (const float*)d_in[26];
  const float* q_w  = (const float*)d_in[27]; const float* q_b  = (const float*)d_in[28];
  const float* qa_w = (const float*)d_in[29]; const float* qa_b = (const float*)d_in[30];
  const float* k_w  = (const float*)d_in[31]; const float* k_b  = (const float*)d_in[32];
  const float* ka_w = (const float*)d_in[33]; const float* ka_b = (const float*)d_in[34];
  const float* tr_w = (const float*)d_in[35]; const float* tr_b = (const float*)d_in[36];
  const float* ao_w = (const float*)d_in[37]; const float* ao_b = (const float*)d_in[38];
  const float* fln_w = (const float*)d_in[39]; const float* fln_b = (const float*)d_in[40];
  const float* fi_w = (const float*)d_in[41]; const float* fi_b = (const float*)d_in[42];
  const float* fo_w = (const float*)d_in[43]; const float* fo_b = (const float*)d_in[44];
  const float* m1_w = (const float*)d_in[45]; const float* m1_b = (const float*)d_in[46];
  const float* m2_w = (const float*)d_in[47]; const float* m2_b = (const float*)d_in[48];
  const float* out_w = (const float*)d_in[49]; const float* out_b = (const float*)d_in[50];

  char* ws = (char*)d_ws;
  size_t off = 0;
  auto alloc = [&](size_t bytes) -> char* {
    char* p = ws + off;
    off += bytes;
    off = (off + 255) & ~(size_t)255;
    return p;
  };

  // small scratch
  u16*   zp    = (u16*)alloc(256);
  float* rmb   = (float*)alloc(6L * BB * DD * 4);
  float* csb   = (float*)alloc(6L * DD * 4);
  float* wpT   = (float*)alloc(48 * 4);
  float* rbias = (float*)alloc((long)BB * DD * 4);
  float* qsf   = (float*)alloc(3L * MM * 12 * 4);
  float* ksf   = (float*)alloc(3L * MM * 12 * 4);

  // bf16 weight cache (55.4 MB); cW_al is the K-concatenated align weight
  u16* Wc = (u16*)alloc(27721728L * 2);
  u16* cW_g1   = Wc;
  u16* cW_g2   = Wc + 2359296L;
  u16* cW_fi   = Wc + 4718592L;
  u16* cW_fo   = Wc + 7077888L;
  u16* cW_m1   = Wc + 9437184L;
  u16* cW_m2   = Wc + 11796480L;
  u16* cW_g3   = Wc + 14155776L;
  u16* cW_al   = Wc + 15335424L;
  u16* cW_g4   = Wc + 18874368L;
  u16* cW_c1   = Wc + 19464192L;
  u16* cW_q    = Wc + 20054016L;
  u16* cW_k    = Wc + 20643840L;
  u16* cW_tr   = Wc + 21233664L;
  u16* cW_ao   = Wc + 21823488L;
  u16* cW_out  = Wc + 22413312L;
  u16* w3r     = Wc + 23003136L;
  u16* w5r     = Wc + 24772608L;

  // big aliased regions (~184 MB); R1,R3,R4 are CONTIGUOUS (sizes 256-aligned)
  char* R1 = alloc((long)MM * 4608 * 2);  // A' -> qbuf -> [interb3 head] -> Jb
  char* R3 = alloc(MDL * 8);              // cc+o1 -> ctxkk -> [interb3] -> Pn+Jn
  char* R4 = alloc(MDL * 8);              // o2+o3+gb -> kkTsf -> [interb3 tail]
  char* R5 = alloc(MDL * 2);              // xb16 (persistent)
  char* R6 = alloc(MDL * 8);              // U = [U5,U3,U1,U5dup]
  char* R8 = alloc(MDL * 6);              // attp -> outp (3 layers)
  char* R9 = alloc(MDL * 6);              // attb (3 layers)
  char* R10 = alloc((long)MM * FFN * 2);  // awb -> interb (m1/m2)

  u16*   Ap    = (u16*)R1;
  u16*   qbuf  = (u16*)R1;
  float* Jb    = (float*)R1;
  u16*   interb3 = (u16*)R1;               // 75.5 MB spans R1+R3+R4 (fi->fo only)
  u16*   cc    = (u16*)R3;                 // [MM][1536]: left=Et(b16), right=Ea(b16)
  u16*   o1    = (u16*)R3 + 2 * MDL;
  u16*   ctxkk = (u16*)R3;
  u16*   PnB   = (u16*)R3;
  u16*   Jn    = (u16*)R3 + MDL;
  u16*   o2    = (u16*)R4;
  u16*   o3    = (u16*)R4 + 2 * MDL;
  u16*   gbuf  = (u16*)R4 + 3 * MDL;
  u16*   kkTsf = (u16*)R4;
  u16*   xb16  = (u16*)R5;
  u16*   U     = (u16*)R6;
  u16*   attp  = (u16*)R8;
  u16*   outp  = (u16*)R8;
  u16*   attb  = (u16*)R9;
  u16*   awb   = (u16*)R10;
  u16*   interb = (u16*)R10;

  auto gemm = [&](int tile, int op, const u16* A, const u16* W,
                  const float* bias, const float* rowBias,
                  const void* resid, int rB, void* Cc, int oB,
                  int Mi, int Ni, int Ki, int ldc,
                  int ntaps, int pad, long wtap,
                  int batch, long ab, long wb, long cb, long rbch) {
#define GL(BM, BN, OPV) gemm_bt<BM, BN, OPV><<<dim3(Ni / BN, Mi / BM, batch), 256, 0, stream>>>( \
      A, W, bias, rowBias, resid, Cc, Ni, Ki, ldc, rB, oB, ntaps, pad, wtap, ab, wb, cb, rbch, zp)
    if (tile == 1) {
      if (op == 0) GL(128, 64, 0); else if (op == 1) GL(128, 64, 1);
      else if (op == 2) GL(128, 64, 2); else GL(128, 64, 3);
    } else {
      if (op == 0) GL(128, 128, 0); else if (op == 1) GL(128, 128, 1);
      else if (op == 2) GL(128, 128, 2); else GL(128, 128, 3);
    }
#undef GL
  };

  zero_kernel<<<1, 128, 0, stream>>>(zp);

  // --- fusion weights first (analytic means over fp32 inputs) ---
  rowmean_all<<<dim3(24, 6), 256, 0, stream>>>(fin[0], fin[1], fin[2], fin[3], fin[4], fin[5], rmb);
  colsum_kernel<<<18, 256, 0, stream>>>(align_w, csb);
  fusion_weights<<<1, 64, 0, stream>>>(rmb, csb, align_b, att_w, att_b, wpT);
  rowbias_kernel<<<24, 256, 0, stream>>>(wpT, align_b, rbias);

  // --- bulk conversion: weights + wplus-scaled interleaved A' + Ea->cc right half ---
  {
    ConvJobs J;
    int idx = 0;
    long total2 = 0;
    auto add = [&](const float* s, u16* d, int n2v, int rl2, int dp2, const float* sc) {
      J.src[idx] = s; J.dst[idx] = d; J.n2[idx] = n2v;
      J.rowLen2[idx] = rl2; J.dstPitch2[idx] = dp2; J.scl[idx] = sc;
      total2 += n2v; ++idx;
    };
    for (int n = 0; n < 6; ++n)                       // A'[row][n*768+k] = wplus*f_n
      add(fin[n], Ap + n * DD, 393216, 96, 576, wpT + n * 8);
    add(Ea, cc + DD, 393216, 96, 192, nullptr);       // cc right half
    add(g1_w, cW_g1, 294912, 294912, 294912, nullptr);
    add(g2_w, cW_g2, 294912, 294912, 294912, nullptr);
    add(fi_w, cW_fi, 294912, 294912, 294912, nullptr);
    add(fo_w, cW_fo, 294912, 294912, 294912, nullptr);
    add(m1_w, cW_m1, 294912, 294912, 294912, nullptr);
    add(m2_w, cW_m2, 294912, 294912, 294912, nullptr);
    add(g3_w, cW_g3, 147456, 147456, 147456, nullptr);
    for (int n = 0; n < 6; ++n)                       // W'[o][n*768+k] = align_w[n][o][k]
      add(align_w + (long)n * 589824, cW_al + n * DD, 73728, 96, 576, nullptr);
    add(g4_w, cW_g4, 73728, 73728, 73728, nullptr);
    add(c1_w, cW_c1, 73728, 73728, 73728, nullptr);
    add(q_w,  cW_q,  73728, 73728, 73728, nullptr);
    add(k_w,  cW_k,  73728, 73728, 73728, nullptr);
    add(tr_w, cW_tr, 73728, 73728, 73728, nullptr);
    add(ao_w, cW_ao, 73728, 73728, 73728, nullptr);
    add(out_w, cW_out, 73728, 73728, 73728, nullptr);
    convert_all<<<(int)((total2 + 255) / 256), 256, 0, stream>>>(J, total2);
  }
  repack_conv<<<(3 * 589824 + 255) / 256, 256, 0, stream>>>(c3_w, w3r, 3);
  repack_conv<<<(5 * 589824 + 255) / 256, 256, 0, stream>>>(c5_w, w5r, 5);

  // --- FeatureAlignment: ONE GEMM, K=4608, writes Et(bf16) into cc left half ---
  gemm(1, 0, Ap, cW_al, nullptr, rbias, nullptr, 0, cc, 1,
       MM, DD, 4608, 1536, 1, 0, 0, 1, 0, 0, 0, 0);

  // --- GatedFusion ---
  gemm(1, 1, cc, cW_g1, g1_b, nullptr, nullptr, 0, o1, 1, MM, 1536, 1536, 1536, 1, 0, 0, 1, 0, 0, 0, 0);
  gemm(1, 1, o1, cW_g2, g2_b, nullptr, nullptr, 0, o2, 1, MM, 1536, 1536, 1536, 1, 0, 0, 1, 0, 0, 0, 0);
  gemm(1, 1, o2, cW_g3, g3_b, nullptr, nullptr, 0, o3, 1, MM, DD, 1536, DD, 1, 0, 0, 1, 0, 0, 0, 0);
  gemm(1, 3, o3, cW_g4, g4_b, nullptr, nullptr, 0, gbuf, 1, MM, DD, DD, DD, 1, 0, 0, 1, 0, 0, 0, 0);
  ef_ln_kernel<<<MM, 256, 0, stream>>>(gbuf, Ea, cc, ln_w, ln_b, xb16);   // x = LN(Ef)

  // --- multi-scale convs; U layout [U5,U3,U1,U5dup] ---
  gemm(1, 0, xb16, w5r, c5_b, nullptr, nullptr, 0, U, 1, MM, DD, DD, DD, 5, 2, 589824, 1, 0, 0, 0, 0);
  gemm(1, 0, xb16, w3r, c3_b, nullptr, nullptr, 0, U + MDL, 1, MM, DD, DD, DD, 3, 1, 589824, 1, 0, 0, 0, 0);
  gemm(1, 0, xb16, cW_c1, c1_b, nullptr, nullptr, 0, U + 2 * MDL, 1, MM, DD, DD, DD, 1, 0, 0, 1, 0, 0, 0, 0);
  copy16<<<1536, 256, 0, stream>>>(U, U + 3 * MDL);   // U5dup

  // --- 3 fastformer layers, batched z=3: hid=U+z*MDL, ctx=U+(z+1)*MDL ---
  gemm(1, 0, U,       cW_q, q_b, nullptr, nullptr, 0, qbuf,  1, MM, DD, DD, DD, 1, 0, 0, 3, MDL, 0, MDL, 0);
  gemm(1, 0, U + MDL, cW_k, k_b, nullptr, nullptr, 0, ctxkk, 1, MM, DD, DD, DD, 1, 0, 0, 3, MDL, 0, MDL, 0);
  lin_small<<<3 * MM / 4, 256, 0, stream>>>(qbuf,  qa_w, qa_b, 0.125f, qsf);
  lin_small<<<3 * MM / 4, 256, 0, stream>>>(ctxkk, ka_w, ka_b, 0.125f, ksf);
  scores_softmax<<<3 * MM, 256, 0, stream>>>(qsf, ksf, awb);
  transpose_kernel<<<dim3(24, 16, 24), dim3(32, 8), 0, stream>>>(ctxkk, kkTsf);
  gemm(1, 0, awb, kkTsf, nullptr, nullptr, nullptr, 0, ctxkk, 1, TT, DD, TT, DD,
       1, 0, 0, 24, (long)TT * TT, (long)DD * TT, (long)TT * DD, 0);
  gemm(1, 0, ctxkk, cW_tr, tr_b, nullptr, qbuf, 1, kkTsf, 1, MM, DD, DD, DD, 1, 0, 0, 3, MDL, 0, MDL, MDL);
  gemm(1, 0, kkTsf, cW_ao, ao_b, nullptr, U,    1, attp,  1, MM, DD, DD, DD, 1, 0, 0, 3, MDL, 0, MDL, MDL);
  ln_kernel<<<3 * MM, 256, 0, stream>>>(attp, 1, fln_w, fln_b, nullptr, attb, 0);
  // FFN: batched z=3 on 128x64 tile (grid 4608 / 1152 blocks, 3 blocks/CU)
  gemm(1, 2, attb, cW_fi, fi_b, nullptr, nullptr, 0, interb3, 1,
       MM, FFN, DD, FFN, 1, 0, 0, 3, MDL, 0, (long)MM * FFN, 0);
  gemm(1, 0, interb3, cW_fo, fo_b, nullptr, attb, 1, outp, 1,
       MM, DD, FFN, DD, 1, 0, 0, 3, (long)MM * FFN, 0, MDL, MDL);
  ln3sum_kernel<<<MM, 256, 0, stream>>>(outp, fln_w, fln_b, ln_w, ln_b, PnB);

  // --- tail ---
  gemm(1, 2, PnB, cW_m1, m1_b, nullptr, nullptr, 0, interb, 1, MM, FFN, DD, FFN, 1, 0, 0, 1, 0, 0, 0, 0);
  gemm(1, 0, interb, cW_m2, m2_b, nullptr, xb16, 1, Jb, 0, MM, DD, FFN, DD, 1, 0, 0, 1, 0, 0, 0, 0);
  ln_kernel<<<MM, 256, 0, stream>>>(Jb, 0, ln_w, ln_b, nullptr, Jn, 0);
  gemm(1, 0, Jn, cW_out, out_b, nullptr, nullptr, 0, d_out, 0, MM, DD, DD, DD, 1, 0, 0, 1, 0, 0, 0, 0);
}

// Round 5
// 1350.157 us; speedup vs baseline: 1.3613x; 1.0368x over previous
//
#include <hip/hip_runtime.h>
#include <math.h>

// MFFNet forward on MI355X. fp32 in/out; all GEMMs bf16-MFMA with fp32 acc.
// GEMM core: double-buffered LDS, T2 XOR chunk-swizzle (both-sides),
// counted vmcnt (T4), setprio (T5). THIS REVISION: strength-reduced staging
// (per-thread global pointers advanced +64/step; bounds+mul hoisted per tap),
// k-loop unrolled x2 for static buffer select (ds_read addrs -> immediates),
// NTAPS templated. N>=1536 GEMMs on 128x128 tile; rest 128x64 (3 blocks/CU).

typedef unsigned short u16;
typedef __attribute__((ext_vector_type(8))) short short8;     // 8 bf16
typedef __attribute__((ext_vector_type(8))) unsigned short us8;
typedef __attribute__((ext_vector_type(4))) float floatx4;
typedef unsigned __attribute__((address_space(1))) gu32;
typedef unsigned __attribute__((address_space(3))) lu32;

#define DD 768
#define TT 512
#define BB 8
#define MM 4096      // B*T rows
#define FFN 3072
#define MDL ((long)MM * DD)

__device__ __forceinline__ float b2f(u16 u) {
  union { unsigned u32; float f; } x; x.u32 = ((unsigned)u) << 16; return x.f;
}
__device__ __forceinline__ u16 f2b(float f) {   // round-to-nearest-even
  union { float f; unsigned u; } x; x.f = f;
  unsigned r = x.u + 0x7FFFu + ((x.u >> 16) & 1u);
  return (u16)(r >> 16);
}

// ---------------------------------------------------------------------------
// GEMM: C[M,N] = act(A[M,K] @ W[N,K]^T + bias + rowBias + resid)
// A, W bf16. 4 waves; BK=64; LDS stride 64 els; double-buffered, 2x unrolled.
// Staging via pointer arrays advanced +64 els/step (strength-reduced; OOB rows
// use a 8K-element zero page that tolerates the walk). T2 swizzle chunk^=row&7
// on global source + ds_read (both-sides, rule #21). Counted vmcnt(LT) keeps
// the newest tile's loads in flight across compute. nk = K/64 must be EVEN
// (true for K in {512,768,1536,3072,4608}).
// OP: 0=none 1=relu 2=gelu 3=sigmoid. NTAPS/pad = conv-over-T.
// ---------------------------------------------------------------------------
template<int BM, int BN, int OP, int NTAPS>
__global__ __launch_bounds__(256)
void gemm_bt(const u16* __restrict__ A, const u16* __restrict__ W,
             const float* __restrict__ bias, const float* __restrict__ rowBias,
             const void* __restrict__ residv, void* __restrict__ Cv,
             int N, int K, int ldc, int rBf16, int outBf16,
             int pad, long wtapStride,
             long aBatch, long wBatch, long cBatch, long rBatch,
             const u16* __restrict__ zp)
{
  __shared__ __align__(16) u16 sA[2][BM * 64];
  __shared__ __align__(16) u16 sB[2][BN * 64];
  const int tid  = threadIdx.x;
  const int lane = tid & 63;
  const int wv   = tid >> 6;

  // XCD swizzle: contiguous tile range per XCD
  int gx = gridDim.x, gy = gridDim.y;
  int bn = blockIdx.y * gx + blockIdx.x;
  int Tt = gx * gy;
  if ((Tt & 7) == 0) bn = (bn & 7) * (Tt >> 3) + (bn >> 3);
  const int m0 = (bn / gx) * BM;
  const int n0 = (bn % gx) * BN;
  const u16* Ab  = A + (long)blockIdx.z * aBatch;
  const u16* Wb0 = W + (long)blockIdx.z * wBatch;

  constexpr int NI = (BM == 128 && BN == 128) ? 4 : (BM == 128 ? 2 : 1);
  constexpr int NJ = 4;
  int wr, wc;
  if constexpr (BM == 128 && BN == 128) { wr = (wv >> 1) * 64; wc = (wv & 1) * 64; }
  else if constexpr (BM == 128)          { wr = wv * 32;        wc = 0; }
  else                                    { wr = wv * 16;        wc = 0; }

  floatx4 acc[NI][NJ];
#pragma unroll
  for (int i = 0; i < NI; ++i)
#pragma unroll
    for (int j = 0; j < NJ; ++j) acc[i][j] = (floatx4){0.f, 0.f, 0.f, 0.f};

  const int mrow = lane & 15;
  const int ksub = (lane >> 4) * 8;

  constexpr int LA = BM / 32, LB = BN / 32, LT = LA + LB;
  const u16* aP[LA];
  const u16* wP[LB];

  auto stage = [&](u16* sAb, u16* sBb) {
#pragma unroll
    for (int it = 0; it < LA; ++it) {
      int slot = it * 256 + tid;
      __builtin_amdgcn_global_load_lds((const gu32*)aP[it],
                                       (lu32*)((char*)sAb + slot * 16), 16, 0, 0);
      aP[it] += 64;
    }
#pragma unroll
    for (int it = 0; it < LB; ++it) {
      int slot = it * 256 + tid;
      __builtin_amdgcn_global_load_lds((const gu32*)wP[it],
                                       (lu32*)((char*)sBb + slot * 16), 16, 0, 0);
      wP[it] += 64;
    }
  };

  auto compute = [&](const u16* sAb, const u16* sBb) {
    __builtin_amdgcn_s_setprio(1);
#pragma unroll
    for (int kb = 0; kb < 64; kb += 32) {
      const int ch0 = (kb + ksub) >> 3;            // logical chunk 0..7
      short8 af[NI], bfr[NJ];
#pragma unroll
      for (int i = 0; i < NI; ++i) {
        int ra = wr + i * 16 + mrow;
        af[i] = *(const short8*)(sAb + ra * 64 + ((ch0 ^ (ra & 7)) << 3));
      }
#pragma unroll
      for (int j = 0; j < NJ; ++j) {
        int rb = wc + j * 16 + mrow;
        bfr[j] = *(const short8*)(sBb + rb * 64 + ((ch0 ^ (rb & 7)) << 3));
      }
#pragma unroll
      for (int i = 0; i < NI; ++i)
#pragma unroll
        for (int j = 0; j < NJ; ++j)
          acc[i][j] = __builtin_amdgcn_mfma_f32_16x16x32_bf16(af[i], bfr[j], acc[i][j], 0, 0, 0);
    }
    __builtin_amdgcn_s_setprio(0);
  };

  auto waitp = [&]() {   // wait: newest stage (LT loads) may stay in flight
    if constexpr (LT == 6) asm volatile("s_waitcnt vmcnt(6)" ::: "memory");
    else                   asm volatile("s_waitcnt vmcnt(8)" ::: "memory");
  };

  const int nk = K >> 6;   // EVEN for all shapes used

  for (int tap = 0; tap < NTAPS; ++tap) {
    // per-tap pointer setup (bounds check + row*K multiply hoisted here)
    if constexpr (NTAPS == 1) {
#pragma unroll
      for (int it = 0; it < LA; ++it) {
        int slot = it * 256 + tid;
        int row = slot >> 3;
        int col = ((slot ^ row) & 7) * 8;          // T2 source swizzle
        aP[it] = Ab + (long)(m0 + row) * K + col;
      }
#pragma unroll
      for (int it = 0; it < LB; ++it) {
        int slot = it * 256 + tid;
        int row = slot >> 3;
        int col = ((slot ^ row) & 7) * 8;
        wP[it] = Wb0 + (long)(n0 + row) * K + col;
      }
    } else {
      const int dt = tap - pad;
      const u16* Wt = Wb0 + (long)tap * wtapStride;
#pragma unroll
      for (int it = 0; it < LA; ++it) {
        int slot = it * 256 + tid;
        int row = slot >> 3;
        int col = ((slot ^ row) & 7) * 8;
        int gr = m0 + row;
        int t  = gr & (TT - 1);
        aP[it] = ((unsigned)(t + dt) < (unsigned)TT)
               ? (Ab + (long)(gr + dt) * K + col) : (zp + col);  // zp walk-safe
      }
#pragma unroll
      for (int it = 0; it < LB; ++it) {
        int slot = it * 256 + tid;
        int row = slot >> 3;
        int col = ((slot ^ row) & 7) * 8;
        wP[it] = Wt + (long)(n0 + row) * K + col;
      }
    }

    stage(&sA[0][0], &sB[0][0]);                   // tile 0 -> buf0
    for (int s = 0; s < nk; s += 2) {
      // half-iter A: stage s+1 -> buf1, compute s from buf0
      stage(&sA[1][0], &sB[1][0]);
      waitp();
      __builtin_amdgcn_s_barrier();
      compute(&sA[0][0], &sB[0][0]);
      __builtin_amdgcn_s_barrier();
      // half-iter B: stage s+2 -> buf0 (unless done), compute s+1 from buf1
      if (s + 2 < nk) { stage(&sA[0][0], &sB[0][0]); waitp(); }
      else asm volatile("s_waitcnt vmcnt(0)" ::: "memory");
      __builtin_amdgcn_s_barrier();
      compute(&sA[1][0], &sB[1][0]);
      __builtin_amdgcn_s_barrier();
    }
  }

  // epilogue: C/D layout col=lane&15, row=(lane>>4)*4+reg (m89-verified)
  const int cn = lane & 15;
  const int rq = (lane >> 4) * 4;
  u16*   Ch = (u16*)Cv   + (long)blockIdx.z * cBatch;
  float* Cf = (float*)Cv + (long)blockIdx.z * cBatch;
  const long zr = (long)blockIdx.z * rBatch;
#pragma unroll
  for (int j = 0; j < NJ; ++j) {
    int gn = n0 + wc + j * 16 + cn;
    float bv = bias ? bias[gn] : 0.f;
#pragma unroll
    for (int i = 0; i < NI; ++i) {
#pragma unroll
      for (int r = 0; r < 4; ++r) {
        int gm = m0 + wr + i * 16 + rq + r;
        long idx = (long)gm * ldc + gn;
        float v = acc[i][j][r] + bv;
        if (rowBias) v += rowBias[(gm >> 9) * N + gn];
        if (residv)
          v += rBf16 ? b2f(((const u16*)residv)[idx + zr]) : ((const float*)residv)[idx + zr];
        if (OP == 1) v = fmaxf(v, 0.f);
        if (OP == 2) v = 0.5f * v * (1.f + erff(v * 0.70710678118654752440f));
        if (OP == 3) v = 1.f / (1.f + expf(-v));
        if (outBf16) Ch[idx] = f2b(v);
        else Cf[idx] = v;
      }
    }
  }
}

// ---------------------------------------------------------------------------
// bulk fp32 -> bf16 conversion with row remap (pitch) + per-b scale.
// ---------------------------------------------------------------------------
#define NJOBS 27
struct ConvJobs {
  const float* src[NJOBS];
  u16* dst[NJOBS];
  int n2[NJOBS];         // pairs (8 floats) per job
  int rowLen2[NJOBS];    // pairs per source row
  int dstPitch2[NJOBS];  // dst row pitch in pairs
  const float* scl[NJOBS];  // per-(row>>9) scale or null
};
__global__ void convert_all(ConvJobs J, long total2)
{
  long g = (long)blockIdx.x * 256 + threadIdx.x;
  if (g >= total2) return;
  int j = 0; long off = g;
  while (off >= J.n2[j]) { off -= J.n2[j]; ++j; }
  long row = off / J.rowLen2[j];
  long c2  = off - row * J.rowLen2[j];
  const float4* s = (const float4*)J.src[j] + off * 2;
  float4 x = s[0], y = s[1];
  float sc = J.scl[j] ? J.scl[j][row >> 9] : 1.f;
  us8 h;
  h[0] = f2b(x.x * sc); h[1] = f2b(x.y * sc); h[2] = f2b(x.z * sc); h[3] = f2b(x.w * sc);
  h[4] = f2b(y.x * sc); h[5] = f2b(y.y * sc); h[6] = f2b(y.z * sc); h[7] = f2b(y.w * sc);
  *(us8*)(J.dst[j] + (row * (long)J.dstPitch2[j] + c2) * 8) = h;
}

__global__ void zero_kernel(u16* zp)
{
  int i = blockIdx.x * 256 + threadIdx.x;
  if (i < 8192) zp[i] = 0;
}

__global__ void copy16(const u16* __restrict__ s, u16* __restrict__ d)
{
  long g = (long)blockIdx.x * 256 + threadIdx.x;
  *(us8*)(d + g * 8) = *(const us8*)(s + g * 8);
}

// LayerNorm over D=768; input fp32 or bf16; out fp32 or bf16
__global__ void ln_kernel(const void* __restrict__ x, int xBf16,
                          const float* __restrict__ w, const float* __restrict__ b,
                          float* __restrict__ y32, u16* __restrict__ y16, int accum)
{
  const int row = blockIdx.x;
  const int tid = threadIdx.x;
  __shared__ float rs[256], rq[256];
  float v[3];
  long base = (long)row * DD;
  float s = 0.f, q = 0.f;
#pragma unroll
  for (int i = 0; i < 3; ++i) {
    int c = tid + i * 256;
    float t = xBf16 ? b2f(((const u16*)x)[base + c]) : ((const float*)x)[base + c];
    v[i] = t; s += t; q += t * t;
  }
  rs[tid] = s; rq[tid] = q; __syncthreads();
  for (int st = 128; st > 0; st >>= 1) {
    if (tid < st) { rs[tid] += rs[tid + st]; rq[tid] += rq[tid + st]; }
    __syncthreads();
  }
  float mean = rs[0] * (1.f / DD);
  float var  = fmaxf(rq[0] * (1.f / DD) - mean * mean, 0.f);
  float rstd = rsqrtf(var + 1e-12f);
#pragma unroll
  for (int i = 0; i < 3; ++i) {
    int c = tid + i * 256;
    float o = ((v[i] - mean) * rstd) * w[c] + b[c];
    if (y32) { if (accum) y32[base + c] += o; else y32[base + c] = o; }
    if (y16) {
      if (accum && !y32) y16[base + c] = f2b(b2f(y16[base + c]) + o);
      else y16[base + c] = f2b(o);
    }
  }
}

// Ef = g*Ea + (1-g)*Et, then LN(Ef) -> bf16. Et read from cc left half (pitch 1536).
__global__ void ef_ln_kernel(const u16* __restrict__ g, const float* __restrict__ Ea,
                             const u16* __restrict__ EtC,
                             const float* __restrict__ w, const float* __restrict__ b,
                             u16* __restrict__ xo)
{
  const int row = blockIdx.x;
  const int tid = threadIdx.x;
  __shared__ float rs[256], rq[256];
  float v[3];
  float s = 0.f, q = 0.f;
#pragma unroll
  for (int i = 0; i < 3; ++i) {
    int c = tid + i * 256;
    float gv = b2f(g[(long)row * DD + c]);
    float et = b2f(EtC[(long)row * 1536 + c]);
    float e  = gv * Ea[(long)row * DD + c] + (1.f - gv) * et;
    v[i] = e; s += e; q += e * e;
  }
  rs[tid] = s; rq[tid] = q; __syncthreads();
  for (int st = 128; st > 0; st >>= 1) {
    if (tid < st) { rs[tid] += rs[tid + st]; rq[tid] += rq[tid + st]; }
    __syncthreads();
  }
  float mean = rs[0] * (1.f / DD);
  float var  = fmaxf(rq[0] * (1.f / DD) - mean * mean, 0.f);
  float rstd = rsqrtf(var + 1e-12f);
#pragma unroll
  for (int i = 0; i < 3; ++i) {
    int c = tid + i * 256;
    xo[(long)row * DD + c] = f2b(((v[i] - mean) * rstd) * w[c] + b[c]);
  }
}

// Pn = LN( sum_z LN(outp[z], fln) , ln ). Sum in f32.
__global__ void ln3sum_kernel(const u16* __restrict__ o,
                              const float* __restrict__ fw, const float* __restrict__ fb,
                              const float* __restrict__ lw, const float* __restrict__ lb,
                              u16* __restrict__ Pn)
{
  const int row = blockIdx.x;
  const int tid = threadIdx.x;
  __shared__ float rs[256], rq[256];
  float v[3][3], mz[3], rz[3];
  for (int z = 0; z < 3; ++z) {
    long base = (long)z * MDL + (long)row * DD;
    float s = 0.f, q = 0.f;
#pragma unroll
    for (int i = 0; i < 3; ++i) {
      int c = tid + i * 256;
      float t = b2f(o[base + c]);
      v[z][i] = t; s += t; q += t * t;
    }
    rs[tid] = s; rq[tid] = q; __syncthreads();
    for (int st = 128; st > 0; st >>= 1) {
      if (tid < st) { rs[tid] += rs[tid + st]; rq[tid] += rq[tid + st]; }
      __syncthreads();
    }
    float mean = rs[0] * (1.f / DD);
    float var  = fmaxf(rq[0] * (1.f / DD) - mean * mean, 0.f);
    mz[z] = mean; rz[z] = rsqrtf(var + 1e-12f);
    __syncthreads();
  }
  float p[3];
  float s = 0.f, q = 0.f;
#pragma unroll
  for (int i = 0; i < 3; ++i) {
    int c = tid + i * 256;
    float pv = 0.f;
#pragma unroll
    for (int z = 0; z < 3; ++z) pv += (v[z][i] - mz[z]) * rz[z];
    pv = pv * fw[c] + 3.f * fb[c];
    p[i] = pv; s += pv; q += pv * pv;
  }
  rs[tid] = s; rq[tid] = q; __syncthreads();
  for (int st = 128; st > 0; st >>= 1) {
    if (tid < st) { rs[tid] += rs[tid + st]; rq[tid] += rq[tid + st]; }
    __syncthreads();
  }
  float mean = rs[0] * (1.f / DD);
  float var  = fmaxf(rq[0] * (1.f / DD) - mean * mean, 0.f);
  float rstd = rsqrtf(var + 1e-12f);
#pragma unroll
  for (int i = 0; i < 3; ++i) {
    int c = tid + i * 256;
    Pn[(long)row * DD + c] = f2b(((p[i] - mean) * rstd) * lw[c] + lb[c]);
  }
}

// all 6 streams' rowmeans in one launch
__global__ void rowmean_all(const float* f0, const float* f1, const float* f2,
                            const float* f3, const float* f4, const float* f5,
                            float* __restrict__ rm)
{
  const float* fs[6] = {f0, f1, f2, f3, f4, f5};
  int n = blockIdx.y;
  int b = blockIdx.x / 3, chunk = blockIdx.x % 3;
  int d = chunk * 256 + threadIdx.x;
  const float* base = fs[n] + (long)b * TT * DD + d;
  float s = 0.f;
  for (int t = 0; t < TT; ++t) s += base[(long)t * DD];
  rm[((long)n * BB + b) * DD + d] = s * (1.f / TT);
}

__global__ void colsum_kernel(const float* __restrict__ w, float* __restrict__ cs)
{
  int n = blockIdx.x / 3, chunk = blockIdx.x % 3;
  int e = chunk * 256 + threadIdx.x;
  const float* base = w + (long)n * DD * DD + e;
  float s = 0.f;
  for (int d = 0; d < DD; ++d) s += base[(long)d * DD];
  cs[n * DD + e] = s;
}

__global__ void fusion_weights(const float* __restrict__ rm, const float* __restrict__ cs,
                               const float* __restrict__ align_b,
                               const float* __restrict__ aw, const float* __restrict__ ab,
                               float* __restrict__ wpT)
{
  __shared__ float msh[48];
  int tid = threadIdx.x;
  if (tid < 48) {
    int b = tid / 6, n = tid % 6;
    const float* r = rm + ((long)n * BB + b) * DD;
    const float* c = cs + n * DD;
    float dot = 0.f, bs = 0.f;
    for (int e = 0; e < DD; ++e) dot += r[e] * c[e];
    for (int d = 0; d < DD; ++d) bs += align_b[n * DD + d];
    msh[b * 6 + n] = (dot + bs) * (1.f / DD);
  }
  __syncthreads();
  if (tid < BB) {
    int b = tid;
    float z[6];
#pragma unroll
    for (int n = 0; n < 6; ++n) {
      float s = ab[n];
#pragma unroll
      for (int j = 0; j < 6; ++j)
        s += (aw[n * 12 + j] + aw[n * 12 + 6 + j]) * msh[b * 6 + j];
      z[n] = fmaxf(s, 0.f);
    }
    float mx = z[0];
#pragma unroll
    for (int n = 1; n < 6; ++n) mx = fmaxf(mx, z[n]);
    float se = 0.f, e[6];
#pragma unroll
    for (int n = 0; n < 6; ++n) { e[n] = expf(z[n] - mx); se += e[n]; }
#pragma unroll
    for (int n = 0; n < 6; ++n) wpT[n * 8 + b] = e[n] / se + (1.f / 6.f);
  }
}

// rb[b,d] = sum_n wplus[b,n] * align_b[n,d]
__global__ void rowbias_kernel(const float* __restrict__ wpT, const float* __restrict__ ab,
                               float* __restrict__ rb)
{
  int b = blockIdx.x / 3;
  int d = (blockIdx.x % 3) * 256 + threadIdx.x;
  float s = 0.f;
#pragma unroll
  for (int n = 0; n < 6; ++n) s += wpT[n * 8 + b] * ab[n * DD + d];
  rb[b * DD + d] = s;
}

// conv weight [O,I,KT] fp32 -> [KT][O][I] bf16
__global__ void repack_conv(const float* __restrict__ src, u16* __restrict__ dst, int KT)
{
  long e = (long)blockIdx.x * 256 + threadIdx.x;
  if (e >= (long)KT * DD * DD) return;
  int k = (int)(e / (DD * DD));
  int rem = (int)(e - (long)k * DD * DD);
  int o = rem / DD, i = rem % DD;
  dst[e] = f2b(src[((long)o * DD + i) * KT + k]);
}

// out[row,h] = (X[row,:] . Wt[h,:] + bias[h]) * scale ; H=12, X bf16
__global__ void lin_small(const u16* __restrict__ X, const float* __restrict__ Wt,
                          const float* __restrict__ bias, float scale,
                          float* __restrict__ out)
{
  int row = blockIdx.x * 4 + (threadIdx.x >> 6);
  int lane = threadIdx.x & 63;
  float acc[12];
#pragma unroll
  for (int h = 0; h < 12; ++h) acc[h] = 0.f;
  for (int k = lane; k < DD; k += 64) {
    float xv = b2f(X[(long)row * DD + k]);
#pragma unroll
    for (int h = 0; h < 12; ++h) acc[h] += xv * Wt[h * DD + k];
  }
#pragma unroll
  for (int h = 0; h < 12; ++h)
    for (int off = 32; off > 0; off >>= 1) acc[h] += __shfl_down(acc[h], off);
  if (lane == 0) {
#pragma unroll
    for (int h = 0; h < 12; ++h)
      out[(long)row * 12 + h] = (acc[h] + bias[h]) * scale;
  }
}

__global__ void scores_softmax(const float* __restrict__ qs, const float* __restrict__ ks,
                               u16* __restrict__ aw)
{
  int bs = blockIdx.x;            // global (z*8+b)*512+s
  int b = bs >> 9;
  int tid = threadIdx.x;
  __shared__ float qsh[12];
  __shared__ float red[256];
  if (tid < 12) qsh[tid] = qs[(long)bs * 12 + tid];
  __syncthreads();
  float sc[2];
#pragma unroll
  for (int p = 0; p < 2; ++p) {
    int c = tid + p * 256;
    const float* kr = ks + (long)(b * 512 + c) * 12;
    float v = 0.f;
#pragma unroll
    for (int h = 0; h < 12; ++h) v += qsh[h] * kr[h];
    sc[p] = v;
  }
  red[tid] = fmaxf(sc[0], sc[1]); __syncthreads();
  for (int st = 128; st > 0; st >>= 1) {
    if (tid < st) red[tid] = fmaxf(red[tid], red[tid + st]);
    __syncthreads();
  }
  float mx = red[0]; __syncthreads();
  float e0 = expf(sc[0] - mx), e1 = expf(sc[1] - mx);
  red[tid] = e0 + e1; __syncthreads();
  for (int st = 128; st > 0; st >>= 1) {
    if (tid < st) red[tid] += red[tid + st];
    __syncthreads();
  }
  float inv = 1.f / red[0];
  aw[(long)bs * 512 + tid]       = f2b(e0 * inv);
  aw[(long)bs * 512 + tid + 256] = f2b(e1 * inv);
}

__global__ void transpose_kernel(const u16* __restrict__ in, u16* __restrict__ out)
{
  int b = blockIdx.z;
  const u16* ib = in + (long)b * TT * DD;
  u16* ob = out + (long)b * TT * DD;
  __shared__ u16 tile[32][33];
  int c0 = blockIdx.x * 32;   // d
  int r0 = blockIdx.y * 32;   // t
  int tx = threadIdx.x, ty = threadIdx.y;
#pragma unroll
  for (int i = 0; i < 4; ++i)
    tile[ty + 8 * i][tx] = ib[(long)(r0 + ty + 8 * i) * DD + c0 + tx];
  __syncthreads();
#pragma unroll
  for (int i = 0; i < 4; ++i)
    ob[(long)(c0 + ty + 8 * i) * TT + r0 + tx] = tile[tx][ty + 8 * i];
}

// ---------------------------------------------------------------------------
extern "C" void kernel_launch(void* const* d_in, const int* in_sizes, int n_in,
                              void* d_out, int out_size, void* d_ws, size_t ws_size,
                              hipStream_t stream)
{
  (void)in_sizes; (void)n_in; (void)out_size; (void)ws_size;
  const float* fin[6];
  for (int i = 0; i < 6; ++i) fin[i] = (const float*)d_in[i];
  const float* Ea      = (const float*)d_in[6];
  const float* align_w = (const float*)d_in[7];
  const float* align_b = (const float*)d_in[8];
  const float* att_w   = (const float*)d_in[9];
  const float* att_b   = (const float*)d_in[10];
  const float* g1_w = (const float*)d_in[11]; const float* g1_b = (const float*)d_in[12];
  const float* g2_w = (const float*)d_in[13]; const float* g2_b = (const float*)d_in[14];
  const float* g3_w = (const float*)d_in[15]; const float* g3_b = (const float*)d_in[16];
  const float* g4_w = (const float*)d_in[17]; const float* g4_b = (const float*)d_in[18];
  const float* ln_w = (const float*)d_in[19]; const float* ln_b = (const float*)d_in[20];
  const float* c1_w = (const float*)d_in[21]; const float* c1_b = (const float*)d_in[22];
  const float* c3_w = (const float*)d_in[23]; const float* c3_b = (const float*)d_in[24];
  const float* c5_w = (const float*)d_in[25]; const float* c5_b = (const float*)d_in[26];
  const float* q_w  = (const float*)d_in[27]; const float* q_b  = (const float*)d_in[28];
  const float* qa_w = (const float*)d_in[29]; const float* qa_b = (const float*)d_in[30];
  const float* k_w  = (const float*)d_in[31]; const float* k_b  = (const float*)d_in[32];
  const float* ka_w = (const float*)d_in[33]; const float* ka_b = (const float*)d_in[34];
  const float* tr_w = (const float*)d_in[35]; const float* tr_b = (const float*)d_in[36];
  const float* ao_w = (const float*)d_in[37]; const float* ao_b = (const float*)d_in[38];
  const float* fln_w = (const float*)d_in[39]; const float* fln_b = (const float*)d_in[40];
  const float* fi_w = (const float*)d_in[41]; const float* fi_b = (const float*)d_in[42];
  const float* fo_w = (const float*)d_in[43]; const float* fo_b = (const float*)d_in[44];
  const float* m1_w = (const float*)d_in[45]; const float* m1_b = (const float*)d_in[46];
  const float* m2_w = (const float*)d_in[47]; const float* m2_b = (const float*)d_in[48];
  const float* out_w = (const float*)d_in[49]; const float* out_b = (const float*)d_in[50];

  char* ws = (char*)d_ws;
  size_t off = 0;
  auto alloc = [&](size_t bytes) -> char* {
    char* p = ws + off;
    off += bytes;
    off = (off + 255) & ~(size_t)255;
    return p;
  };

  // small scratch
  u16*   zp    = (u16*)alloc(16384);   // 8K-element zero page (pointer-walk safe)
  float* rmb   = (float*)alloc(6L * BB * DD * 4);
  float* csb   = (float*)alloc(6L * DD * 4);
  float* wpT   = (float*)alloc(48 * 4);
  float* rbias = (float*)alloc((long)BB * DD * 4);
  float* qsf   = (float*)alloc(3L * MM * 12 * 4);
  float* ksf   = (float*)alloc(3L * MM * 12 * 4);

  // bf16 weight cache (55.4 MB); cW_al is the K-concatenated align weight
  u16* Wc = (u16*)alloc(27721728L * 2);
  u16* cW_g1   = Wc;
  u16* cW_g2   = Wc + 2359296L;
  u16* cW_fi   = Wc + 4718592L;
  u16* cW_fo   = Wc + 7077888L;
  u16* cW_m1   = Wc + 9437184L;
  u16* cW_m2   = Wc + 11796480L;
  u16* cW_g3   = Wc + 14155776L;
  u16* cW_al   = Wc + 15335424L;
  u16* cW_g4   = Wc + 18874368L;
  u16* cW_c1   = Wc + 19464192L;
  u16* cW_q    = Wc + 20054016L;
  u16* cW_k    = Wc + 20643840L;
  u16* cW_tr   = Wc + 21233664L;
  u16* cW_ao   = Wc + 21823488L;
  u16* cW_out  = Wc + 22413312L;
  u16* w3r     = Wc + 23003136L;
  u16* w5r     = Wc + 24772608L;

  // big aliased regions (~184 MB); R1,R3,R4 are CONTIGUOUS (sizes 256-aligned)
  char* R1 = alloc((long)MM * 4608 * 2);  // A' -> qbuf -> [interb3 head] -> Jb
  char* R3 = alloc(MDL * 8);              // cc+o1 -> ctxkk -> [interb3] -> Pn+Jn
  char* R4 = alloc(MDL * 8);              // o2+o3+gb -> kkTsf -> [interb3 tail]
  char* R5 = alloc(MDL * 2);              // xb16 (persistent)
  char* R6 = alloc(MDL * 8);              // U = [U5,U3,U1,U5dup]
  char* R8 = alloc(MDL * 6);              // attp -> outp (3 layers)
  char* R9 = alloc(MDL * 6);              // attb (3 layers)
  char* R10 = alloc((long)MM * FFN * 2);  // awb -> interb (m1/m2)

  u16*   Ap    = (u16*)R1;
  u16*   qbuf  = (u16*)R1;
  float* Jb    = (float*)R1;
  u16*   interb3 = (u16*)R1;               // 75.5 MB spans R1+R3+R4 (fi->fo only)
  u16*   cc    = (u16*)R3;                 // [MM][1536]: left=Et(b16), right=Ea(b16)
  u16*   o1    = (u16*)R3 + 2 * MDL;
  u16*   ctxkk = (u16*)R3;
  u16*   PnB   = (u16*)R3;
  u16*   Jn    = (u16*)R3 + MDL;
  u16*   o2    = (u16*)R4;
  u16*   o3    = (u16*)R4 + 2 * MDL;
  u16*   gbuf  = (u16*)R4 + 3 * MDL;
  u16*   kkTsf = (u16*)R4;
  u16*   xb16  = (u16*)R5;
  u16*   U     = (u16*)R6;
  u16*   attp  = (u16*)R8;
  u16*   outp  = (u16*)R8;
  u16*   attb  = (u16*)R9;
  u16*   awb   = (u16*)R10;
  u16*   interb = (u16*)R10;

  // tile: 1 = 128x64, 2 = 128x128 (N>=1536 GEMMs)
  auto gemm = [&](int tile, int op, int ntaps, const u16* A, const u16* W,
                  const float* bias, const float* rowBias,
                  const void* resid, int rB, void* Cc, int oB,
                  int Mi, int Ni, int Ki, int ldc,
                  int pad, long wtap,
                  int batch, long ab, long wb, long cb, long rbch) {
#define GL(BM, BN, OPV, NT) gemm_bt<BM, BN, OPV, NT><<<dim3(Ni / BN, Mi / BM, batch), 256, 0, stream>>>( \
      A, W, bias, rowBias, resid, Cc, Ni, Ki, ldc, rB, oB, pad, wtap, ab, wb, cb, rbch, zp)
    if (tile == 2) {
      if (op == 1) GL(128, 128, 1, 1);
      else         GL(128, 128, 2, 1);
    } else if (ntaps == 5) GL(128, 64, 0, 5);
    else if (ntaps == 3)   GL(128, 64, 0, 3);
    else if (op == 1)      GL(128, 64, 1, 1);
    else if (op == 3)      GL(128, 64, 3, 1);
    else                   GL(128, 64, 0, 1);
#undef GL
  };

  zero_kernel<<<32, 256, 0, stream>>>(zp);

  // --- fusion weights first (analytic means over fp32 inputs) ---
  rowmean_all<<<dim3(24, 6), 256, 0, stream>>>(fin[0], fin[1], fin[2], fin[3], fin[4], fin[5], rmb);
  colsum_kernel<<<18, 256, 0, stream>>>(align_w, csb);
  fusion_weights<<<1, 64, 0, stream>>>(rmb, csb, align_b, att_w, att_b, wpT);
  rowbias_kernel<<<24, 256, 0, stream>>>(wpT, align_b, rbias);

  // --- bulk conversion: weights + wplus-scaled interleaved A' + Ea->cc right half ---
  {
    ConvJobs J;
    int idx = 0;
    long total2 = 0;
    auto add = [&](const float* s, u16* d, int n2v, int rl2, int dp2, const float* sc) {
      J.src[idx] = s; J.dst[idx] = d; J.n2[idx] = n2v;
      J.rowLen2[idx] = rl2; J.dstPitch2[idx] = dp2; J.scl[idx] = sc;
      total2 += n2v; ++idx;
    };
    for (int n = 0; n < 6; ++n)                       // A'[row][n*768+k] = wplus*f_n
      add(fin[n], Ap + n * DD, 393216, 96, 576, wpT + n * 8);
    add(Ea, cc + DD, 393216, 96, 192, nullptr);       // cc right half
    add(g1_w, cW_g1, 294912, 294912, 294912, nullptr);
    add(g2_w, cW_g2, 294912, 294912, 294912, nullptr);
    add(fi_w, cW_fi, 294912, 294912, 294912, nullptr);
    add(fo_w, cW_fo, 294912, 294912, 294912, nullptr);
    add(m1_w, cW_m1, 294912, 294912, 294912, nullptr);
    add(m2_w, cW_m2, 294912, 294912, 294912, nullptr);
    add(g3_w, cW_g3, 147456, 147456, 147456, nullptr);
    for (int n = 0; n < 6; ++n)                       // W'[o][n*768+k] = align_w[n][o][k]
      add(align_w + (long)n * 589824, cW_al + n * DD, 73728, 96, 576, nullptr);
    add(g4_w, cW_g4, 73728, 73728, 73728, nullptr);
    add(c1_w, cW_c1, 73728, 73728, 73728, nullptr);
    add(q_w,  cW_q,  73728, 73728, 73728, nullptr);
    add(k_w,  cW_k,  73728, 73728, 73728, nullptr);
    add(tr_w, cW_tr, 73728, 73728, 73728, nullptr);
    add(ao_w, cW_ao, 73728, 73728, 73728, nullptr);
    add(out_w, cW_out, 73728, 73728, 73728, nullptr);
    convert_all<<<(int)((total2 + 255) / 256), 256, 0, stream>>>(J, total2);
  }
  repack_conv<<<(3 * 589824 + 255) / 256, 256, 0, stream>>>(c3_w, w3r, 3);
  repack_conv<<<(5 * 589824 + 255) / 256, 256, 0, stream>>>(c5_w, w5r, 5);

  // --- FeatureAlignment: ONE GEMM, K=4608, writes Et(bf16) into cc left half ---
  gemm(1, 0, 1, Ap, cW_al, nullptr, rbias, nullptr, 0, cc, 1,
       MM, DD, 4608, 1536, 0, 0, 1, 0, 0, 0, 0);

  // --- GatedFusion ---
  gemm(2, 1, 1, cc, cW_g1, g1_b, nullptr, nullptr, 0, o1, 1, MM, 1536, 1536, 1536, 0, 0, 1, 0, 0, 0, 0);
  gemm(2, 1, 1, o1, cW_g2, g2_b, nullptr, nullptr, 0, o2, 1, MM, 1536, 1536, 1536, 0, 0, 1, 0, 0, 0, 0);
  gemm(1, 1, 1, o2, cW_g3, g3_b, nullptr, nullptr, 0, o3, 1, MM, DD, 1536, DD, 0, 0, 1, 0, 0, 0, 0);
  gemm(1, 3, 1, o3, cW_g4, g4_b, nullptr, nullptr, 0, gbuf, 1, MM, DD, DD, DD, 0, 0, 1, 0, 0, 0, 0);
  ef_ln_kernel<<<MM, 256, 0, stream>>>(gbuf, Ea, cc, ln_w, ln_b, xb16);   // x = LN(Ef)

  // --- multi-scale convs; U layout [U5,U3,U1,U5dup] ---
  gemm(1, 0, 5, xb16, w5r, c5_b, nullptr, nullptr, 0, U, 1, MM, DD, DD, DD, 2, 589824, 1, 0, 0, 0, 0);
  gemm(1, 0, 3, xb16, w3r, c3_b, nullptr, nullptr, 0, U + MDL, 1, MM, DD, DD, DD, 1, 589824, 1, 0, 0, 0, 0);
  gemm(1, 0, 1, xb16, cW_c1, c1_b, nullptr, nullptr, 0, U + 2 * MDL, 1, MM, DD, DD, DD, 0, 0, 1, 0, 0, 0, 0);
  copy16<<<1536, 256, 0, stream>>>(U, U + 3 * MDL);   // U5dup

  // --- 3 fastformer layers, batched z=3: hid=U+z*MDL, ctx=U+(z+1)*MDL ---
  gemm(1, 0, 1, U,       cW_q, q_b, nullptr, nullptr, 0, qbuf,  1, MM, DD, DD, DD, 0, 0, 3, MDL, 0, MDL, 0);
  gemm(1, 0, 1, U + MDL, cW_k, k_b, nullptr, nullptr, 0, ctxkk, 1, MM, DD, DD, DD, 0, 0, 3, MDL, 0, MDL, 0);
  lin_small<<<3 * MM / 4, 256, 0, stream>>>(qbuf,  qa_w, qa_b, 0.125f, qsf);
  lin_small<<<3 * MM / 4, 256, 0, stream>>>(ctxkk, ka_w, ka_b, 0.125f, ksf);
  scores_softmax<<<3 * MM, 256, 0, stream>>>(qsf, ksf, awb);
  transpose_kernel<<<dim3(24, 16, 24), dim3(32, 8), 0, stream>>>(ctxkk, kkTsf);
  gemm(1, 0, 1, awb, kkTsf, nullptr, nullptr, nullptr, 0, ctxkk, 1, TT, DD, TT, DD,
       0, 0, 24, (long)TT * TT, (long)DD * TT, (long)TT * DD, 0);
  gemm(1, 0, 1, ctxkk, cW_tr, tr_b, nullptr, qbuf, 1, kkTsf, 1, MM, DD, DD, DD, 0, 0, 3, MDL, 0, MDL, MDL);
  gemm(1, 0, 1, kkTsf, cW_ao, ao_b, nullptr, U,    1, attp,  1, MM, DD, DD, DD, 0, 0, 3, MDL, 0, MDL, MDL);
  ln_kernel<<<3 * MM, 256, 0, stream>>>(attp, 1, fln_w, fln_b, nullptr, attb, 0);
  // FFN: batched z=3; fi on 128x128 (grid 2304), fo on 128x64 (grid 1152)
  gemm(2, 2, 1, attb, cW_fi, fi_b, nullptr, nullptr, 0, interb3, 1,
       MM, FFN, DD, FFN, 0, 0, 3, MDL, 0, (long)MM * FFN, 0);
  gemm(1, 0, 1, interb3, cW_fo, fo_b, nullptr, attb, 1, outp, 1,
       MM, DD, FFN, DD, 0, 0, 3, (long)MM * FFN, 0, MDL, MDL);
  ln3sum_kernel<<<MM, 256, 0, stream>>>(outp, fln_w, fln_b, ln_w, ln_b, PnB);

  // --- tail ---
  gemm(2, 2, 1, PnB, cW_m1, m1_b, nullptr, nullptr, 0, interb, 1, MM, FFN, DD, FFN, 0, 0, 1, 0, 0, 0, 0);
  gemm(1, 0, 1, interb, cW_m2, m2_b, nullptr, xb16, 1, Jb, 0, MM, DD, FFN, DD, 0, 0, 1, 0, 0, 0, 0);
  ln_kernel<<<MM, 256, 0, stream>>>(Jb, 0, ln_w, ln_b, nullptr, Jn, 0);
  gemm(1, 0, 1, Jn, cW_out, out_b, nullptr, nullptr, 0, d_out, 0, MM, DD, DD, DD, 0, 0, 1, 0, 0, 0, 0);
}

// Round 6
// 1207.187 us; speedup vs baseline: 1.5225x; 1.1184x over previous
//
#include <hip/hip_runtime.h>
#include <math.h>

// MFFNet forward on MI355X. fp32 in/out; all GEMMs bf16-MFMA with fp32 acc.
// GEMM core: double-buffered LDS, T2 XOR chunk-swizzle (both-sides),
// counted vmcnt (T4), setprio (T5), strength-reduced pointer staging.
// THIS REVISION: coalesced bf16 epilogue (per-wave LDS slab -> b128 reads ->
// 128B-segment global_store_dwordx4; kills partial-sector RFO traffic that
// showed as WRITE_SIZE 8x algorithmic bytes), uniform 128x64 tile (48KB LDS,
// 3 blocks/CU) for ALL GEMMs.

typedef unsigned short u16;
typedef __attribute__((ext_vector_type(8))) short short8;     // 8 bf16
typedef __attribute__((ext_vector_type(8))) unsigned short us8;
typedef __attribute__((ext_vector_type(4))) float floatx4;
typedef unsigned __attribute__((address_space(1))) gu32;
typedef unsigned __attribute__((address_space(3))) lu32;

#define DD 768
#define TT 512
#define BB 8
#define MM 4096      // B*T rows
#define FFN 3072
#define MDL ((long)MM * DD)

__device__ __forceinline__ float b2f(u16 u) {
  union { unsigned u32; float f; } x; x.u32 = ((unsigned)u) << 16; return x.f;
}
__device__ __forceinline__ u16 f2b(float f) {   // round-to-nearest-even
  union { float f; unsigned u; } x; x.f = f;
  unsigned r = x.u + 0x7FFFu + ((x.u >> 16) & 1u);
  return (u16)(r >> 16);
}

// ---------------------------------------------------------------------------
// GEMM: C[M,N] = act(A[M,K] @ W[N,K]^T + bias + rowBias + resid)
// A, W bf16. 4 waves; BM=128 BN=64; BK=64; LDS stride 64 els; double-buffered,
// 2x unrolled k-loop (static buffer select). Staging via pointer arrays
// advanced +64 els/step. T2 swizzle chunk^=row&7 on global source + ds_read.
// Counted vmcnt(6) keeps newest tile's loads in flight across compute.
// bf16 epilogue: per-wave LDS slab (stride 72, 16B-aligned rows) -> b128
// read-back -> 16B/lane coalesced stores (8x128B segments per instruction).
// nk = K/64 must be EVEN (true for K in {512,768,1536,3072,4608}).
// OP: 0=none 1=relu 2=gelu 3=sigmoid. NTAPS/pad = conv-over-T.
// ---------------------------------------------------------------------------
template<int BM, int BN, int OP, int NTAPS>
__global__ __launch_bounds__(256)
void gemm_bt(const u16* __restrict__ A, const u16* __restrict__ W,
             const float* __restrict__ bias, const float* __restrict__ rowBias,
             const void* __restrict__ residv, void* __restrict__ Cv,
             int N, int K, int ldc, int rBf16, int outBf16,
             int pad, long wtapStride,
             long aBatch, long wBatch, long cBatch, long rBatch,
             const u16* __restrict__ zp)
{
  __shared__ __align__(16) u16 smem[2 * (BM + BN) * 64];
  u16* const sAbuf = smem;                    // [2][BM*64]
  u16* const sBbuf = smem + 2 * BM * 64;      // [2][BN*64]
  const int tid  = threadIdx.x;
  const int lane = tid & 63;
  const int wv   = tid >> 6;

  // XCD swizzle: contiguous tile range per XCD
  int gx = gridDim.x, gy = gridDim.y;
  int bn = blockIdx.y * gx + blockIdx.x;
  int Tt = gx * gy;
  if ((Tt & 7) == 0) bn = (bn & 7) * (Tt >> 3) + (bn >> 3);
  const int m0 = (bn / gx) * BM;
  const int n0 = (bn % gx) * BN;
  const u16* Ab  = A + (long)blockIdx.z * aBatch;
  const u16* Wb0 = W + (long)blockIdx.z * wBatch;

  constexpr int NI = 2;                       // wave tile 32x64 (wr = wv*32)
  constexpr int NJ = 4;
  const int wr = wv * 32;
  const int wc = 0;

  floatx4 acc[NI][NJ];
#pragma unroll
  for (int i = 0; i < NI; ++i)
#pragma unroll
    for (int j = 0; j < NJ; ++j) acc[i][j] = (floatx4){0.f, 0.f, 0.f, 0.f};

  const int mrow = lane & 15;
  const int ksub = (lane >> 4) * 8;

  constexpr int LA = BM / 32, LB = BN / 32;
  const u16* aP[LA];
  const u16* wP[LB];

  auto stage = [&](u16* sAb, u16* sBb) {
#pragma unroll
    for (int it = 0; it < LA; ++it) {
      int slot = it * 256 + tid;
      __builtin_amdgcn_global_load_lds((const gu32*)aP[it],
                                       (lu32*)((char*)sAb + slot * 16), 16, 0, 0);
      aP[it] += 64;
    }
#pragma unroll
    for (int it = 0; it < LB; ++it) {
      int slot = it * 256 + tid;
      __builtin_amdgcn_global_load_lds((const gu32*)wP[it],
                                       (lu32*)((char*)sBb + slot * 16), 16, 0, 0);
      wP[it] += 64;
    }
  };

  auto compute = [&](const u16* sAb, const u16* sBb) {
    __builtin_amdgcn_s_setprio(1);
#pragma unroll
    for (int kb = 0; kb < 64; kb += 32) {
      const int ch0 = (kb + ksub) >> 3;            // logical chunk 0..7
      short8 af[NI], bfr[NJ];
#pragma unroll
      for (int i = 0; i < NI; ++i) {
        int ra = wr + i * 16 + mrow;
        af[i] = *(const short8*)(sAb + ra * 64 + ((ch0 ^ (ra & 7)) << 3));
      }
#pragma unroll
      for (int j = 0; j < NJ; ++j) {
        int rb = wc + j * 16 + mrow;
        bfr[j] = *(const short8*)(sBb + rb * 64 + ((ch0 ^ (rb & 7)) << 3));
      }
#pragma unroll
      for (int i = 0; i < NI; ++i)
#pragma unroll
        for (int j = 0; j < NJ; ++j)
          acc[i][j] = __builtin_amdgcn_mfma_f32_16x16x32_bf16(af[i], bfr[j], acc[i][j], 0, 0, 0);
    }
    __builtin_amdgcn_s_setprio(0);
  };

  auto waitp = [&]() {   // wait: newest stage (6 loads) may stay in flight
    asm volatile("s_waitcnt vmcnt(6)" ::: "memory");
  };

  const int nk = K >> 6;   // EVEN for all shapes used

  for (int tap = 0; tap < NTAPS; ++tap) {
    // per-tap pointer setup (bounds check + row*K multiply hoisted here)
    if constexpr (NTAPS == 1) {
#pragma unroll
      for (int it = 0; it < LA; ++it) {
        int slot = it * 256 + tid;
        int row = slot >> 3;
        int col = ((slot ^ row) & 7) * 8;          // T2 source swizzle
        aP[it] = Ab + (long)(m0 + row) * K + col;
      }
#pragma unroll
      for (int it = 0; it < LB; ++it) {
        int slot = it * 256 + tid;
        int row = slot >> 3;
        int col = ((slot ^ row) & 7) * 8;
        wP[it] = Wb0 + (long)(n0 + row) * K + col;
      }
    } else {
      const int dt = tap - pad;
      const u16* Wt = Wb0 + (long)tap * wtapStride;
#pragma unroll
      for (int it = 0; it < LA; ++it) {
        int slot = it * 256 + tid;
        int row = slot >> 3;
        int col = ((slot ^ row) & 7) * 8;
        int gr = m0 + row;
        int t  = gr & (TT - 1);
        aP[it] = ((unsigned)(t + dt) < (unsigned)TT)
               ? (Ab + (long)(gr + dt) * K + col) : (zp + col);  // zp walk-safe
      }
#pragma unroll
      for (int it = 0; it < LB; ++it) {
        int slot = it * 256 + tid;
        int row = slot >> 3;
        int col = ((slot ^ row) & 7) * 8;
        wP[it] = Wt + (long)(n0 + row) * K + col;
      }
    }

    stage(sAbuf, sBbuf);                           // tile 0 -> buf0
    for (int s = 0; s < nk; s += 2) {
      // half-iter A: stage s+1 -> buf1, compute s from buf0
      stage(sAbuf + BM * 64, sBbuf + BN * 64);
      waitp();
      __builtin_amdgcn_s_barrier();
      compute(sAbuf, sBbuf);
      __builtin_amdgcn_s_barrier();
      // half-iter B: stage s+2 -> buf0 (unless done), compute s+1 from buf1
      if (s + 2 < nk) { stage(sAbuf, sBbuf); waitp(); }
      else asm volatile("s_waitcnt vmcnt(0)" ::: "memory");
      __builtin_amdgcn_s_barrier();
      compute(sAbuf + BM * 64, sBbuf + BN * 64);
      __builtin_amdgcn_s_barrier();                // also fences LDS for epilogue reuse
    }
  }

  // epilogue: C/D layout col=lane&15, row=(lane>>4)*4+reg (m89-verified).
  // bf16 path: stage into per-wave LDS slab, read back b128, store 16B/lane.
  const int cn = lane & 15;
  const int rq = (lane >> 4) * 4;
  u16*   Ch = (u16*)Cv   + (long)blockIdx.z * cBatch;
  float* Cf = (float*)Cv + (long)blockIdx.z * cBatch;
  const long zr = (long)blockIdx.z * rBatch;
  constexpr int WTM = NI * 16;                     // 32 rows per wave
  u16* slab = smem + wv * (WTM * 72);              // stride 72 u16 (144B, 16B-mult)

#pragma unroll
  for (int j = 0; j < NJ; ++j) {
    int gn = n0 + wc + j * 16 + cn;
    float bv = bias ? bias[gn] : 0.f;
#pragma unroll
    for (int i = 0; i < NI; ++i) {
#pragma unroll
      for (int r = 0; r < 4; ++r) {
        int gm = m0 + wr + i * 16 + rq + r;
        long idx = (long)gm * ldc + gn;
        float v = acc[i][j][r] + bv;
        if (rowBias) v += rowBias[(gm >> 9) * N + gn];
        if (residv)
          v += rBf16 ? b2f(((const u16*)residv)[idx + zr]) : ((const float*)residv)[idx + zr];
        if (OP == 1) v = fmaxf(v, 0.f);
        if (OP == 2) v = 0.5f * v * (1.f + erff(v * 0.70710678118654752440f));
        if (OP == 3) v = 1.f / (1.f + expf(-v));
        if (outBf16) slab[(i * 16 + rq + r) * 72 + j * 16 + cn] = f2b(v);
        else Cf[idx] = v;
      }
    }
  }
  if (outBf16) {
#pragma unroll
    for (int p = 0; p < NI * 2; ++p) {            // 4 passes: 8 rows x 128B each
      int rr = p * 8 + (lane >> 3);
      us8 vv = *(const us8*)(slab + rr * 72 + (lane & 7) * 8);
      *(us8*)(Ch + (long)(m0 + wr + rr) * ldc + n0 + wc + (lane & 7) * 8) = vv;
    }
  }
}

// ---------------------------------------------------------------------------
// bulk fp32 -> bf16 conversion with row remap (pitch) + per-b scale.
// ---------------------------------------------------------------------------
#define NJOBS 27
struct ConvJobs {
  const float* src[NJOBS];
  u16* dst[NJOBS];
  int n2[NJOBS];         // pairs (8 floats) per job
  int rowLen2[NJOBS];    // pairs per source row
  int dstPitch2[NJOBS];  // dst row pitch in pairs
  const float* scl[NJOBS];  // per-(row>>9) scale or null
};
__global__ void convert_all(ConvJobs J, long total2)
{
  long g = (long)blockIdx.x * 256 + threadIdx.x;
  if (g >= total2) return;
  int j = 0; long off = g;
  while (off >= J.n2[j]) { off -= J.n2[j]; ++j; }
  long row = off / J.rowLen2[j];
  long c2  = off - row * J.rowLen2[j];
  const float4* s = (const float4*)J.src[j] + off * 2;
  float4 x = s[0], y = s[1];
  float sc = J.scl[j] ? J.scl[j][row >> 9] : 1.f;
  us8 h;
  h[0] = f2b(x.x * sc); h[1] = f2b(x.y * sc); h[2] = f2b(x.z * sc); h[3] = f2b(x.w * sc);
  h[4] = f2b(y.x * sc); h[5] = f2b(y.y * sc); h[6] = f2b(y.z * sc); h[7] = f2b(y.w * sc);
  *(us8*)(J.dst[j] + (row * (long)J.dstPitch2[j] + c2) * 8) = h;
}

__global__ void zero_kernel(u16* zp)
{
  int i = blockIdx.x * 256 + threadIdx.x;
  if (i < 8192) zp[i] = 0;
}

__global__ void copy16(const u16* __restrict__ s, u16* __restrict__ d)
{
  long g = (long)blockIdx.x * 256 + threadIdx.x;
  *(us8*)(d + g * 8) = *(const us8*)(s + g * 8);
}

// LayerNorm over D=768; input fp32 or bf16; out fp32 or bf16
__global__ void ln_kernel(const void* __restrict__ x, int xBf16,
                          const float* __restrict__ w, const float* __restrict__ b,
                          float* __restrict__ y32, u16* __restrict__ y16, int accum)
{
  const int row = blockIdx.x;
  const int tid = threadIdx.x;
  __shared__ float rs[256], rq[256];
  float v[3];
  long base = (long)row * DD;
  float s = 0.f, q = 0.f;
#pragma unroll
  for (int i = 0; i < 3; ++i) {
    int c = tid + i * 256;
    float t = xBf16 ? b2f(((const u16*)x)[base + c]) : ((const float*)x)[base + c];
    v[i] = t; s += t; q += t * t;
  }
  rs[tid] = s; rq[tid] = q; __syncthreads();
  for (int st = 128; st > 0; st >>= 1) {
    if (tid < st) { rs[tid] += rs[tid + st]; rq[tid] += rq[tid + st]; }
    __syncthreads();
  }
  float mean = rs[0] * (1.f / DD);
  float var  = fmaxf(rq[0] * (1.f / DD) - mean * mean, 0.f);
  float rstd = rsqrtf(var + 1e-12f);
#pragma unroll
  for (int i = 0; i < 3; ++i) {
    int c = tid + i * 256;
    float o = ((v[i] - mean) * rstd) * w[c] + b[c];
    if (y32) { if (accum) y32[base + c] += o; else y32[base + c] = o; }
    if (y16) {
      if (accum && !y32) y16[base + c] = f2b(b2f(y16[base + c]) + o);
      else y16[base + c] = f2b(o);
    }
  }
}

// Ef = g*Ea + (1-g)*Et, then LN(Ef) -> bf16. Et read from cc left half (pitch 1536).
__global__ void ef_ln_kernel(const u16* __restrict__ g, const float* __restrict__ Ea,
                             const u16* __restrict__ EtC,
                             const float* __restrict__ w, const float* __restrict__ b,
                             u16* __restrict__ xo)
{
  const int row = blockIdx.x;
  const int tid = threadIdx.x;
  __shared__ float rs[256], rq[256];
  float v[3];
  float s = 0.f, q = 0.f;
#pragma unroll
  for (int i = 0; i < 3; ++i) {
    int c = tid + i * 256;
    float gv = b2f(g[(long)row * DD + c]);
    float et = b2f(EtC[(long)row * 1536 + c]);
    float e  = gv * Ea[(long)row * DD + c] + (1.f - gv) * et;
    v[i] = e; s += e; q += e * e;
  }
  rs[tid] = s; rq[tid] = q; __syncthreads();
  for (int st = 128; st > 0; st >>= 1) {
    if (tid < st) { rs[tid] += rs[tid + st]; rq[tid] += rq[tid + st]; }
    __syncthreads();
  }
  float mean = rs[0] * (1.f / DD);
  float var  = fmaxf(rq[0] * (1.f / DD) - mean * mean, 0.f);
  float rstd = rsqrtf(var + 1e-12f);
#pragma unroll
  for (int i = 0; i < 3; ++i) {
    int c = tid + i * 256;
    xo[(long)row * DD + c] = f2b(((v[i] - mean) * rstd) * w[c] + b[c]);
  }
}

// Pn = LN( sum_z LN(outp[z], fln) , ln ). Sum in f32.
__global__ void ln3sum_kernel(const u16* __restrict__ o,
                              const float* __restrict__ fw, const float* __restrict__ fb,
                              const float* __restrict__ lw, const float* __restrict__ lb,
                              u16* __restrict__ Pn)
{
  const int row = blockIdx.x;
  const int tid = threadIdx.x;
  __shared__ float rs[256], rq[256];
  float v[3][3], mz[3], rz[3];
  for (int z = 0; z < 3; ++z) {
    long base = (long)z * MDL + (long)row * DD;
    float s = 0.f, q = 0.f;
#pragma unroll
    for (int i = 0; i < 3; ++i) {
      int c = tid + i * 256;
      float t = b2f(o[base + c]);
      v[z][i] = t; s += t; q += t * t;
    }
    rs[tid] = s; rq[tid] = q; __syncthreads();
    for (int st = 128; st > 0; st >>= 1) {
      if (tid < st) { rs[tid] += rs[tid + st]; rq[tid] += rq[tid + st]; }
      __syncthreads();
    }
    float mean = rs[0] * (1.f / DD);
    float var  = fmaxf(rq[0] * (1.f / DD) - mean * mean, 0.f);
    mz[z] = mean; rz[z] = rsqrtf(var + 1e-12f);
    __syncthreads();
  }
  float p[3];
  float s = 0.f, q = 0.f;
#pragma unroll
  for (int i = 0; i < 3; ++i) {
    int c = tid + i * 256;
    float pv = 0.f;
#pragma unroll
    for (int z = 0; z < 3; ++z) pv += (v[z][i] - mz[z]) * rz[z];
    pv = pv * fw[c] + 3.f * fb[c];
    p[i] = pv; s += pv; q += pv * pv;
  }
  rs[tid] = s; rq[tid] = q; __syncthreads();
  for (int st = 128; st > 0; st >>= 1) {
    if (tid < st) { rs[tid] += rs[tid + st]; rq[tid] += rq[tid + st]; }
    __syncthreads();
  }
  float mean = rs[0] * (1.f / DD);
  float var  = fmaxf(rq[0] * (1.f / DD) - mean * mean, 0.f);
  float rstd = rsqrtf(var + 1e-12f);
#pragma unroll
  for (int i = 0; i < 3; ++i) {
    int c = tid + i * 256;
    Pn[(long)row * DD + c] = f2b(((p[i] - mean) * rstd) * lw[c] + lb[c]);
  }
}

// all 6 streams' rowmeans in one launch
__global__ void rowmean_all(const float* f0, const float* f1, const float* f2,
                            const float* f3, const float* f4, const float* f5,
                            float* __restrict__ rm)
{
  const float* fs[6] = {f0, f1, f2, f3, f4, f5};
  int n = blockIdx.y;
  int b = blockIdx.x / 3, chunk = blockIdx.x % 3;
  int d = chunk * 256 + threadIdx.x;
  const float* base = fs[n] + (long)b * TT * DD + d;
  float s = 0.f;
  for (int t = 0; t < TT; ++t) s += base[(long)t * DD];
  rm[((long)n * BB + b) * DD + d] = s * (1.f / TT);
}

__global__ void colsum_kernel(const float* __restrict__ w, float* __restrict__ cs)
{
  int n = blockIdx.x / 3, chunk = blockIdx.x % 3;
  int e = chunk * 256 + threadIdx.x;
  const float* base = w + (long)n * DD * DD + e;
  float s = 0.f;
  for (int d = 0; d < DD; ++d) s += base[(long)d * DD];
  cs[n * DD + e] = s;
}

__global__ void fusion_weights(const float* __restrict__ rm, const float* __restrict__ cs,
                               const float* __restrict__ align_b,
                               const float* __restrict__ aw, const float* __restrict__ ab,
                               float* __restrict__ wpT)
{
  __shared__ float msh[48];
  int tid = threadIdx.x;
  if (tid < 48) {
    int b = tid / 6, n = tid % 6;
    const float* r = rm + ((long)n * BB + b) * DD;
    const float* c = cs + n * DD;
    float dot = 0.f, bs = 0.f;
    for (int e = 0; e < DD; ++e) dot += r[e] * c[e];
    for (int d = 0; d < DD; ++d) bs += align_b[n * DD + d];
    msh[b * 6 + n] = (dot + bs) * (1.f / DD);
  }
  __syncthreads();
  if (tid < BB) {
    int b = tid;
    float z[6];
#pragma unroll
    for (int n = 0; n < 6; ++n) {
      float s = ab[n];
#pragma unroll
      for (int j = 0; j < 6; ++j)
        s += (aw[n * 12 + j] + aw[n * 12 + 6 + j]) * msh[b * 6 + j];
      z[n] = fmaxf(s, 0.f);
    }
    float mx = z[0];
#pragma unroll
    for (int n = 1; n < 6; ++n) mx = fmaxf(mx, z[n]);
    float se = 0.f, e[6];
#pragma unroll
    for (int n = 0; n < 6; ++n) { e[n] = expf(z[n] - mx); se += e[n]; }
#pragma unroll
    for (int n = 0; n < 6; ++n) wpT[n * 8 + b] = e[n] / se + (1.f / 6.f);
  }
}

// rb[b,d] = sum_n wplus[b,n] * align_b[n,d]
__global__ void rowbias_kernel(const float* __restrict__ wpT, const float* __restrict__ ab,
                               float* __restrict__ rb)
{
  int b = blockIdx.x / 3;
  int d = (blockIdx.x % 3) * 256 + threadIdx.x;
  float s = 0.f;
#pragma unroll
  for (int n = 0; n < 6; ++n) s += wpT[n * 8 + b] * ab[n * DD + d];
  rb[b * DD + d] = s;
}

// conv weight [O,I,KT] fp32 -> [KT][O][I] bf16
__global__ void repack_conv(const float* __restrict__ src, u16* __restrict__ dst, int KT)
{
  long e = (long)blockIdx.x * 256 + threadIdx.x;
  if (e >= (long)KT * DD * DD) return;
  int k = (int)(e / (DD * DD));
  int rem = (int)(e - (long)k * DD * DD);
  int o = rem / DD, i = rem % DD;
  dst[e] = f2b(src[((long)o * DD + i) * KT + k]);
}

// out[row,h] = (X[row,:] . Wt[h,:] + bias[h]) * scale ; H=12, X bf16
__global__ void lin_small(const u16* __restrict__ X, const float* __restrict__ Wt,
                          const float* __restrict__ bias, float scale,
                          float* __restrict__ out)
{
  int row = blockIdx.x * 4 + (threadIdx.x >> 6);
  int lane = threadIdx.x & 63;
  float acc[12];
#pragma unroll
  for (int h = 0; h < 12; ++h) acc[h] = 0.f;
  for (int k = lane; k < DD; k += 64) {
    float xv = b2f(X[(long)row * DD + k]);
#pragma unroll
    for (int h = 0; h < 12; ++h) acc[h] += xv * Wt[h * DD + k];
  }
#pragma unroll
  for (int h = 0; h < 12; ++h)
    for (int off = 32; off > 0; off >>= 1) acc[h] += __shfl_down(acc[h], off);
  if (lane == 0) {
#pragma unroll
    for (int h = 0; h < 12; ++h)
      out[(long)row * 12 + h] = (acc[h] + bias[h]) * scale;
  }
}

__global__ void scores_softmax(const float* __restrict__ qs, const float* __restrict__ ks,
                               u16* __restrict__ aw)
{
  int bs = blockIdx.x;            // global (z*8+b)*512+s
  int b = bs >> 9;
  int tid = threadIdx.x;
  __shared__ float qsh[12];
  __shared__ float red[256];
  if (tid < 12) qsh[tid] = qs[(long)bs * 12 + tid];
  __syncthreads();
  float sc[2];
#pragma unroll
  for (int p = 0; p < 2; ++p) {
    int c = tid + p * 256;
    const float* kr = ks + (long)(b * 512 + c) * 12;
    float v = 0.f;
#pragma unroll
    for (int h = 0; h < 12; ++h) v += qsh[h] * kr[h];
    sc[p] = v;
  }
  red[tid] = fmaxf(sc[0], sc[1]); __syncthreads();
  for (int st = 128; st > 0; st >>= 1) {
    if (tid < st) red[tid] = fmaxf(red[tid], red[tid + st]);
    __syncthreads();
  }
  float mx = red[0]; __syncthreads();
  float e0 = expf(sc[0] - mx), e1 = expf(sc[1] - mx);
  red[tid] = e0 + e1; __syncthreads();
  for (int st = 128; st > 0; st >>= 1) {
    if (tid < st) red[tid] += red[tid + st];
    __syncthreads();
  }
  float inv = 1.f / red[0];
  aw[(long)bs * 512 + tid]       = f2b(e0 * inv);
  aw[(long)bs * 512 + tid + 256] = f2b(e1 * inv);
}

__global__ void transpose_kernel(const u16* __restrict__ in, u16* __restrict__ out)
{
  int b = blockIdx.z;
  const u16* ib = in + (long)b * TT * DD;
  u16* ob = out + (long)b * TT * DD;
  __shared__ u16 tile[32][33];
  int c0 = blockIdx.x * 32;   // d
  int r0 = blockIdx.y * 32;   // t
  int tx = threadIdx.x, ty = threadIdx.y;
#pragma unroll
  for (int i = 0; i < 4; ++i)
    tile[ty + 8 * i][tx] = ib[(long)(r0 + ty + 8 * i) * DD + c0 + tx];
  __syncthreads();
#pragma unroll
  for (int i = 0; i < 4; ++i)
    ob[(long)(c0 + ty + 8 * i) * TT + r0 + tx] = tile[tx][ty + 8 * i];
}

// ---------------------------------------------------------------------------
extern "C" void kernel_launch(void* const* d_in, const int* in_sizes, int n_in,
                              void* d_out, int out_size, void* d_ws, size_t ws_size,
                              hipStream_t stream)
{
  (void)in_sizes; (void)n_in; (void)out_size; (void)ws_size;
  const float* fin[6];
  for (int i = 0; i < 6; ++i) fin[i] = (const float*)d_in[i];
  const float* Ea      = (const float*)d_in[6];
  const float* align_w = (const float*)d_in[7];
  const float* align_b = (const float*)d_in[8];
  const float* att_w   = (const float*)d_in[9];
  const float* att_b   = (const float*)d_in[10];
  const float* g1_w = (const float*)d_in[11]; const float* g1_b = (const float*)d_in[12];
  const float* g2_w = (const float*)d_in[13]; const float* g2_b = (const float*)d_in[14];
  const float* g3_w = (const float*)d_in[15]; const float* g3_b = (const float*)d_in[16];
  const float* g4_w = (const float*)d_in[17]; const float* g4_b = (const float*)d_in[18];
  const float* ln_w = (const float*)d_in[19]; const float* ln_b = (const float*)d_in[20];
  const float* c1_w = (const float*)d_in[21]; const float* c1_b = (const float*)d_in[22];
  const float* c3_w = (const float*)d_in[23]; const float* c3_b = (const float*)d_in[24];
  const float* c5_w = (const float*)d_in[25]; const float* c5_b = (const float*)d_in[26];
  const float* q_w  = (const float*)d_in[27]; const float* q_b  = (const float*)d_in[28];
  const float* qa_w = (const float*)d_in[29]; const float* qa_b = (const float*)d_in[30];
  const float* k_w  = (const float*)d_in[31]; const float* k_b  = (const float*)d_in[32];
  const float* ka_w = (const float*)d_in[33]; const float* ka_b = (const float*)d_in[34];
  const float* tr_w = (const float*)d_in[35]; const float* tr_b = (const float*)d_in[36];
  const float* ao_w = (const float*)d_in[37]; const float* ao_b = (const float*)d_in[38];
  const float* fln_w = (const float*)d_in[39]; const float* fln_b = (const float*)d_in[40];
  const float* fi_w = (const float*)d_in[41]; const float* fi_b = (const float*)d_in[42];
  const float* fo_w = (const float*)d_in[43]; const float* fo_b = (const float*)d_in[44];
  const float* m1_w = (const float*)d_in[45]; const float* m1_b = (const float*)d_in[46];
  const float* m2_w = (const float*)d_in[47]; const float* m2_b = (const float*)d_in[48];
  const float* out_w = (const float*)d_in[49]; const float* out_b = (const float*)d_in[50];

  char* ws = (char*)d_ws;
  size_t off = 0;
  auto alloc = [&](size_t bytes) -> char* {
    char* p = ws + off;
    off += bytes;
    off = (off + 255) & ~(size_t)255;
    return p;
  };

  // small scratch
  u16*   zp    = (u16*)alloc(16384);   // 8K-element zero page (pointer-walk safe)
  float* rmb   = (float*)alloc(6L * BB * DD * 4);
  float* csb   = (float*)alloc(6L * DD * 4);
  float* wpT   = (float*)alloc(48 * 4);
  float* rbias = (float*)alloc((long)BB * DD * 4);
  float* qsf   = (float*)alloc(3L * MM * 12 * 4);
  float* ksf   = (float*)alloc(3L * MM * 12 * 4);

  // bf16 weight cache (55.4 MB); cW_al is the K-concatenated align weight
  u16* Wc = (u16*)alloc(27721728L * 2);
  u16* cW_g1   = Wc;
  u16* cW_g2   = Wc + 2359296L;
  u16* cW_fi   = Wc + 4718592L;
  u16* cW_fo   = Wc + 7077888L;
  u16* cW_m1   = Wc + 9437184L;
  u16* cW_m2   = Wc + 11796480L;
  u16* cW_g3   = Wc + 14155776L;
  u16* cW_al   = Wc + 15335424L;
  u16* cW_g4   = Wc + 18874368L;
  u16* cW_c1   = Wc + 19464192L;
  u16* cW_q    = Wc + 20054016L;
  u16* cW_k    = Wc + 20643840L;
  u16* cW_tr   = Wc + 21233664L;
  u16* cW_ao   = Wc + 21823488L;
  u16* cW_out  = Wc + 22413312L;
  u16* w3r     = Wc + 23003136L;
  u16* w5r     = Wc + 24772608L;

  // big aliased regions (~184 MB); R1,R3,R4 are CONTIGUOUS (sizes 256-aligned)
  char* R1 = alloc((long)MM * 4608 * 2);  // A' -> qbuf -> [interb3 head] -> Jb
  char* R3 = alloc(MDL * 8);              // cc+o1 -> ctxkk -> [interb3] -> Pn+Jn
  char* R4 = alloc(MDL * 8);              // o2+o3+gb -> kkTsf -> [interb3 tail]
  char* R5 = alloc(MDL * 2);              // xb16 (persistent)
  char* R6 = alloc(MDL * 8);              // U = [U5,U3,U1,U5dup]
  char* R8 = alloc(MDL * 6);              // attp -> outp (3 layers)
  char* R9 = alloc(MDL * 6);              // attb (3 layers)
  char* R10 = alloc((long)MM * FFN * 2);  // awb -> interb (m1/m2)

  u16*   Ap    = (u16*)R1;
  u16*   qbuf  = (u16*)R1;
  float* Jb    = (float*)R1;
  u16*   interb3 = (u16*)R1;               // 75.5 MB spans R1+R3+R4 (fi->fo only)
  u16*   cc    = (u16*)R3;                 // [MM][1536]: left=Et(b16), right=Ea(b16)
  u16*   o1    = (u16*)R3 + 2 * MDL;
  u16*   ctxkk = (u16*)R3;
  u16*   PnB   = (u16*)R3;
  u16*   Jn    = (u16*)R3 + MDL;
  u16*   o2    = (u16*)R4;
  u16*   o3    = (u16*)R4 + 2 * MDL;
  u16*   gbuf  = (u16*)R4 + 3 * MDL;
  u16*   kkTsf = (u16*)R4;
  u16*   xb16  = (u16*)R5;
  u16*   U     = (u16*)R6;
  u16*   attp  = (u16*)R8;
  u16*   outp  = (u16*)R8;
  u16*   attb  = (u16*)R9;
  u16*   awb   = (u16*)R10;
  u16*   interb = (u16*)R10;

  // uniform 128x64 tile (48KB LDS, 3 blocks/CU)
  auto gemm = [&](int op, int ntaps, const u16* A, const u16* W,
                  const float* bias, const float* rowBias,
                  const void* resid, int rB, void* Cc, int oB,
                  int Mi, int Ni, int Ki, int ldc,
                  int pad, long wtap,
                  int batch, long ab, long wb, long cb, long rbch) {
#define GL(OPV, NT) gemm_bt<128, 64, OPV, NT><<<dim3(Ni / 64, Mi / 128, batch), 256, 0, stream>>>( \
      A, W, bias, rowBias, resid, Cc, Ni, Ki, ldc, rB, oB, pad, wtap, ab, wb, cb, rbch, zp)
    if (ntaps == 5)      GL(0, 5);
    else if (ntaps == 3) GL(0, 3);
    else if (op == 1)    GL(1, 1);
    else if (op == 2)    GL(2, 1);
    else if (op == 3)    GL(3, 1);
    else                 GL(0, 1);
#undef GL
  };

  zero_kernel<<<32, 256, 0, stream>>>(zp);

  // --- fusion weights first (analytic means over fp32 inputs) ---
  rowmean_all<<<dim3(24, 6), 256, 0, stream>>>(fin[0], fin[1], fin[2], fin[3], fin[4], fin[5], rmb);
  colsum_kernel<<<18, 256, 0, stream>>>(align_w, csb);
  fusion_weights<<<1, 64, 0, stream>>>(rmb, csb, align_b, att_w, att_b, wpT);
  rowbias_kernel<<<24, 256, 0, stream>>>(wpT, align_b, rbias);

  // --- bulk conversion: weights + wplus-scaled interleaved A' + Ea->cc right half ---
  {
    ConvJobs J;
    int idx = 0;
    long total2 = 0;
    auto add = [&](const float* s, u16* d, int n2v, int rl2, int dp2, const float* sc) {
      J.src[idx] = s; J.dst[idx] = d; J.n2[idx] = n2v;
      J.rowLen2[idx] = rl2; J.dstPitch2[idx] = dp2; J.scl[idx] = sc;
      total2 += n2v; ++idx;
    };
    for (int n = 0; n < 6; ++n)                       // A'[row][n*768+k] = wplus*f_n
      add(fin[n], Ap + n * DD, 393216, 96, 576, wpT + n * 8);
    add(Ea, cc + DD, 393216, 96, 192, nullptr);       // cc right half
    add(g1_w, cW_g1, 294912, 294912, 294912, nullptr);
    add(g2_w, cW_g2, 294912, 294912, 294912, nullptr);
    add(fi_w, cW_fi, 294912, 294912, 294912, nullptr);
    add(fo_w, cW_fo, 294912, 294912, 294912, nullptr);
    add(m1_w, cW_m1, 294912, 294912, 294912, nullptr);
    add(m2_w, cW_m2, 294912, 294912, 294912, nullptr);
    add(g3_w, cW_g3, 147456, 147456, 147456, nullptr);
    for (int n = 0; n < 6; ++n)                       // W'[o][n*768+k] = align_w[n][o][k]
      add(align_w + (long)n * 589824, cW_al + n * DD, 73728, 96, 576, nullptr);
    add(g4_w, cW_g4, 73728, 73728, 73728, nullptr);
    add(c1_w, cW_c1, 73728, 73728, 73728, nullptr);
    add(q_w,  cW_q,  73728, 73728, 73728, nullptr);
    add(k_w,  cW_k,  73728, 73728, 73728, nullptr);
    add(tr_w, cW_tr, 73728, 73728, 73728, nullptr);
    add(ao_w, cW_ao, 73728, 73728, 73728, nullptr);
    add(out_w, cW_out, 73728, 73728, 73728, nullptr);
    convert_all<<<(int)((total2 + 255) / 256), 256, 0, stream>>>(J, total2);
  }
  repack_conv<<<(3 * 589824 + 255) / 256, 256, 0, stream>>>(c3_w, w3r, 3);
  repack_conv<<<(5 * 589824 + 255) / 256, 256, 0, stream>>>(c5_w, w5r, 5);

  // --- FeatureAlignment: ONE GEMM, K=4608, writes Et(bf16) into cc left half ---
  gemm(0, 1, Ap, cW_al, nullptr, rbias, nullptr, 0, cc, 1,
       MM, DD, 4608, 1536, 0, 0, 1, 0, 0, 0, 0);

  // --- GatedFusion ---
  gemm(1, 1, cc, cW_g1, g1_b, nullptr, nullptr, 0, o1, 1, MM, 1536, 1536, 1536, 0, 0, 1, 0, 0, 0, 0);
  gemm(1, 1, o1, cW_g2, g2_b, nullptr, nullptr, 0, o2, 1, MM, 1536, 1536, 1536, 0, 0, 1, 0, 0, 0, 0);
  gemm(1, 1, o2, cW_g3, g3_b, nullptr, nullptr, 0, o3, 1, MM, DD, 1536, DD, 0, 0, 1, 0, 0, 0, 0);
  gemm(3, 1, o3, cW_g4, g4_b, nullptr, nullptr, 0, gbuf, 1, MM, DD, DD, DD, 0, 0, 1, 0, 0, 0, 0);
  ef_ln_kernel<<<MM, 256, 0, stream>>>(gbuf, Ea, cc, ln_w, ln_b, xb16);   // x = LN(Ef)

  // --- multi-scale convs; U layout [U5,U3,U1,U5dup] ---
  gemm(0, 5, xb16, w5r, c5_b, nullptr, nullptr, 0, U, 1, MM, DD, DD, DD, 2, 589824, 1, 0, 0, 0, 0);
  gemm(0, 3, xb16, w3r, c3_b, nullptr, nullptr, 0, U + MDL, 1, MM, DD, DD, DD, 1, 589824, 1, 0, 0, 0, 0);
  gemm(0, 1, xb16, cW_c1, c1_b, nullptr, nullptr, 0, U + 2 * MDL, 1, MM, DD, DD, DD, 0, 0, 1, 0, 0, 0, 0);
  copy16<<<1536, 256, 0, stream>>>(U, U + 3 * MDL);   // U5dup

  // --- 3 fastformer layers, batched z=3: hid=U+z*MDL, ctx=U+(z+1)*MDL ---
  gemm(0, 1, U,       cW_q, q_b, nullptr, nullptr, 0, qbuf,  1, MM, DD, DD, DD, 0, 0, 3, MDL, 0, MDL, 0);
  gemm(0, 1, U + MDL, cW_k, k_b, nullptr, nullptr, 0, ctxkk, 1, MM, DD, DD, DD, 0, 0, 3, MDL, 0, MDL, 0);
  lin_small<<<3 * MM / 4, 256, 0, stream>>>(qbuf,  qa_w, qa_b, 0.125f, qsf);
  lin_small<<<3 * MM / 4, 256, 0, stream>>>(ctxkk, ka_w, ka_b, 0.125f, ksf);
  scores_softmax<<<3 * MM, 256, 0, stream>>>(qsf, ksf, awb);
  transpose_kernel<<<dim3(24, 16, 24), dim3(32, 8), 0, stream>>>(ctxkk, kkTsf);
  gemm(0, 1, awb, kkTsf, nullptr, nullptr, nullptr, 0, ctxkk, 1, TT, DD, TT, DD,
       0, 0, 24, (long)TT * TT, (long)DD * TT, (long)TT * DD, 0);
  gemm(0, 1, ctxkk, cW_tr, tr_b, nullptr, qbuf, 1, kkTsf, 1, MM, DD, DD, DD, 0, 0, 3, MDL, 0, MDL, MDL);
  gemm(0, 1, kkTsf, cW_ao, ao_b, nullptr, U,    1, attp,  1, MM, DD, DD, DD, 0, 0, 3, MDL, 0, MDL, MDL);
  ln_kernel<<<3 * MM, 256, 0, stream>>>(attp, 1, fln_w, fln_b, nullptr, attb, 0);
  // FFN: batched z=3; fi grid 48x32x3=4608, fo grid 12x32x3=1152
  gemm(2, 1, attb, cW_fi, fi_b, nullptr, nullptr, 0, interb3, 1,
       MM, FFN, DD, FFN, 0, 0, 3, MDL, 0, (long)MM * FFN, 0);
  gemm(0, 1, interb3, cW_fo, fo_b, nullptr, attb, 1, outp, 1,
       MM, DD, FFN, DD, 0, 0, 3, (long)MM * FFN, 0, MDL, MDL);
  ln3sum_kernel<<<MM, 256, 0, stream>>>(outp, fln_w, fln_b, ln_w, ln_b, PnB);

  // --- tail ---
  gemm(2, 1, PnB, cW_m1, m1_b, nullptr, nullptr, 0, interb, 1, MM, FFN, DD, FFN, 0, 0, 1, 0, 0, 0, 0);
  gemm(0, 1, interb, cW_m2, m2_b, nullptr, xb16, 1, Jb, 0, MM, DD, FFN, DD, 0, 0, 1, 0, 0, 0, 0);
  ln_kernel<<<MM, 256, 0, stream>>>(Jb, 0, ln_w, ln_b, nullptr, Jn, 0);
  gemm(0, 1, Jn, cW_out, out_b, nullptr, nullptr, 0, d_out, 0, MM, DD, DD, DD, 0, 0, 1, 0, 0, 0, 0);
}